// Round 3
// baseline (5927.229 us; speedup 1.0000x reference)
//
#include <hip/hip_runtime.h>

typedef unsigned short u16;
typedef __attribute__((ext_vector_type(8))) short short8;
typedef __attribute__((ext_vector_type(4))) float floatx4;
typedef _Float16 half8 __attribute__((ext_vector_type(8)));
typedef _Float16 half2v __attribute__((ext_vector_type(2)));

#define AGENT __HIP_MEMORY_SCOPE_AGENT

// ---------- helpers ----------
__device__ __forceinline__ float bf2f(u16 v) { return __uint_as_float(((unsigned)v) << 16); }
__device__ __forceinline__ u16 f2bf(float f) {
    unsigned u = __float_as_uint(f);
    unsigned r = (u + 0x7FFFu + ((u >> 16) & 1u)) >> 16;
    return (u16)r;
}
__device__ __forceinline__ float sigm_(float x) { return 1.f / (1.f + __expf(-x)); }
__device__ __forceinline__ float tanh_(float x) {
    x = fminf(fmaxf(x, -15.f), 15.f);
    float e = __expf(2.f * x);
    return (e - 1.f) / (e + 1.f);
}

// B=32, C=512, H=6, W=40, NC=97, L=26, T=27

// ---------- dtype sniffing: flag=1 if inputs are fp32, 0 if bf16 ----------
__global__ void sniff_k(const void* __restrict__ feat_raw, int* __restrict__ flag) {
    if (threadIdx.x == 0 && blockIdx.x == 0) {
        const u16* p = (const u16*)feat_raw;
        int insane = 0;
        #pragma unroll
        for (int i = 0; i < 32; i += 2) {
            float x = bf2f(p[i]);
            float a = fabsf(x);
            if (!(a <= 1000.f)) insane = 1;
            if (x != 0.f && a < 1e-8f) insane = 1;
        }
        *flag = insane;
    }
}

// zero the lstm barrier counters (ws is poisoned 0xAA each launch)
__global__ void init_bar_k(int* __restrict__ bar) {
    bar[threadIdx.x] = 0;
}

// canonical bf16 copy of a float tensor (either fp32 or bf16 source)
__global__ __launch_bounds__(256) void canon_k(const void* __restrict__ src, u16* __restrict__ dst,
                                               int n, const int* __restrict__ flag) {
    int i = blockIdx.x * 256 + threadIdx.x;
    if (i >= n) return;
    if (*flag) dst[i] = f2bf(((const float*)src)[i]);
    else       dst[i] = ((const u16*)src)[i];
}

// canonical fp32 copy (for valid_ratios: exact mask arithmetic)
__global__ __launch_bounds__(64) void canonf_k(const void* __restrict__ src, float* __restrict__ dst,
                                               int n, const int* __restrict__ flag) {
    int i = blockIdx.x * 64 + threadIdx.x;
    if (i >= n) return;
    dst[i] = (*flag) ? ((const float*)src)[i] : bf2f(((const u16*)src)[i]);
}

// ---------- prep kernels ----------

// fc (B,C,6,40) bf16 -> featv (B,40,C) bf16 (max over H)
__global__ __launch_bounds__(256) void featv_k(const u16* __restrict__ fc, u16* __restrict__ featv) {
    int idx = blockIdx.x * 256 + threadIdx.x;
    int c = idx & 511;
    int r = idx >> 9;
    int w = r % 40, b = r / 40;
    float mx = -1e30f;
    const u16* fp = fc + ((long)(b * 512 + c) * 6) * 40 + w;
    #pragma unroll
    for (int h = 0; h < 6; h++) mx = fmaxf(mx, bf2f(fp[h * 40]));
    featv[idx] = f2bf(mx);
}

// fc (B,C,6,40) -> featP (B,8,42,C) bf16 zero-padded NHWC
__global__ __launch_bounds__(256) void padfeat_k(const u16* __restrict__ fc, u16* __restrict__ featP) {
    int idx = blockIdx.x * 256 + threadIdx.x;
    int c = idx & 511;
    int r = idx >> 9;
    int wp = r % 42; int r2 = r / 42;
    int hp = r2 & 7; int b = r2 >> 3;
    u16 v = 0;
    if (hp >= 1 && hp <= 6 && wp >= 1 && wp <= 40)
        v = fc[((long)(b * 512 + c) * 6 + (hp - 1)) * 40 + (wp - 1)];
    featP[idx] = v;
}

// k_W (Co,Ci,3,3) raw -> W2 (Co, (kh*3+kw)*512+ci) bf16, dtype-aware
__global__ __launch_bounds__(256) void w2_k(const void* __restrict__ kW, u16* __restrict__ W2,
                                            const int* __restrict__ flag) {
    int idx = blockIdx.x * 256 + threadIdx.x;
    int co = idx / 4608;
    int r = idx % 4608;
    int kh = r / 1536;
    int r2 = r % 1536;
    int kw = r2 / 512;
    int ci = r2 & 511;
    long si = ((long)(co * 512 + ci) * 3 + kh) * 3 + kw;
    W2[idx] = (*flag) ? f2bf(((const float*)kW)[si]) : ((const u16*)kW)[si];
}

// Whh (2048,512) raw -> Wq3 f16 for lstm_sync.
// flat o = (((j*32 + c)*512 + t)*8 + jj); thread t: rid=t>>1, hf=t&1;
// n = (rid>>6)*512 + j*64 + (rid&63); k = hf*256 + c*8 + jj
__global__ __launch_bounds__(256) void wq3_k(const void* __restrict__ W, _Float16* __restrict__ Wq3,
                                             const int* __restrict__ flag) {
    int o = blockIdx.x * 256 + threadIdx.x;       // 131072 total, each writes 8
    int t = o & 511;
    int c = (o >> 9) & 31;
    int j = o >> 14;                              // 0..7
    int rid = t >> 1, hf = t & 1;
    int n = (rid >> 6) * 512 + j * 64 + (rid & 63);
    int k = hf * 256 + c * 8;
    int fl = *flag;
    _Float16* dst = Wq3 + (long)o * 8;
    #pragma unroll
    for (int jj = 0; jj < 8; jj++) {
        long si = (long)n * 512 + k + jj;
        float v = fl ? ((const float*)W)[si] : bf2f(((const u16*)W)[si]);
        dst[jj] = (_Float16)v;
    }
}

// ---------- NT GEMM: C(MxN,f32) = A(MxK,bf16,lda) * B(NxK,bf16)^T + bias ----------
__global__ __launch_bounds__(256) void gemm_nt_f32(
    const u16* __restrict__ A, int lda,
    const u16* __restrict__ Bw,
    const u16* __restrict__ bias0, const u16* __restrict__ bias1,
    float* __restrict__ C, int M, int N, int K, int ldc)
{
    __shared__ __align__(16) u16 As[64][40];
    __shared__ __align__(16) u16 Bs[64][40];
    const int tid = threadIdx.x;
    const int bn = blockIdx.x, bm = blockIdx.y;
    const int l = tid & 63, wid = tid >> 6;
    const int wm = wid >> 1, wn = wid & 1;
    const int lr = tid >> 2, lc = (tid & 3) * 8;
    const int l15 = l & 15, lq = l >> 4;

    floatx4 acc00 = (floatx4)(0.f), acc01 = (floatx4)(0.f), acc10 = (floatx4)(0.f), acc11 = (floatx4)(0.f);

    int am = bm * 64 + lr; if (am > M - 1) am = M - 1;
    const u16* Ap = A + (long)am * lda + lc;
    const u16* Bp = Bw + (long)(bn * 64 + lr) * K + lc;

    for (int k0 = 0; k0 < K; k0 += 32) {
        *(short8*)&As[lr][lc] = *(const short8*)(Ap + k0);
        *(short8*)&Bs[lr][lc] = *(const short8*)(Bp + k0);
        __syncthreads();
        short8 af0 = *(const short8*)&As[wm * 32 + l15][lq * 8];
        short8 af1 = *(const short8*)&As[wm * 32 + 16 + l15][lq * 8];
        short8 bf0 = *(const short8*)&Bs[wn * 32 + l15][lq * 8];
        short8 bf1 = *(const short8*)&Bs[wn * 32 + 16 + l15][lq * 8];
        acc00 = __builtin_amdgcn_mfma_f32_16x16x32_bf16(af0, bf0, acc00, 0, 0, 0);
        acc01 = __builtin_amdgcn_mfma_f32_16x16x32_bf16(af0, bf1, acc01, 0, 0, 0);
        acc10 = __builtin_amdgcn_mfma_f32_16x16x32_bf16(af1, bf0, acc10, 0, 0, 0);
        acc11 = __builtin_amdgcn_mfma_f32_16x16x32_bf16(af1, bf1, acc11, 0, 0, 0);
        __syncthreads();
    }
    floatx4 accs[2][2] = {{acc00, acc01}, {acc10, acc11}};
    #pragma unroll
    for (int i = 0; i < 2; i++)
        #pragma unroll
        for (int j = 0; j < 2; j++)
            #pragma unroll
            for (int r = 0; r < 4; r++) {
                int gm = bm * 64 + wm * 32 + i * 16 + lq * 4 + r;
                int gn = bn * 64 + wn * 32 + j * 16 + l15;
                if (gm < M) {
                    float v = accs[i][j][r];
                    if (bias0) v += bf2f(bias0[gn]);
                    if (bias1) v += bf2f(bias1[gn]);
                    C[(long)gm * ldc + gn] = v;
                }
            }
}

// ---------- conv3x3 as implicit-im2col NT GEMM: out kmap (B*240, 512) bf16 ----------
__global__ __launch_bounds__(256) void conv_gemm(
    const u16* __restrict__ featP, const u16* __restrict__ W2,
    const u16* __restrict__ kb, u16* __restrict__ kmap)
{
    __shared__ __align__(16) u16 As[64][40];
    __shared__ __align__(16) u16 Bs[64][40];
    const int tid = threadIdx.x;
    const int bn = blockIdx.x, bm = blockIdx.y;
    const int l = tid & 63, wid = tid >> 6;
    const int wm = wid >> 1, wn = wid & 1;
    const int lr = tid >> 2, lc = (tid & 3) * 8;
    const int l15 = l & 15, lq = l >> 4;

    floatx4 acc00 = (floatx4)(0.f), acc01 = (floatx4)(0.f), acc10 = (floatx4)(0.f), acc11 = (floatx4)(0.f);

    int gm = bm * 64 + lr;
    int b = gm / 240;
    int hw = gm % 240;
    int h = hw / 40, w = hw % 40;
    const u16* fb = featP + (long)(b * 8) * 42 * 512;
    const u16* Bp = W2 + (long)(bn * 64 + lr) * 4608 + lc;

    for (int k0 = 0; k0 < 4608; k0 += 32) {
        int kh = k0 / 1536;
        int kw = (k0 % 1536) / 512;
        int ci0 = k0 & 511;
        const u16* ap = fb + ((long)((h + kh) * 42 + (w + kw))) * 512 + ci0 + lc;
        *(short8*)&As[lr][lc] = *(const short8*)ap;
        *(short8*)&Bs[lr][lc] = *(const short8*)(Bp + k0);
        __syncthreads();
        short8 af0 = *(const short8*)&As[wm * 32 + l15][lq * 8];
        short8 af1 = *(const short8*)&As[wm * 32 + 16 + l15][lq * 8];
        short8 bf0 = *(const short8*)&Bs[wn * 32 + l15][lq * 8];
        short8 bf1 = *(const short8*)&Bs[wn * 32 + 16 + l15][lq * 8];
        acc00 = __builtin_amdgcn_mfma_f32_16x16x32_bf16(af0, bf0, acc00, 0, 0, 0);
        acc01 = __builtin_amdgcn_mfma_f32_16x16x32_bf16(af0, bf1, acc01, 0, 0, 0);
        acc10 = __builtin_amdgcn_mfma_f32_16x16x32_bf16(af1, bf0, acc10, 0, 0, 0);
        acc11 = __builtin_amdgcn_mfma_f32_16x16x32_bf16(af1, bf1, acc11, 0, 0, 0);
        __syncthreads();
    }
    floatx4 accs[2][2] = {{acc00, acc01}, {acc10, acc11}};
    #pragma unroll
    for (int i = 0; i < 2; i++)
        #pragma unroll
        for (int j = 0; j < 2; j++)
            #pragma unroll
            for (int r = 0; r < 4; r++) {
                int om = bm * 64 + wm * 32 + i * 16 + lq * 4 + r;
                int on = bn * 64 + wn * 32 + j * 16 + l15;
                float v = accs[i][j][r] + bf2f(kb[on]);
                kmap[(long)om * 512 + on] = f2bf(v);
            }
}

// ---------- LSTM recurrence, weight-in-register multi-block version ----------
// grid = 256 blocks: b = blockIdx>>3 (batch), j = blockIdx&7 (unit slice of 64).
// 512 threads: rid = tid>>1 (gate-row 0..255: gate g=rid>>6, unit off=rid&63),
// hf = tid&1 (k half of 256). Weights (256 rows x 512 k, f16) live in VGPRs.
// h exchange via double-buffered global hEx (agent-scope atomics) + per-batch
// monotone spin barrier bar[b]. VGPR pressure (~190) guarantees 1 block/CU,
// so all 256 blocks are co-resident -> no deadlock.
__global__ __launch_bounds__(512, 2) void lstm_sync(
    const float* __restrict__ xpre, const _Float16* __restrict__ Wq3,
    u16* __restrict__ seq_out, float* __restrict__ f32_out,
    unsigned* __restrict__ hEx, int* __restrict__ bar,
    int T, int f32_ld)
{
    const int b = blockIdx.x >> 3, j = blockIdx.x & 7;
    const int tid = threadIdx.x;
    const int hf = tid & 1;

    __shared__ __align__(16) _Float16 hS2[4 * 136];   // 4 k-slices of 128, padded
    __shared__ float part[512];                        // part[rid*2+hf] == part[tid]
    __shared__ _Float16 hLoc[64];

    // preload weights into registers: 32 chunks of half8 -> 128 half2
    half2v w2[128];
    const half8* wp8 = (const half8*)Wq3;
    #pragma unroll
    for (int c = 0; c < 32; c++) {
        half8 wv = wp8[(long)(j * 32 + c) * 512 + tid];
        w2[c * 4 + 0] = __builtin_shufflevector(wv, wv, 0, 1);
        w2[c * 4 + 1] = __builtin_shufflevector(wv, wv, 2, 3);
        w2[c * 4 + 2] = __builtin_shufflevector(wv, wv, 4, 5);
        w2[c * 4 + 3] = __builtin_shufflevector(wv, wv, 6, 7);
    }
    float cst = 0.f;

    for (int t = 0; t < T; t++) {
        float a = 0.f;
        if (t > 0) {
            // wait for all 8 blocks of this batch to finish step t-1
            if (tid == 0) {
                const int target = 8 * t;
                while (__hip_atomic_load(bar + b, __ATOMIC_ACQUIRE, AGENT) < target)
                    __builtin_amdgcn_s_sleep(4);
            }
            __syncthreads();
            // stage h(t-1) from global exchange into LDS (agent-scope loads)
            if (tid < 256) {
                unsigned v = __hip_atomic_load(
                    &hEx[(((t - 1) & 1) * 32 + b) * 256 + tid], __ATOMIC_RELAXED, AGENT);
                int k = tid * 2;
                *(unsigned*)&hS2[(k >> 7) * 136 + (k & 127)] = v;
            }
            __syncthreads();
            // recurrent dot: this thread's gate-row, its 256-k half
            #pragma unroll
            for (int c = 0; c < 32; c++) {
                int s = hf * 2 + (c >> 4);
                half8 hv = *(const half8*)&hS2[s * 136 + (c & 15) * 8];
                a = __builtin_amdgcn_fdot2(__builtin_shufflevector(hv, hv, 0, 1), w2[c * 4 + 0], a, false);
                a = __builtin_amdgcn_fdot2(__builtin_shufflevector(hv, hv, 2, 3), w2[c * 4 + 1], a, false);
                a = __builtin_amdgcn_fdot2(__builtin_shufflevector(hv, hv, 4, 5), w2[c * 4 + 2], a, false);
                a = __builtin_amdgcn_fdot2(__builtin_shufflevector(hv, hv, 6, 7), w2[c * 4 + 3], a, false);
            }
        }
        part[tid] = a;
        __syncthreads();
        // elementwise: threads 0..63 own the 64 units of this slice
        if (tid < 64) {
            const float* xp = xpre + ((long)b * T + t) * 2048;
            int w = tid;
            float gi = xp[j * 64 + w]        + part[(0   + w) * 2] + part[(0   + w) * 2 + 1];
            float gf = xp[512 + j * 64 + w]  + part[(64  + w) * 2] + part[(64  + w) * 2 + 1];
            float gg = xp[1024 + j * 64 + w] + part[(128 + w) * 2] + part[(128 + w) * 2 + 1];
            float go = xp[1536 + j * 64 + w] + part[(192 + w) * 2] + part[(192 + w) * 2 + 1];
            cst = sigm_(gf) * cst + sigm_(gi) * tanh_(gg);
            float h = sigm_(go) * tanh_(cst);
            hLoc[w] = (_Float16)h;
            long so = ((long)b * T + t) * 512 + j * 64 + w;
            seq_out[so] = f2bf(h);
            if (f32_out) f32_out[((long)b * T + t) * f32_ld + j * 64 + w] = h;
        }
        __syncthreads();
        // publish this slice's h(t) to the exchange buffer
        if (tid < 32) {
            half2v hp2 = *(const half2v*)&hLoc[2 * tid];
            unsigned v = *(const unsigned*)&hp2;
            __hip_atomic_store(&hEx[((t & 1) * 32 + b) * 256 + j * 32 + tid], v,
                               __ATOMIC_RELAXED, AGENT);
        }
        __threadfence();
        __syncthreads();
        if (tid == 0)
            __hip_atomic_fetch_add(bar + b, 1, __ATOMIC_RELEASE, AGENT);
    }
}

// ---------- token build: tok (B,27,512) bf16 ----------
__global__ __launch_bounds__(256) void tok_k(
    const float* __restrict__ holf, const u16* __restrict__ cemb,
    const int* __restrict__ label, u16* __restrict__ tok)
{
    int idx = blockIdx.x * 256 + threadIdx.x;
    int c = idx & 511;
    int m = idx >> 9;
    int b = m / 27, t = m % 27;
    float v;
    if (t == 0) v = holf[(long)b * 512 + c];
    else v = bf2f(cemb[(long)label[b * 26 + (t - 1)] * 512 + c]);
    tok[idx] = f2bf(v);
}

// ---------- fused score: tanh-dot + mask + softmax -> aw (B,27,240) f32 ----------
__global__ __launch_bounds__(256) void score_k(
    const float* __restrict__ q, const u16* __restrict__ kmap,
    const u16* __restrict__ sW, const u16* __restrict__ sb,
    const float* __restrict__ vr, float* __restrict__ aw)
{
    int bt = blockIdx.x;
    int b = bt / 27;
    int tid = threadIdx.x;
    __shared__ float qs[512];
    __shared__ float ss[512];
    __shared__ float red[256];
    qs[tid] = q[(long)bt * 512 + tid];
    qs[tid + 256] = q[(long)bt * 512 + tid + 256];
    ss[tid] = bf2f(sW[tid]);
    ss[tid + 256] = bf2f(sW[tid + 256]);
    __syncthreads();
    float sc = -INFINITY;
    float ex = 0.f;
    if (tid < 240) {
        const u16* kp = kmap + ((long)b * 240 + tid) * 512;
        float acc = 0.f;
        for (int c = 0; c < 512; c++) {
            float x = bf2f(kp[c]) + qs[c];
            acc = fmaf(ss[c], tanh_(x), acc);
        }
        acc += bf2f(sb[0]);
        float r = vr[b];
        int vw = (int)ceilf(40.f * r);
        if (vw > 40) vw = 40;
        int wcol = tid % 40;
        sc = (wcol >= vw) ? -INFINITY : acc;
    }
    red[tid] = sc;
    __syncthreads();
    for (int s = 128; s > 0; s >>= 1) {
        if (tid < s) red[tid] = fmaxf(red[tid], red[tid + s]);
        __syncthreads();
    }
    float mx = red[0];
    __syncthreads();
    if (tid < 240) ex = (sc == -INFINITY) ? 0.f : __expf(sc - mx);
    red[tid] = ex;
    __syncthreads();
    for (int s = 128; s > 0; s >>= 1) {
        if (tid < s) red[tid] += red[tid + s];
        __syncthreads();
    }
    float inv = 1.f / red[0];
    if (tid < 240) aw[(long)bt * 240 + tid] = ex * inv;
}

// ---------- attn_feat -> concat cols [512,1024) f32 ----------
__global__ __launch_bounds__(256) void attn_k(
    const u16* __restrict__ fc, const float* __restrict__ aw,
    float* __restrict__ concat)
{
    int b = blockIdx.x >> 3;
    int cc = (blockIdx.x & 7) * 64;
    int tid = threadIdx.x;
    __shared__ float awS[27 * 240];
    __shared__ u16 fS[64 * 240];
    for (int i = tid; i < 27 * 240; i += 256) awS[i] = aw[(long)b * 27 * 240 + i];
    for (int i = tid; i < 64 * 240; i += 256) fS[i] = fc[((long)b * 512 + cc) * 240 + i];
    __syncthreads();
    for (int item = tid; item < 64 * 27; item += 256) {
        int c = item / 27, t = item % 27;
        const u16* fp = &fS[c * 240];
        const float* ap = &awS[t * 240];
        float acc = 0.f;
        for (int hw = 0; hw < 240; hw++) acc = fmaf(bf2f(fp[hw]), ap[hw], acc);
        concat[((long)(b * 27 + t)) * 1536 + 512 + cc + c] = acc;
    }
}

// ---------- holistic broadcast -> concat cols [1024,1536) ----------
__global__ __launch_bounds__(256) void holfill_k(const float* __restrict__ holf, float* __restrict__ concat) {
    int idx = blockIdx.x * 256 + threadIdx.x;
    int c = idx & 511;
    int m = idx >> 9;
    int b = m / 27;
    concat[(long)m * 1536 + 1024 + c] = holf[(long)b * 512 + c];
}

// ---------- prediction + slice: out (B,26,97), dtype per flag ----------
__global__ __launch_bounds__(256) void pred_k(
    const float* __restrict__ concat, const u16* __restrict__ pW,
    const u16* __restrict__ pb, void* __restrict__ out, const int* __restrict__ flag)
{
    int m0 = blockIdx.x * 4;
    int tid = threadIdx.x;
    const int fl = *flag;
    __shared__ float aS[4][1536];
    for (int i = tid; i < 4 * 1536; i += 256)
        aS[i / 1536][i % 1536] = concat[(long)(m0 + i / 1536) * 1536 + (i % 1536)];
    __syncthreads();
    int r = tid >> 6;
    int nb = tid & 63;
    int m = m0 + r;
    int b = m / 27, t = m % 27;
    for (int n = nb; n < 97; n += 64) {
        const u16* wp = pW + (long)n * 1536;
        float acc = 0.f;
        for (int k = 0; k < 1536; k++) acc = fmaf(aS[r][k], bf2f(wp[k]), acc);
        acc += bf2f(pb[n]);
        if (t > 0) {
            long o = ((long)(b * 26 + (t - 1))) * 97 + n;
            if (fl) ((float*)out)[o] = acc;
            else    ((u16*)out)[o] = f2bf(acc);
        }
    }
}

// ---------- launch ----------
extern "C" void kernel_launch(void* const* d_in, const int* in_sizes, int n_in,
                              void* d_out, int out_size, void* d_ws, size_t ws_size,
                              hipStream_t stream) {
    (void)in_sizes; (void)n_in; (void)out_size; (void)ws_size;
    const void* feat_r   = d_in[0];
    const int*  label    = (const int*)d_in[1];
    const void* vr_r     = d_in[2];
    const void* e0_Wih_r = d_in[3];
    const void* e0_Whh_r = d_in[4];
    const void* e0_bih_r = d_in[5];
    const void* e0_bhh_r = d_in[6];
    const void* e1_Wih_r = d_in[7];
    const void* e1_Whh_r = d_in[8];
    const void* e1_bih_r = d_in[9];
    const void* e1_bhh_r = d_in[10];
    const void* enc_W_r  = d_in[11];
    const void* enc_b_r  = d_in[12];
    const void* q_W_r    = d_in[13];
    const void* q_b_r    = d_in[14];
    const void* k_W_r    = d_in[15];
    const void* k_b_r    = d_in[16];
    const void* s_W_r    = d_in[17];
    const void* s_b_r    = d_in[18];
    const void* emb_r    = d_in[19];
    const void* d0_Wih_r = d_in[20];
    const void* d0_Whh_r = d_in[21];
    const void* d0_bih_r = d_in[22];
    const void* d0_bhh_r = d_in[23];
    const void* d1_Wih_r = d_in[24];
    const void* d1_Whh_r = d_in[25];
    const void* d1_bih_r = d_in[26];
    const void* d1_bhh_r = d_in[27];
    const void* pred_W_r = d_in[28];
    const void* pred_b_r = d_in[29];

    char* w = (char*)d_ws;
    size_t off = 0;
    auto alloc = [&](size_t bytes) -> void* {
        void* p = w + off;
        off = (off + bytes + 63) & ~(size_t)63;
        return p;
    };
    int*   flag    = (int*)  alloc(4);
    int*   bar     = (int*)  alloc(128 * 4);          // 4 layers x 32 batch counters
    unsigned* hEx  = (unsigned*)alloc(2 * 32 * 256 * 4);
    u16*   fc      = (u16*)  alloc(3932160ull * 2);
    u16*   cW[4];
    for (int i = 0; i < 4; i++) cW[i] = (u16*)alloc(1048576ull * 2);
    u16*   cb[8];
    for (int i = 0; i < 8; i++) cb[i] = (u16*)alloc(2048ull * 2);
    u16*   cencW   = (u16*)  alloc(262144ull * 2);
    u16*   cqW     = (u16*)  alloc(262144ull * 2);
    u16*   cpredW  = (u16*)  alloc(148992ull * 2);
    u16*   cemb    = (u16*)  alloc(49664ull * 2);
    u16*   cencb   = (u16*)  alloc(512ull * 2);
    u16*   cqb     = (u16*)  alloc(512ull * 2);
    u16*   ckb     = (u16*)  alloc(512ull * 2);
    u16*   csW     = (u16*)  alloc(512ull * 2);
    u16*   csb     = (u16*)  alloc(2);
    u16*   cpredb  = (u16*)  alloc(97ull * 2);
    float* cvr     = (float*)alloc(32ull * 4);
    u16*   featv   = (u16*)  alloc(655360ull * 2);
    float* xpre    = (float*)alloc(2621440ull * 4);   // (1280,2048) f32; kmap aliases later
    u16*   seq0    = (u16*)  alloc(655360ull * 2);
    u16*   seq1    = (u16*)  alloc(655360ull * 2);
    u16*   tok     = (u16*)  alloc(442368ull * 2);
    u16*   seqd0   = (u16*)  alloc(442368ull * 2);
    u16*   Hid     = (u16*)  alloc(442368ull * 2);
    float* holf    = (float*)alloc(16384ull * 4);
    float* qf      = (float*)alloc(442368ull * 4);
    u16*   featP   = (u16*)  alloc(5505024ull * 2);
    u16*   W2      = (u16*)  alloc(2359296ull * 2);
    float* aw      = (float*)alloc(207360ull * 4);
    float* concat  = (float*)alloc(1327104ull * 4);
    _Float16* Wq[4];
    for (int i = 0; i < 4; i++) Wq[i] = (_Float16*)alloc(1048576ull * 2);
    u16*   kmap    = (u16*)xpre;                       // alias: xpre dead before conv_gemm

    // ---- dtype sniff + canonicalize ----
    sniff_k<<<dim3(1), 64, 0, stream>>>(feat_r, flag);
    init_bar_k<<<dim3(1), 128, 0, stream>>>(bar);
    auto canon = [&](const void* src, u16* dst, int n) {
        canon_k<<<dim3((n + 255) / 256), 256, 0, stream>>>(src, dst, n, flag);
    };
    canon(feat_r, fc, 3932160);
    canon(e0_Wih_r, cW[0], 1048576); canon(e1_Wih_r, cW[1], 1048576);
    canon(d0_Wih_r, cW[2], 1048576); canon(d1_Wih_r, cW[3], 1048576);
    canon(e0_bih_r, cb[0], 2048); canon(e0_bhh_r, cb[1], 2048);
    canon(e1_bih_r, cb[2], 2048); canon(e1_bhh_r, cb[3], 2048);
    canon(d0_bih_r, cb[4], 2048); canon(d0_bhh_r, cb[5], 2048);
    canon(d1_bih_r, cb[6], 2048); canon(d1_bhh_r, cb[7], 2048);
    canon(enc_W_r, cencW, 262144); canon(enc_b_r, cencb, 512);
    canon(q_W_r, cqW, 262144); canon(q_b_r, cqb, 512);
    canon(k_b_r, ckb, 512); canon(s_W_r, csW, 512); canon(s_b_r, csb, 1);
    canon(emb_r, cemb, 49664);
    canon(pred_W_r, cpredW, 148992); canon(pred_b_r, cpredb, 97);
    canonf_k<<<dim3(1), 64, 0, stream>>>(vr_r, cvr, 32, flag);
    w2_k<<<dim3(9216), 256, 0, stream>>>(k_W_r, W2, flag);
    wq3_k<<<dim3(512), 256, 0, stream>>>(e0_Whh_r, Wq[0], flag);
    wq3_k<<<dim3(512), 256, 0, stream>>>(e1_Whh_r, Wq[1], flag);
    wq3_k<<<dim3(512), 256, 0, stream>>>(d0_Whh_r, Wq[2], flag);
    wq3_k<<<dim3(512), 256, 0, stream>>>(d1_Whh_r, Wq[3], flag);

    // ---- prep ----
    featv_k  <<<dim3(2560), 256, 0, stream>>>(fc, featv);
    padfeat_k<<<dim3(21504), 256, 0, stream>>>(fc, featP);

    // ---- encoder ----
    gemm_nt_f32<<<dim3(32, 20), 256, 0, stream>>>(featv, 512, cW[0], cb[0], cb[1], xpre, 1280, 2048, 512, 2048);
    lstm_sync<<<dim3(256), 512, 0, stream>>>(xpre, Wq[0], seq0, nullptr, hEx, bar + 0, 40, 0);
    gemm_nt_f32<<<dim3(32, 20), 256, 0, stream>>>(seq0, 512, cW[1], cb[2], cb[3], xpre, 1280, 2048, 512, 2048);
    lstm_sync<<<dim3(256), 512, 0, stream>>>(xpre, Wq[1], seq1, nullptr, hEx, bar + 32, 40, 0);
    gemm_nt_f32<<<dim3(8, 1), 256, 0, stream>>>(seq1 + 39 * 512, 40 * 512, cencW, cencb, nullptr, holf, 32, 512, 512, 512);

    // ---- decoder ----
    tok_k<<<dim3(1728), 256, 0, stream>>>(holf, cemb, label, tok);
    gemm_nt_f32<<<dim3(32, 14), 256, 0, stream>>>(tok, 512, cW[2], cb[4], cb[5], xpre, 864, 2048, 512, 2048);
    lstm_sync<<<dim3(256), 512, 0, stream>>>(xpre, Wq[2], seqd0, nullptr, hEx, bar + 64, 27, 0);
    gemm_nt_f32<<<dim3(32, 14), 256, 0, stream>>>(seqd0, 512, cW[3], cb[6], cb[7], xpre, 864, 2048, 512, 2048);
    lstm_sync<<<dim3(256), 512, 0, stream>>>(xpre, Wq[3], Hid, concat, hEx, bar + 96, 27, 1536);

    // ---- attention (xpre dead from here; kmap aliases it) ----
    gemm_nt_f32<<<dim3(8, 14), 256, 0, stream>>>(Hid, 512, cqW, cqb, nullptr, qf, 864, 512, 512, 512);
    conv_gemm<<<dim3(8, 120), 256, 0, stream>>>(featP, W2, ckb, kmap);
    score_k<<<dim3(864), 256, 0, stream>>>(qf, kmap, csW, csb, cvr, aw);
    attn_k<<<dim3(256), 256, 0, stream>>>(fc, aw, concat);
    holfill_k<<<dim3(1728), 256, 0, stream>>>(holf, concat);

    // ---- prediction ----
    pred_k<<<dim3(216), 256, 0, stream>>>(concat, cpredW, cpredb, d_out, flag);
}

// Round 4
// 5823.391 us; speedup vs baseline: 1.0178x; 1.0178x over previous
//
#include <hip/hip_runtime.h>

typedef unsigned short u16;
typedef __attribute__((ext_vector_type(8))) short short8;
typedef __attribute__((ext_vector_type(4))) float floatx4;
typedef _Float16 half8 __attribute__((ext_vector_type(8)));
typedef _Float16 half2v __attribute__((ext_vector_type(2)));

#define AGENT __HIP_MEMORY_SCOPE_AGENT

// ---------- helpers ----------
__device__ __forceinline__ float bf2f(u16 v) { return __uint_as_float(((unsigned)v) << 16); }
__device__ __forceinline__ u16 f2bf(float f) {
    unsigned u = __float_as_uint(f);
    unsigned r = (u + 0x7FFFu + ((u >> 16) & 1u)) >> 16;
    return (u16)r;
}
__device__ __forceinline__ float sigm_(float x) { return 1.f / (1.f + __expf(-x)); }
__device__ __forceinline__ float tanh_(float x) {
    x = fminf(fmaxf(x, -15.f), 15.f);
    float e = __expf(2.f * x);
    return (e - 1.f) / (e + 1.f);
}

// B=32, C=512, H=6, W=40, NC=97, L=26, T=27

// ---------- dtype sniffing: flag=1 if inputs are fp32, 0 if bf16 ----------
__global__ void sniff_k(const void* __restrict__ feat_raw, int* __restrict__ flag) {
    if (threadIdx.x == 0 && blockIdx.x == 0) {
        const u16* p = (const u16*)feat_raw;
        int insane = 0;
        #pragma unroll
        for (int i = 0; i < 32; i += 2) {
            float x = bf2f(p[i]);
            float a = fabsf(x);
            if (!(a <= 1000.f)) insane = 1;
            if (x != 0.f && a < 1e-8f) insane = 1;
        }
        *flag = insane;
    }
}

__global__ void init_bar_k(int* __restrict__ bar) {
    bar[threadIdx.x] = 0;
}

// ---------- one-shot canonicalization of all weight tensors into one bf16 region ----------
struct SrcPtrs {
    const void* e0Wih; const void* e1Wih; const void* d0Wih; const void* d1Wih;
    const void* b0; const void* b1; const void* b2; const void* b3;
    const void* b4; const void* b5; const void* b6; const void* b7;
    const void* encW; const void* qW; const void* predW; const void* emb;
    const void* encb; const void* qb; const void* kb; const void* sW;
    const void* sb; const void* predb;
};
// region layout (element offsets)
#define OFF_W0      0
#define OFF_W1      1048576
#define OFF_W2      2097152
#define OFF_W3      3145728
#define OFF_B       4194304     // 8 x 2048
#define OFF_ENCW    4210688
#define OFF_QW      4472832
#define OFF_PREDW   4734976
#define OFF_EMB     4883968
#define OFF_ENCB    4933632
#define OFF_QB      4934144
#define OFF_KB      4934656
#define OFF_SW      4935168
#define OFF_SB      4935680
#define OFF_PREDB   4935681
#define CANON_TOTAL 4935778

__global__ __launch_bounds__(256) void canon_all(SrcPtrs S, u16* __restrict__ dst,
                                                 const int* __restrict__ flag) {
    int idx = blockIdx.x * 256 + threadIdx.x;
    if (idx >= CANON_TOTAL) return;
    const void* s; int loc;
    if (idx < OFF_B) {                      // 4 x 2^20 Wih
        int k = idx >> 20; loc = idx & 1048575;
        s = (k == 0) ? S.e0Wih : (k == 1) ? S.e1Wih : (k == 2) ? S.d0Wih : S.d1Wih;
    } else if (idx < OFF_ENCW) {            // 8 x 2^11 biases
        int r = idx - OFF_B; int k = r >> 11; loc = r & 2047;
        s = (k == 0) ? S.b0 : (k == 1) ? S.b1 : (k == 2) ? S.b2 : (k == 3) ? S.b3
          : (k == 4) ? S.b4 : (k == 5) ? S.b5 : (k == 6) ? S.b6 : S.b7;
    } else if (idx < OFF_QW)    { s = S.encW;  loc = idx - OFF_ENCW; }
    else if (idx < OFF_PREDW)   { s = S.qW;    loc = idx - OFF_QW; }
    else if (idx < OFF_EMB)     { s = S.predW; loc = idx - OFF_PREDW; }
    else if (idx < OFF_ENCB)    { s = S.emb;   loc = idx - OFF_EMB; }
    else if (idx < OFF_QB)      { s = S.encb;  loc = idx - OFF_ENCB; }
    else if (idx < OFF_KB)      { s = S.qb;    loc = idx - OFF_QB; }
    else if (idx < OFF_SW)      { s = S.kb;    loc = idx - OFF_KB; }
    else if (idx < OFF_SB)      { s = S.sW;    loc = idx - OFF_SW; }
    else if (idx < OFF_PREDB)   { s = S.sb;    loc = idx - OFF_SB; }
    else                        { s = S.predb; loc = idx - OFF_PREDB; }
    dst[idx] = (*flag) ? f2bf(((const float*)s)[loc]) : ((const u16*)s)[loc];
}

// canonical fp32 copy (for valid_ratios: exact mask arithmetic)
__global__ __launch_bounds__(64) void canonf_k(const void* __restrict__ src, float* __restrict__ dst,
                                               int n, const int* __restrict__ flag) {
    int i = blockIdx.x * 64 + threadIdx.x;
    if (i >= n) return;
    dst[i] = (*flag) ? ((const float*)src)[i] : bf2f(((const u16*)src)[i]);
}

// ---------- prep kernels (read raw feat, dtype-aware) ----------

__device__ __forceinline__ float rdf(const void* p, long i, int fl) {
    return fl ? ((const float*)p)[i] : bf2f(((const u16*)p)[i]);
}

// feat (B,C,6,40) raw -> featv (B,40,C) bf16 (max over H)
__global__ __launch_bounds__(256) void featv_k(const void* __restrict__ feat, u16* __restrict__ featv,
                                               const int* __restrict__ flag) {
    const int fl = *flag;
    int idx = blockIdx.x * 256 + threadIdx.x;
    int c = idx & 511;
    int r = idx >> 9;
    int w = r % 40, b = r / 40;
    float mx = -1e30f;
    long base = ((long)(b * 512 + c) * 6) * 40 + w;
    #pragma unroll
    for (int h = 0; h < 6; h++) mx = fmaxf(mx, rdf(feat, base + h * 40, fl));
    featv[idx] = f2bf(mx);
}

// feat (B,C,6,40) raw -> featP (B,8,42,C) bf16 zero-padded NHWC
__global__ __launch_bounds__(256) void padfeat_k(const void* __restrict__ feat, u16* __restrict__ featP,
                                                 const int* __restrict__ flag) {
    const int fl = *flag;
    int idx = blockIdx.x * 256 + threadIdx.x;
    int c = idx & 511;
    int r = idx >> 9;
    int wp = r % 42; int r2 = r / 42;
    int hp = r2 & 7; int b = r2 >> 3;
    u16 v = 0;
    if (hp >= 1 && hp <= 6 && wp >= 1 && wp <= 40) {
        long si = ((long)(b * 512 + c) * 6 + (hp - 1)) * 40 + (wp - 1);
        v = fl ? f2bf(((const float*)feat)[si]) : ((const u16*)feat)[si];
    }
    featP[idx] = v;
}

// k_W (Co,Ci,3,3) raw -> W2 (Co, (kh*3+kw)*512+ci) bf16
__global__ __launch_bounds__(256) void w2_k(const void* __restrict__ kW, u16* __restrict__ W2,
                                            const int* __restrict__ flag) {
    int idx = blockIdx.x * 256 + threadIdx.x;
    int co = idx / 4608;
    int r = idx % 4608;
    int kh = r / 1536;
    int r2 = r % 1536;
    int kw = r2 / 512;
    int ci = r2 & 511;
    long si = ((long)(co * 512 + ci) * 3 + kh) * 3 + kw;
    W2[idx] = (*flag) ? f2bf(((const float*)kW)[si]) : ((const u16*)kW)[si];
}

// 4x Whh (2048,512) raw -> Wq3 f16 for lstm_sync (all four layers, one launch).
// flat o = (((j*32 + c)*512 + t)*8 + jj); thread t: rid=t>>1, hf=t&1;
// n = (rid>>6)*512 + j*64 + (rid&63); k = hf*256 + c*8 + jj
__global__ __launch_bounds__(256) void wq3_all(
    const void* __restrict__ s0, const void* __restrict__ s1,
    const void* __restrict__ s2, const void* __restrict__ s3,
    _Float16* __restrict__ d0, _Float16* __restrict__ d1,
    _Float16* __restrict__ d2, _Float16* __restrict__ d3,
    const int* __restrict__ flag)
{
    int gb = blockIdx.x;
    int id = gb >> 9;
    const void* W = (id == 0) ? s0 : (id == 1) ? s1 : (id == 2) ? s2 : s3;
    _Float16* D = (id == 0) ? d0 : (id == 1) ? d1 : (id == 2) ? d2 : d3;
    int o = (gb & 511) * 256 + threadIdx.x;
    int t = o & 511;
    int c = (o >> 9) & 31;
    int j = o >> 14;
    int rid = t >> 1, hf = t & 1;
    int n = (rid >> 6) * 512 + j * 64 + (rid & 63);
    int k = hf * 256 + c * 8;
    int fl = *flag;
    _Float16* dst = D + (long)o * 8;
    #pragma unroll
    for (int jj = 0; jj < 8; jj++) {
        long si = (long)n * 512 + k + jj;
        float v = fl ? ((const float*)W)[si] : bf2f(((const u16*)W)[si]);
        dst[jj] = (_Float16)v;
    }
}

// ---------- NT GEMM: C(MxN,f32) = A(MxK,bf16,lda) * B(NxK,bf16)^T + bias ----------
__global__ __launch_bounds__(256) void gemm_nt_f32(
    const u16* __restrict__ A, int lda,
    const u16* __restrict__ Bw,
    const u16* __restrict__ bias0, const u16* __restrict__ bias1,
    float* __restrict__ C, int M, int N, int K, int ldc)
{
    __shared__ __align__(16) u16 As[64][40];
    __shared__ __align__(16) u16 Bs[64][40];
    const int tid = threadIdx.x;
    const int bn = blockIdx.x, bm = blockIdx.y;
    const int l = tid & 63, wid = tid >> 6;
    const int wm = wid >> 1, wn = wid & 1;
    const int lr = tid >> 2, lc = (tid & 3) * 8;
    const int l15 = l & 15, lq = l >> 4;

    floatx4 acc00 = (floatx4)(0.f), acc01 = (floatx4)(0.f), acc10 = (floatx4)(0.f), acc11 = (floatx4)(0.f);

    int am = bm * 64 + lr; if (am > M - 1) am = M - 1;
    const u16* Ap = A + (long)am * lda + lc;
    const u16* Bp = Bw + (long)(bn * 64 + lr) * K + lc;

    for (int k0 = 0; k0 < K; k0 += 32) {
        *(short8*)&As[lr][lc] = *(const short8*)(Ap + k0);
        *(short8*)&Bs[lr][lc] = *(const short8*)(Bp + k0);
        __syncthreads();
        short8 af0 = *(const short8*)&As[wm * 32 + l15][lq * 8];
        short8 af1 = *(const short8*)&As[wm * 32 + 16 + l15][lq * 8];
        short8 bf0 = *(const short8*)&Bs[wn * 32 + l15][lq * 8];
        short8 bf1 = *(const short8*)&Bs[wn * 32 + 16 + l15][lq * 8];
        acc00 = __builtin_amdgcn_mfma_f32_16x16x32_bf16(af0, bf0, acc00, 0, 0, 0);
        acc01 = __builtin_amdgcn_mfma_f32_16x16x32_bf16(af0, bf1, acc01, 0, 0, 0);
        acc10 = __builtin_amdgcn_mfma_f32_16x16x32_bf16(af1, bf0, acc10, 0, 0, 0);
        acc11 = __builtin_amdgcn_mfma_f32_16x16x32_bf16(af1, bf1, acc11, 0, 0, 0);
        __syncthreads();
    }
    floatx4 accs[2][2] = {{acc00, acc01}, {acc10, acc11}};
    #pragma unroll
    for (int i = 0; i < 2; i++)
        #pragma unroll
        for (int j = 0; j < 2; j++)
            #pragma unroll
            for (int r = 0; r < 4; r++) {
                int gm = bm * 64 + wm * 32 + i * 16 + lq * 4 + r;
                int gn = bn * 64 + wn * 32 + j * 16 + l15;
                if (gm < M) {
                    float v = accs[i][j][r];
                    if (bias0) v += bf2f(bias0[gn]);
                    if (bias1) v += bf2f(bias1[gn]);
                    C[(long)gm * ldc + gn] = v;
                }
            }
}

// ---------- conv3x3 as implicit-im2col NT GEMM: out kmap (B*240, 512) bf16 ----------
__global__ __launch_bounds__(256) void conv_gemm(
    const u16* __restrict__ featP, const u16* __restrict__ W2,
    const u16* __restrict__ kb, u16* __restrict__ kmap)
{
    __shared__ __align__(16) u16 As[64][40];
    __shared__ __align__(16) u16 Bs[64][40];
    const int tid = threadIdx.x;
    const int bn = blockIdx.x, bm = blockIdx.y;
    const int l = tid & 63, wid = tid >> 6;
    const int wm = wid >> 1, wn = wid & 1;
    const int lr = tid >> 2, lc = (tid & 3) * 8;
    const int l15 = l & 15, lq = l >> 4;

    floatx4 acc00 = (floatx4)(0.f), acc01 = (floatx4)(0.f), acc10 = (floatx4)(0.f), acc11 = (floatx4)(0.f);

    int gm = bm * 64 + lr;
    int b = gm / 240;
    int hw = gm % 240;
    int h = hw / 40, w = hw % 40;
    const u16* fb = featP + (long)(b * 8) * 42 * 512;
    const u16* Bp = W2 + (long)(bn * 64 + lr) * 4608 + lc;

    for (int k0 = 0; k0 < 4608; k0 += 32) {
        int kh = k0 / 1536;
        int kw = (k0 % 1536) / 512;
        int ci0 = k0 & 511;
        const u16* ap = fb + ((long)((h + kh) * 42 + (w + kw))) * 512 + ci0 + lc;
        *(short8*)&As[lr][lc] = *(const short8*)ap;
        *(short8*)&Bs[lr][lc] = *(const short8*)(Bp + k0);
        __syncthreads();
        short8 af0 = *(const short8*)&As[wm * 32 + l15][lq * 8];
        short8 af1 = *(const short8*)&As[wm * 32 + 16 + l15][lq * 8];
        short8 bf0 = *(const short8*)&Bs[wn * 32 + l15][lq * 8];
        short8 bf1 = *(const short8*)&Bs[wn * 32 + 16 + l15][lq * 8];
        acc00 = __builtin_amdgcn_mfma_f32_16x16x32_bf16(af0, bf0, acc00, 0, 0, 0);
        acc01 = __builtin_amdgcn_mfma_f32_16x16x32_bf16(af0, bf1, acc01, 0, 0, 0);
        acc10 = __builtin_amdgcn_mfma_f32_16x16x32_bf16(af1, bf0, acc10, 0, 0, 0);
        acc11 = __builtin_amdgcn_mfma_f32_16x16x32_bf16(af1, bf1, acc11, 0, 0, 0);
        __syncthreads();
    }
    floatx4 accs[2][2] = {{acc00, acc01}, {acc10, acc11}};
    #pragma unroll
    for (int i = 0; i < 2; i++)
        #pragma unroll
        for (int j = 0; j < 2; j++)
            #pragma unroll
            for (int r = 0; r < 4; r++) {
                int om = bm * 64 + wm * 32 + i * 16 + lq * 4 + r;
                int on = bn * 64 + wn * 32 + j * 16 + l15;
                float v = accs[i][j][r] + bf2f(kb[on]);
                kmap[(long)om * 512 + on] = f2bf(v);
            }
}

// ---------- LSTM recurrence, weight-in-register multi-block version ----------
// 256 blocks: XCD-swizzled so the 8 slice-blocks of a batch share one XCD's L2
// (speed heuristic only; co-residency = 1 block/CU holds for any mapping).
// 512 threads: rid=tid>>1 (gate-row: gate=rid>>6, unit=rid&63), hf=tid&1 (k half).
// Weights held as 32 named half8 SSA values (128 VGPRs) — no array, no SROA.
#define WL(F) F(0) F(1) F(2) F(3) F(4) F(5) F(6) F(7) F(8) F(9) F(10) F(11) F(12) F(13) F(14) F(15) \
              F(16) F(17) F(18) F(19) F(20) F(21) F(22) F(23) F(24) F(25) F(26) F(27) F(28) F(29) F(30) F(31)
#define WDECL(i) half8 w##i = wp8[(long)(j * 32 + i) * 512 + tid];
#define DOTC(i) { \
    half8 hv = *(const half8*)&hS2[(hf * 2 + (i / 16)) * 136 + (i % 16) * 8]; \
    a = __builtin_amdgcn_fdot2(__builtin_shufflevector(hv, hv, 0, 1), __builtin_shufflevector(w##i, w##i, 0, 1), a, false); \
    a = __builtin_amdgcn_fdot2(__builtin_shufflevector(hv, hv, 2, 3), __builtin_shufflevector(w##i, w##i, 2, 3), a, false); \
    a = __builtin_amdgcn_fdot2(__builtin_shufflevector(hv, hv, 4, 5), __builtin_shufflevector(w##i, w##i, 4, 5), a, false); \
    a = __builtin_amdgcn_fdot2(__builtin_shufflevector(hv, hv, 6, 7), __builtin_shufflevector(w##i, w##i, 6, 7), a, false); }

__global__ __launch_bounds__(512, 2) void lstm_sync(
    const float* __restrict__ xpre, const _Float16* __restrict__ Wq3,
    u16* __restrict__ seq_out, float* __restrict__ f32_out,
    unsigned* __restrict__ hEx, int* __restrict__ bar,
    int T, int f32_ld)
{
    // XCD swizzle: blockIdx i -> xcd = i&7 (round-robin dispatch heuristic);
    // batch b = xcd*4 + (slot&3), slice j = slot>>2  => all j of b on one XCD.
    const int i_ = blockIdx.x;
    const int slot = i_ >> 3;
    const int b = (i_ & 7) * 4 + (slot & 3);
    const int j = slot >> 2;
    const int tid = threadIdx.x;
    const int hf = tid & 1;

    __shared__ __align__(16) _Float16 hS2[4 * 136];
    __shared__ float part[512];
    __shared__ _Float16 hLoc[64];

    const half8* wp8 = (const half8*)Wq3;
    WL(WDECL)                       // 32 named half8 = 128 VGPRs, SSA-guaranteed
    float cst = 0.f;

    for (int t = 0; t < T; t++) {
        float a = 0.f;
        if (t > 0) {
            if (tid == 0) {
                const int target = 8 * t;
                while (__hip_atomic_load(bar + b, __ATOMIC_ACQUIRE, AGENT) < target)
                    __builtin_amdgcn_s_sleep(2);
            }
            __syncthreads();
            if (tid < 256) {
                unsigned v = __hip_atomic_load(
                    &hEx[(((t - 1) & 1) * 32 + b) * 256 + tid], __ATOMIC_RELAXED, AGENT);
                int k = tid * 2;
                *(unsigned*)&hS2[(k >> 7) * 136 + (k & 127)] = v;
            }
            __syncthreads();
            WL(DOTC)
        }
        part[tid] = a;
        __syncthreads();
        if (tid < 64) {
            const float* xp = xpre + ((long)b * T + t) * 2048;
            int w = tid;
            float gi = xp[j * 64 + w]        + part[(0   + w) * 2] + part[(0   + w) * 2 + 1];
            float gf = xp[512 + j * 64 + w]  + part[(64  + w) * 2] + part[(64  + w) * 2 + 1];
            float gg = xp[1024 + j * 64 + w] + part[(128 + w) * 2] + part[(128 + w) * 2 + 1];
            float go = xp[1536 + j * 64 + w] + part[(192 + w) * 2] + part[(192 + w) * 2 + 1];
            cst = sigm_(gf) * cst + sigm_(gi) * tanh_(gg);
            float h = sigm_(go) * tanh_(cst);
            hLoc[w] = (_Float16)h;
            long so = ((long)b * T + t) * 512 + j * 64 + w;
            seq_out[so] = f2bf(h);
            if (f32_out) f32_out[((long)b * T + t) * f32_ld + j * 64 + w] = h;
        }
        __syncthreads();
        if (tid < 32) {
            half2v hp2 = *(const half2v*)&hLoc[2 * tid];
            unsigned v = *(const unsigned*)&hp2;
            __hip_atomic_store(&hEx[((t & 1) * 32 + b) * 256 + j * 32 + tid], v,
                               __ATOMIC_RELAXED, AGENT);
        }
        __threadfence();
        __syncthreads();
        if (tid == 0)
            __hip_atomic_fetch_add(bar + b, 1, __ATOMIC_RELEASE, AGENT);
    }
}

// ---------- token build: tok (B,27,512) bf16 ----------
__global__ __launch_bounds__(256) void tok_k(
    const float* __restrict__ holf, const u16* __restrict__ cemb,
    const int* __restrict__ label, u16* __restrict__ tok)
{
    int idx = blockIdx.x * 256 + threadIdx.x;
    int c = idx & 511;
    int m = idx >> 9;
    int b = m / 27, t = m % 27;
    float v;
    if (t == 0) v = holf[(long)b * 512 + c];
    else v = bf2f(cemb[(long)label[b * 26 + (t - 1)] * 512 + c]);
    tok[idx] = f2bf(v);
}

// ---------- fused score: tanh-dot + mask + softmax -> aw (B,27,240) f32 ----------
__global__ __launch_bounds__(256) void score_k(
    const float* __restrict__ q, const u16* __restrict__ kmap,
    const u16* __restrict__ sW, const u16* __restrict__ sb,
    const float* __restrict__ vr, float* __restrict__ aw)
{
    int bt = blockIdx.x;
    int b = bt / 27;
    int tid = threadIdx.x;
    __shared__ float qs[512];
    __shared__ float ss[512];
    __shared__ float red[256];
    qs[tid] = q[(long)bt * 512 + tid];
    qs[tid + 256] = q[(long)bt * 512 + tid + 256];
    ss[tid] = bf2f(sW[tid]);
    ss[tid + 256] = bf2f(sW[tid + 256]);
    __syncthreads();
    float sc = -INFINITY;
    float ex = 0.f;
    if (tid < 240) {
        const u16* kp = kmap + ((long)b * 240 + tid) * 512;
        float acc = 0.f;
        for (int c = 0; c < 512; c++) {
            float x = bf2f(kp[c]) + qs[c];
            acc = fmaf(ss[c], tanh_(x), acc);
        }
        acc += bf2f(sb[0]);
        float r = vr[b];
        int vw = (int)ceilf(40.f * r);
        if (vw > 40) vw = 40;
        int wcol = tid % 40;
        sc = (wcol >= vw) ? -INFINITY : acc;
    }
    red[tid] = sc;
    __syncthreads();
    for (int s = 128; s > 0; s >>= 1) {
        if (tid < s) red[tid] = fmaxf(red[tid], red[tid + s]);
        __syncthreads();
    }
    float mx = red[0];
    __syncthreads();
    if (tid < 240) ex = (sc == -INFINITY) ? 0.f : __expf(sc - mx);
    red[tid] = ex;
    __syncthreads();
    for (int s = 128; s > 0; s >>= 1) {
        if (tid < s) red[tid] += red[tid + s];
        __syncthreads();
    }
    float inv = 1.f / red[0];
    if (tid < 240) aw[(long)bt * 240 + tid] = ex * inv;
}

// ---------- attn_feat -> concat cols [512,1024) f32 (raw feat, dtype-aware) ----------
__global__ __launch_bounds__(256) void attn_k(
    const void* __restrict__ feat, const float* __restrict__ aw,
    float* __restrict__ concat, const int* __restrict__ flag)
{
    const int fl = *flag;
    int b = blockIdx.x >> 3;
    int cc = (blockIdx.x & 7) * 64;
    int tid = threadIdx.x;
    __shared__ float awS[27 * 240];
    __shared__ u16 fS[64 * 240];
    for (int i = tid; i < 27 * 240; i += 256) awS[i] = aw[(long)b * 27 * 240 + i];
    long fbase = ((long)b * 512 + cc) * 240;
    for (int i = tid; i < 64 * 240; i += 256)
        fS[i] = fl ? f2bf(((const float*)feat)[fbase + i]) : ((const u16*)feat)[fbase + i];
    __syncthreads();
    for (int item = tid; item < 64 * 27; item += 256) {
        int c = item / 27, t = item % 27;
        const u16* fp = &fS[c * 240];
        const float* ap = &awS[t * 240];
        float acc = 0.f;
        for (int hw = 0; hw < 240; hw++) acc = fmaf(bf2f(fp[hw]), ap[hw], acc);
        concat[((long)(b * 27 + t)) * 1536 + 512 + cc + c] = acc;
    }
}

// ---------- holistic broadcast -> concat cols [1024,1536) ----------
__global__ __launch_bounds__(256) void holfill_k(const float* __restrict__ holf, float* __restrict__ concat) {
    int idx = blockIdx.x * 256 + threadIdx.x;
    int c = idx & 511;
    int m = idx >> 9;
    int b = m / 27;
    concat[(long)m * 1536 + 1024 + c] = holf[(long)b * 512 + c];
}

// ---------- prediction + slice: out (B,26,97), dtype per flag ----------
__global__ __launch_bounds__(256) void pred_k(
    const float* __restrict__ concat, const u16* __restrict__ pW,
    const u16* __restrict__ pb, void* __restrict__ out, const int* __restrict__ flag)
{
    int m0 = blockIdx.x * 4;
    int tid = threadIdx.x;
    const int fl = *flag;
    __shared__ float aS[4][1536];
    for (int i = tid; i < 4 * 1536; i += 256)
        aS[i / 1536][i % 1536] = concat[(long)(m0 + i / 1536) * 1536 + (i % 1536)];
    __syncthreads();
    int r = tid >> 6;
    int nb = tid & 63;
    int m = m0 + r;
    int b = m / 27, t = m % 27;
    for (int n = nb; n < 97; n += 64) {
        const u16* wp = pW + (long)n * 1536;
        float acc = 0.f;
        for (int k = 0; k < 1536; k++) acc = fmaf(aS[r][k], bf2f(wp[k]), acc);
        acc += bf2f(pb[n]);
        if (t > 0) {
            long o = ((long)(b * 26 + (t - 1))) * 97 + n;
            if (fl) ((float*)out)[o] = acc;
            else    ((u16*)out)[o] = f2bf(acc);
        }
    }
}

// ---------- launch ----------
extern "C" void kernel_launch(void* const* d_in, const int* in_sizes, int n_in,
                              void* d_out, int out_size, void* d_ws, size_t ws_size,
                              hipStream_t stream) {
    (void)in_sizes; (void)n_in; (void)out_size; (void)ws_size;
    const void* feat_r = d_in[0];
    const int*  label  = (const int*)d_in[1];
    const void* vr_r   = d_in[2];

    char* w = (char*)d_ws;
    size_t off = 0;
    auto alloc = [&](size_t bytes) -> void* {
        void* p = w + off;
        off = (off + bytes + 63) & ~(size_t)63;
        return p;
    };
    int*   flag    = (int*)  alloc(4);
    int*   bar     = (int*)  alloc(128 * 4);
    unsigned* hEx  = (unsigned*)alloc(2 * 32 * 256 * 4);
    u16*   canon   = (u16*)  alloc((size_t)CANON_TOTAL * 2);
    float* cvr     = (float*)alloc(32ull * 4);
    u16*   featv   = (u16*)  alloc(655360ull * 2);
    float* xpre    = (float*)alloc(2621440ull * 4);   // kmap aliases after LSTMs
    u16*   seq0    = (u16*)  alloc(655360ull * 2);
    u16*   seq1    = (u16*)  alloc(655360ull * 2);
    u16*   tok     = (u16*)  alloc(442368ull * 2);
    u16*   seqd0   = (u16*)  alloc(442368ull * 2);
    u16*   Hid     = (u16*)  alloc(442368ull * 2);
    float* holf    = (float*)alloc(16384ull * 4);
    float* qf      = (float*)alloc(442368ull * 4);
    u16*   featP   = (u16*)  alloc(5505024ull * 2);
    u16*   W2      = (u16*)  alloc(2359296ull * 2);
    float* aw      = (float*)alloc(207360ull * 4);
    float* concat  = (float*)alloc(1327104ull * 4);
    _Float16* Wq[4];
    for (int i = 0; i < 4; i++) Wq[i] = (_Float16*)alloc(1048576ull * 2);
    u16*   kmap    = (u16*)xpre;

    u16* cW0    = canon + OFF_W0;
    u16* cW1    = canon + OFF_W1;
    u16* cW2    = canon + OFF_W2;
    u16* cW3    = canon + OFF_W3;
    u16* cb0    = canon + OFF_B;           // e0_bih, e0_bhh, e1_bih, e1_bhh, d0_*, d1_*
    u16* cencW  = canon + OFF_ENCW;
    u16* cqW    = canon + OFF_QW;
    u16* cpredW = canon + OFF_PREDW;
    u16* cemb   = canon + OFF_EMB;
    u16* cencb  = canon + OFF_ENCB;
    u16* cqb    = canon + OFF_QB;
    u16* ckb    = canon + OFF_KB;
    u16* csW    = canon + OFF_SW;
    u16* csb    = canon + OFF_SB;
    u16* cpredb = canon + OFF_PREDB;

    // ---- sniff + canonicalize (one launch for all weights) ----
    sniff_k<<<dim3(1), 64, 0, stream>>>(feat_r, flag);
    init_bar_k<<<dim3(1), 128, 0, stream>>>(bar);
    SrcPtrs S;
    S.e0Wih = d_in[3];  S.e1Wih = d_in[7];  S.d0Wih = d_in[20]; S.d1Wih = d_in[24];
    S.b0 = d_in[5];  S.b1 = d_in[6];  S.b2 = d_in[9];  S.b3 = d_in[10];
    S.b4 = d_in[22]; S.b5 = d_in[23]; S.b6 = d_in[26]; S.b7 = d_in[27];
    S.encW = d_in[11]; S.qW = d_in[13]; S.predW = d_in[28]; S.emb = d_in[19];
    S.encb = d_in[12]; S.qb = d_in[14]; S.kb = d_in[16]; S.sW = d_in[17];
    S.sb = d_in[18]; S.predb = d_in[29];
    canon_all<<<dim3((CANON_TOTAL + 255) / 256), 256, 0, stream>>>(S, canon, flag);
    canonf_k<<<dim3(1), 64, 0, stream>>>(vr_r, cvr, 32, flag);
    w2_k<<<dim3(9216), 256, 0, stream>>>(d_in[15], W2, flag);
    wq3_all<<<dim3(2048), 256, 0, stream>>>(d_in[4], d_in[8], d_in[21], d_in[25],
                                            Wq[0], Wq[1], Wq[2], Wq[3], flag);

    // ---- prep ----
    featv_k  <<<dim3(2560), 256, 0, stream>>>(feat_r, featv, flag);
    padfeat_k<<<dim3(21504), 256, 0, stream>>>(feat_r, featP, flag);

    // ---- encoder ----
    gemm_nt_f32<<<dim3(32, 20), 256, 0, stream>>>(featv, 512, cW0, cb0 + 0 * 2048, cb0 + 1 * 2048, xpre, 1280, 2048, 512, 2048);
    lstm_sync<<<dim3(256), 512, 0, stream>>>(xpre, Wq[0], seq0, nullptr, hEx, bar + 0, 40, 0);
    gemm_nt_f32<<<dim3(32, 20), 256, 0, stream>>>(seq0, 512, cW1, cb0 + 2 * 2048, cb0 + 3 * 2048, xpre, 1280, 2048, 512, 2048);
    lstm_sync<<<dim3(256), 512, 0, stream>>>(xpre, Wq[1], seq1, nullptr, hEx, bar + 32, 40, 0);
    gemm_nt_f32<<<dim3(8, 1), 256, 0, stream>>>(seq1 + 39 * 512, 40 * 512, cencW, cencb, nullptr, holf, 32, 512, 512, 512);

    // ---- decoder ----
    tok_k<<<dim3(1728), 256, 0, stream>>>(holf, cemb, label, tok);
    gemm_nt_f32<<<dim3(32, 14), 256, 0, stream>>>(tok, 512, cW2, cb0 + 4 * 2048, cb0 + 5 * 2048, xpre, 864, 2048, 512, 2048);
    lstm_sync<<<dim3(256), 512, 0, stream>>>(xpre, Wq[2], seqd0, nullptr, hEx, bar + 64, 27, 0);
    gemm_nt_f32<<<dim3(32, 14), 256, 0, stream>>>(seqd0, 512, cW3, cb0 + 6 * 2048, cb0 + 7 * 2048, xpre, 864, 2048, 512, 2048);
    lstm_sync<<<dim3(256), 512, 0, stream>>>(xpre, Wq[3], Hid, concat, hEx, bar + 96, 27, 1536);

    // ---- attention (xpre dead; kmap aliases it) ----
    gemm_nt_f32<<<dim3(8, 14), 256, 0, stream>>>(Hid, 512, cqW, cqb, nullptr, qf, 864, 512, 512, 512);
    conv_gemm<<<dim3(8, 120), 256, 0, stream>>>(featP, W2, ckb, kmap);
    score_k<<<dim3(864), 256, 0, stream>>>(qf, kmap, csW, csb, cvr, aw);
    attn_k<<<dim3(256), 256, 0, stream>>>(feat_r, aw, concat, flag);
    holfill_k<<<dim3(1728), 256, 0, stream>>>(holf, concat);

    // ---- prediction ----
    pred_k<<<dim3(216), 256, 0, stream>>>(concat, cpredW, cpredb, d_out, flag);
}

// Round 5
// 2070.460 us; speedup vs baseline: 2.8628x; 2.8126x over previous
//
#include <hip/hip_runtime.h>

typedef unsigned short u16;
typedef __attribute__((ext_vector_type(8))) short short8;
typedef __attribute__((ext_vector_type(4))) float floatx4;
typedef _Float16 half8 __attribute__((ext_vector_type(8)));
typedef _Float16 half2v __attribute__((ext_vector_type(2)));

#define AGENT __HIP_MEMORY_SCOPE_AGENT

// ---------- helpers ----------
__device__ __forceinline__ float bf2f(u16 v) { return __uint_as_float(((unsigned)v) << 16); }
__device__ __forceinline__ u16 f2bf(float f) {
    unsigned u = __float_as_uint(f);
    unsigned r = (u + 0x7FFFu + ((u >> 16) & 1u)) >> 16;
    return (u16)r;
}
__device__ __forceinline__ float sigm_(float x) { return 1.f / (1.f + __expf(-x)); }
__device__ __forceinline__ float tanh_(float x) {
    x = fminf(fmaxf(x, -15.f), 15.f);
    float e = __expf(2.f * x);
    return (e - 1.f) / (e + 1.f);
}

// B=32, C=512, H=6, W=40, NC=97, L=26, T=27

// ---------- dtype sniffing: flag=1 if inputs are fp32, 0 if bf16 ----------
__global__ void sniff_k(const void* __restrict__ feat_raw, int* __restrict__ flag) {
    if (threadIdx.x == 0 && blockIdx.x == 0) {
        const u16* p = (const u16*)feat_raw;
        int insane = 0;
        #pragma unroll
        for (int i = 0; i < 32; i += 2) {
            float x = bf2f(p[i]);
            float a = fabsf(x);
            if (!(a <= 1000.f)) insane = 1;
            if (x != 0.f && a < 1e-8f) insane = 1;
        }
        *flag = insane;
    }
}

__global__ void init_bar_k(int* __restrict__ bar) {
    bar[threadIdx.x] = 0;
}

// ---------- one-shot canonicalization of all weight tensors into one bf16 region ----------
struct SrcPtrs {
    const void* e0Wih; const void* e1Wih; const void* d0Wih; const void* d1Wih;
    const void* b0; const void* b1; const void* b2; const void* b3;
    const void* b4; const void* b5; const void* b6; const void* b7;
    const void* encW; const void* qW; const void* predW; const void* emb;
    const void* encb; const void* qb; const void* kb; const void* sW;
    const void* sb; const void* predb;
};
// region layout (element offsets)
#define OFF_W0      0
#define OFF_W1      1048576
#define OFF_W2      2097152
#define OFF_W3      3145728
#define OFF_B       4194304     // 8 x 2048
#define OFF_ENCW    4210688
#define OFF_QW      4472832
#define OFF_PREDW   4734976
#define OFF_EMB     4883968
#define OFF_ENCB    4933632
#define OFF_QB      4934144
#define OFF_KB      4934656
#define OFF_SW      4935168
#define OFF_SB      4935680
#define OFF_PREDB   4935681
#define CANON_TOTAL 4935778

__global__ __launch_bounds__(256) void canon_all(SrcPtrs S, u16* __restrict__ dst,
                                                 const int* __restrict__ flag) {
    int idx = blockIdx.x * 256 + threadIdx.x;
    if (idx >= CANON_TOTAL) return;
    const void* s; int loc;
    if (idx < OFF_B) {
        int k = idx >> 20; loc = idx & 1048575;
        s = (k == 0) ? S.e0Wih : (k == 1) ? S.e1Wih : (k == 2) ? S.d0Wih : S.d1Wih;
    } else if (idx < OFF_ENCW) {
        int r = idx - OFF_B; int k = r >> 11; loc = r & 2047;
        s = (k == 0) ? S.b0 : (k == 1) ? S.b1 : (k == 2) ? S.b2 : (k == 3) ? S.b3
          : (k == 4) ? S.b4 : (k == 5) ? S.b5 : (k == 6) ? S.b6 : S.b7;
    } else if (idx < OFF_QW)    { s = S.encW;  loc = idx - OFF_ENCW; }
    else if (idx < OFF_PREDW)   { s = S.qW;    loc = idx - OFF_QW; }
    else if (idx < OFF_EMB)     { s = S.predW; loc = idx - OFF_PREDW; }
    else if (idx < OFF_ENCB)    { s = S.emb;   loc = idx - OFF_EMB; }
    else if (idx < OFF_QB)      { s = S.encb;  loc = idx - OFF_ENCB; }
    else if (idx < OFF_KB)      { s = S.qb;    loc = idx - OFF_QB; }
    else if (idx < OFF_SW)      { s = S.kb;    loc = idx - OFF_KB; }
    else if (idx < OFF_SB)      { s = S.sW;    loc = idx - OFF_SW; }
    else if (idx < OFF_PREDB)   { s = S.sb;    loc = idx - OFF_SB; }
    else                        { s = S.predb; loc = idx - OFF_PREDB; }
    dst[idx] = (*flag) ? f2bf(((const float*)s)[loc]) : ((const u16*)s)[loc];
}

// canonical fp32 copy (for valid_ratios: exact mask arithmetic)
__global__ __launch_bounds__(64) void canonf_k(const void* __restrict__ src, float* __restrict__ dst,
                                               int n, const int* __restrict__ flag) {
    int i = blockIdx.x * 64 + threadIdx.x;
    if (i >= n) return;
    dst[i] = (*flag) ? ((const float*)src)[i] : bf2f(((const u16*)src)[i]);
}

// ---------- prep kernels (read raw feat, dtype-aware) ----------

__device__ __forceinline__ float rdf(const void* p, long i, int fl) {
    return fl ? ((const float*)p)[i] : bf2f(((const u16*)p)[i]);
}

// feat (B,C,6,40) raw -> featv (B,40,C) bf16 (max over H)
__global__ __launch_bounds__(256) void featv_k(const void* __restrict__ feat, u16* __restrict__ featv,
                                               const int* __restrict__ flag) {
    const int fl = *flag;
    int idx = blockIdx.x * 256 + threadIdx.x;
    int c = idx & 511;
    int r = idx >> 9;
    int w = r % 40, b = r / 40;
    float mx = -1e30f;
    long base = ((long)(b * 512 + c) * 6) * 40 + w;
    #pragma unroll
    for (int h = 0; h < 6; h++) mx = fmaxf(mx, rdf(feat, base + h * 40, fl));
    featv[idx] = f2bf(mx);
}

// feat (B,C,6,40) raw -> featP (B,8,42,C) bf16 zero-padded NHWC
__global__ __launch_bounds__(256) void padfeat_k(const void* __restrict__ feat, u16* __restrict__ featP,
                                                 const int* __restrict__ flag) {
    const int fl = *flag;
    int idx = blockIdx.x * 256 + threadIdx.x;
    int c = idx & 511;
    int r = idx >> 9;
    int wp = r % 42; int r2 = r / 42;
    int hp = r2 & 7; int b = r2 >> 3;
    u16 v = 0;
    if (hp >= 1 && hp <= 6 && wp >= 1 && wp <= 40) {
        long si = ((long)(b * 512 + c) * 6 + (hp - 1)) * 40 + (wp - 1);
        v = fl ? f2bf(((const float*)feat)[si]) : ((const u16*)feat)[si];
    }
    featP[idx] = v;
}

// k_W (Co,Ci,3,3) raw -> W2 (Co, (kh*3+kw)*512+ci) bf16
__global__ __launch_bounds__(256) void w2_k(const void* __restrict__ kW, u16* __restrict__ W2,
                                            const int* __restrict__ flag) {
    int idx = blockIdx.x * 256 + threadIdx.x;
    int co = idx / 4608;
    int r = idx % 4608;
    int kh = r / 1536;
    int r2 = r % 1536;
    int kw = r2 / 512;
    int ci = r2 & 511;
    long si = ((long)(co * 512 + ci) * 3 + kh) * 3 + kw;
    W2[idx] = (*flag) ? f2bf(((const float*)kW)[si]) : ((const u16*)kW)[si];
}

// 4x Whh (2048,512) raw -> Wq3 f16 for lstm_sync (all four layers, one launch).
__global__ __launch_bounds__(256) void wq3_all(
    const void* __restrict__ s0, const void* __restrict__ s1,
    const void* __restrict__ s2, const void* __restrict__ s3,
    _Float16* __restrict__ d0, _Float16* __restrict__ d1,
    _Float16* __restrict__ d2, _Float16* __restrict__ d3,
    const int* __restrict__ flag)
{
    int gb = blockIdx.x;
    int id = gb >> 9;
    const void* W = (id == 0) ? s0 : (id == 1) ? s1 : (id == 2) ? s2 : s3;
    _Float16* D = (id == 0) ? d0 : (id == 1) ? d1 : (id == 2) ? d2 : d3;
    int o = (gb & 511) * 256 + threadIdx.x;
    int t = o & 511;
    int c = (o >> 9) & 31;
    int j = o >> 14;
    int rid = t >> 1, hf = t & 1;
    int n = (rid >> 6) * 512 + j * 64 + (rid & 63);
    int k = hf * 256 + c * 8;
    int fl = *flag;
    _Float16* dst = D + (long)o * 8;
    #pragma unroll
    for (int jj = 0; jj < 8; jj++) {
        long si = (long)n * 512 + k + jj;
        float v = fl ? ((const float*)W)[si] : bf2f(((const u16*)W)[si]);
        dst[jj] = (_Float16)v;
    }
}

// ---------- NT GEMM: C(MxN,f32) = A(MxK,bf16,lda) * B(NxK,bf16)^T + bias ----------
__global__ __launch_bounds__(256) void gemm_nt_f32(
    const u16* __restrict__ A, int lda,
    const u16* __restrict__ Bw,
    const u16* __restrict__ bias0, const u16* __restrict__ bias1,
    float* __restrict__ C, int M, int N, int K, int ldc)
{
    __shared__ __align__(16) u16 As[64][40];
    __shared__ __align__(16) u16 Bs[64][40];
    const int tid = threadIdx.x;
    const int bn = blockIdx.x, bm = blockIdx.y;
    const int l = tid & 63, wid = tid >> 6;
    const int wm = wid >> 1, wn = wid & 1;
    const int lr = tid >> 2, lc = (tid & 3) * 8;
    const int l15 = l & 15, lq = l >> 4;

    floatx4 acc00 = (floatx4)(0.f), acc01 = (floatx4)(0.f), acc10 = (floatx4)(0.f), acc11 = (floatx4)(0.f);

    int am = bm * 64 + lr; if (am > M - 1) am = M - 1;
    const u16* Ap = A + (long)am * lda + lc;
    const u16* Bp = Bw + (long)(bn * 64 + lr) * K + lc;

    for (int k0 = 0; k0 < K; k0 += 32) {
        *(short8*)&As[lr][lc] = *(const short8*)(Ap + k0);
        *(short8*)&Bs[lr][lc] = *(const short8*)(Bp + k0);
        __syncthreads();
        short8 af0 = *(const short8*)&As[wm * 32 + l15][lq * 8];
        short8 af1 = *(const short8*)&As[wm * 32 + 16 + l15][lq * 8];
        short8 bf0 = *(const short8*)&Bs[wn * 32 + l15][lq * 8];
        short8 bf1 = *(const short8*)&Bs[wn * 32 + 16 + l15][lq * 8];
        acc00 = __builtin_amdgcn_mfma_f32_16x16x32_bf16(af0, bf0, acc00, 0, 0, 0);
        acc01 = __builtin_amdgcn_mfma_f32_16x16x32_bf16(af0, bf1, acc01, 0, 0, 0);
        acc10 = __builtin_amdgcn_mfma_f32_16x16x32_bf16(af1, bf0, acc10, 0, 0, 0);
        acc11 = __builtin_amdgcn_mfma_f32_16x16x32_bf16(af1, bf1, acc11, 0, 0, 0);
        __syncthreads();
    }
    floatx4 accs[2][2] = {{acc00, acc01}, {acc10, acc11}};
    #pragma unroll
    for (int i = 0; i < 2; i++)
        #pragma unroll
        for (int j = 0; j < 2; j++)
            #pragma unroll
            for (int r = 0; r < 4; r++) {
                int gm = bm * 64 + wm * 32 + i * 16 + lq * 4 + r;
                int gn = bn * 64 + wn * 32 + j * 16 + l15;
                if (gm < M) {
                    float v = accs[i][j][r];
                    if (bias0) v += bf2f(bias0[gn]);
                    if (bias1) v += bf2f(bias1[gn]);
                    C[(long)gm * ldc + gn] = v;
                }
            }
}

// ---------- conv3x3 as implicit-im2col NT GEMM: out kmap (B*240, 512) bf16 ----------
__global__ __launch_bounds__(256) void conv_gemm(
    const u16* __restrict__ featP, const u16* __restrict__ W2,
    const u16* __restrict__ kb, u16* __restrict__ kmap)
{
    __shared__ __align__(16) u16 As[64][40];
    __shared__ __align__(16) u16 Bs[64][40];
    const int tid = threadIdx.x;
    const int bn = blockIdx.x, bm = blockIdx.y;
    const int l = tid & 63, wid = tid >> 6;
    const int wm = wid >> 1, wn = wid & 1;
    const int lr = tid >> 2, lc = (tid & 3) * 8;
    const int l15 = l & 15, lq = l >> 4;

    floatx4 acc00 = (floatx4)(0.f), acc01 = (floatx4)(0.f), acc10 = (floatx4)(0.f), acc11 = (floatx4)(0.f);

    int gm = bm * 64 + lr;
    int b = gm / 240;
    int hw = gm % 240;
    int h = hw / 40, w = hw % 40;
    const u16* fb = featP + (long)(b * 8) * 42 * 512;
    const u16* Bp = W2 + (long)(bn * 64 + lr) * 4608 + lc;

    for (int k0 = 0; k0 < 4608; k0 += 32) {
        int kh = k0 / 1536;
        int kw = (k0 % 1536) / 512;
        int ci0 = k0 & 511;
        const u16* ap = fb + ((long)((h + kh) * 42 + (w + kw))) * 512 + ci0 + lc;
        *(short8*)&As[lr][lc] = *(const short8*)ap;
        *(short8*)&Bs[lr][lc] = *(const short8*)(Bp + k0);
        __syncthreads();
        short8 af0 = *(const short8*)&As[wm * 32 + l15][lq * 8];
        short8 af1 = *(const short8*)&As[wm * 32 + 16 + l15][lq * 8];
        short8 bf0 = *(const short8*)&Bs[wn * 32 + l15][lq * 8];
        short8 bf1 = *(const short8*)&Bs[wn * 32 + 16 + l15][lq * 8];
        acc00 = __builtin_amdgcn_mfma_f32_16x16x32_bf16(af0, bf0, acc00, 0, 0, 0);
        acc01 = __builtin_amdgcn_mfma_f32_16x16x32_bf16(af0, bf1, acc01, 0, 0, 0);
        acc10 = __builtin_amdgcn_mfma_f32_16x16x32_bf16(af1, bf0, acc10, 0, 0, 0);
        acc11 = __builtin_amdgcn_mfma_f32_16x16x32_bf16(af1, bf1, acc11, 0, 0, 0);
        __syncthreads();
    }
    floatx4 accs[2][2] = {{acc00, acc01}, {acc10, acc11}};
    #pragma unroll
    for (int i = 0; i < 2; i++)
        #pragma unroll
        for (int j = 0; j < 2; j++)
            #pragma unroll
            for (int r = 0; r < 4; r++) {
                int om = bm * 64 + wm * 32 + i * 16 + lq * 4 + r;
                int on = bn * 64 + wn * 32 + j * 16 + l15;
                float v = accs[i][j][r] + bf2f(kb[on]);
                kmap[(long)om * 512 + on] = f2bf(v);
            }
}

// ---------- LSTM recurrence, weight-in-register multi-block version ----------
// 256 blocks (XCD-swizzled: 8 slice-blocks of a batch share one XCD's L2).
// 512 threads: rid=tid>>1 (gate-row: gate=rid>>6, unit=rid&63), hf=tid&1 (k half).
// Weights: 32 named half8 (128 VGPRs), pinned via empty asm "+v" (defs cannot be
// rematerialized from memory) + amdgpu_waves_per_eu(2,2) (occupancy target =
// 1 block/CU, VGPR budget 256 -> no scratch spill). VGPR_Count is the tell.
#define WL(F) F(0) F(1) F(2) F(3) F(4) F(5) F(6) F(7) F(8) F(9) F(10) F(11) F(12) F(13) F(14) F(15) \
              F(16) F(17) F(18) F(19) F(20) F(21) F(22) F(23) F(24) F(25) F(26) F(27) F(28) F(29) F(30) F(31)
#define WDECL(i) half8 w##i = wp8[(long)(j * 32 + i) * 512 + tid];
#define WPIN(i)  asm volatile("" : "+v"(w##i));
#define DOTC(i) { \
    half8 hv = *(const half8*)&hS2[(hf * 2 + (i / 16)) * 136 + (i % 16) * 8]; \
    a = __builtin_amdgcn_fdot2(__builtin_shufflevector(hv, hv, 0, 1), __builtin_shufflevector(w##i, w##i, 0, 1), a, false); \
    a = __builtin_amdgcn_fdot2(__builtin_shufflevector(hv, hv, 2, 3), __builtin_shufflevector(w##i, w##i, 2, 3), a, false); \
    a = __builtin_amdgcn_fdot2(__builtin_shufflevector(hv, hv, 4, 5), __builtin_shufflevector(w##i, w##i, 4, 5), a, false); \
    a = __builtin_amdgcn_fdot2(__builtin_shufflevector(hv, hv, 6, 7), __builtin_shufflevector(w##i, w##i, 6, 7), a, false); }

__global__ __launch_bounds__(512) __attribute__((amdgpu_waves_per_eu(2, 2))) void lstm_sync(
    const float* __restrict__ xpre, const _Float16* __restrict__ Wq3,
    u16* __restrict__ seq_out, float* __restrict__ f32_out,
    unsigned* __restrict__ hEx, int* __restrict__ bar,
    int T, int f32_ld)
{
    const int i_ = blockIdx.x;
    const int slot = i_ >> 3;
    const int b = (i_ & 7) * 4 + (slot & 3);
    const int j = slot >> 2;
    const int tid = threadIdx.x;
    const int hf = tid & 1;

    __shared__ __align__(16) _Float16 hS2[4 * 136];
    __shared__ float part[512];
    __shared__ _Float16 hLoc[64];

    const half8* wp8 = (const half8*)Wq3;
    WL(WDECL)
    WL(WPIN)                         // pin: loads execute once, values opaque
    float cst = 0.f;

    for (int t = 0; t < T; t++) {
        float a = 0.f;
        if (t > 0) {
            if (tid == 0) {
                const int target = 8 * t;
                while (__hip_atomic_load(bar + b, __ATOMIC_ACQUIRE, AGENT) < target)
                    __builtin_amdgcn_s_sleep(2);
            }
            __syncthreads();
            if (tid < 256) {
                unsigned v = __hip_atomic_load(
                    &hEx[(((t - 1) & 1) * 32 + b) * 256 + tid], __ATOMIC_RELAXED, AGENT);
                int k = tid * 2;
                *(unsigned*)&hS2[(k >> 7) * 136 + (k & 127)] = v;
            }
            __syncthreads();
            WL(DOTC)
        }
        part[tid] = a;
        __syncthreads();
        if (tid < 64) {
            const float* xp = xpre + ((long)b * T + t) * 2048;
            int w = tid;
            float gi = xp[j * 64 + w]        + part[(0   + w) * 2] + part[(0   + w) * 2 + 1];
            float gf = xp[512 + j * 64 + w]  + part[(64  + w) * 2] + part[(64  + w) * 2 + 1];
            float gg = xp[1024 + j * 64 + w] + part[(128 + w) * 2] + part[(128 + w) * 2 + 1];
            float go = xp[1536 + j * 64 + w] + part[(192 + w) * 2] + part[(192 + w) * 2 + 1];
            cst = sigm_(gf) * cst + sigm_(gi) * tanh_(gg);
            float h = sigm_(go) * tanh_(cst);
            hLoc[w] = (_Float16)h;
            long so = ((long)b * T + t) * 512 + j * 64 + w;
            seq_out[so] = f2bf(h);
            if (f32_out) f32_out[((long)b * T + t) * f32_ld + j * 64 + w] = h;
        }
        __syncthreads();
        if (tid < 32) {
            half2v hp2 = *(const half2v*)&hLoc[2 * tid];
            unsigned v = *(const unsigned*)&hp2;
            __hip_atomic_store(&hEx[((t & 1) * 32 + b) * 256 + j * 32 + tid], v,
                               __ATOMIC_RELAXED, AGENT);
        }
        __syncthreads();             // each wave drains its own stores (vmcnt) here
        if (tid == 0)
            __hip_atomic_fetch_add(bar + b, 1, __ATOMIC_RELEASE, AGENT);
    }
}

// ---------- token build: tok (B,27,512) bf16 ----------
__global__ __launch_bounds__(256) void tok_k(
    const float* __restrict__ holf, const u16* __restrict__ cemb,
    const int* __restrict__ label, u16* __restrict__ tok)
{
    int idx = blockIdx.x * 256 + threadIdx.x;
    int c = idx & 511;
    int m = idx >> 9;
    int b = m / 27, t = m % 27;
    float v;
    if (t == 0) v = holf[(long)b * 512 + c];
    else v = bf2f(cemb[(long)label[b * 26 + (t - 1)] * 512 + c]);
    tok[idx] = f2bf(v);
}

// ---------- fused score: tanh-dot + mask + softmax -> aw (B,27,240) f32 ----------
__global__ __launch_bounds__(256) void score_k(
    const float* __restrict__ q, const u16* __restrict__ kmap,
    const u16* __restrict__ sW, const u16* __restrict__ sb,
    const float* __restrict__ vr, float* __restrict__ aw)
{
    int bt = blockIdx.x;
    int b = bt / 27;
    int tid = threadIdx.x;
    __shared__ float qs[512];
    __shared__ float ss[512];
    __shared__ float red[256];
    qs[tid] = q[(long)bt * 512 + tid];
    qs[tid + 256] = q[(long)bt * 512 + tid + 256];
    ss[tid] = bf2f(sW[tid]);
    ss[tid + 256] = bf2f(sW[tid + 256]);
    __syncthreads();
    float sc = -INFINITY;
    float ex = 0.f;
    if (tid < 240) {
        const u16* kp = kmap + ((long)b * 240 + tid) * 512;
        float acc = 0.f;
        for (int c = 0; c < 512; c++) {
            float x = bf2f(kp[c]) + qs[c];
            acc = fmaf(ss[c], tanh_(x), acc);
        }
        acc += bf2f(sb[0]);
        float r = vr[b];
        int vw = (int)ceilf(40.f * r);
        if (vw > 40) vw = 40;
        int wcol = tid % 40;
        sc = (wcol >= vw) ? -INFINITY : acc;
    }
    red[tid] = sc;
    __syncthreads();
    for (int s = 128; s > 0; s >>= 1) {
        if (tid < s) red[tid] = fmaxf(red[tid], red[tid + s]);
        __syncthreads();
    }
    float mx = red[0];
    __syncthreads();
    if (tid < 240) ex = (sc == -INFINITY) ? 0.f : __expf(sc - mx);
    red[tid] = ex;
    __syncthreads();
    for (int s = 128; s > 0; s >>= 1) {
        if (tid < s) red[tid] += red[tid + s];
        __syncthreads();
    }
    float inv = 1.f / red[0];
    if (tid < 240) aw[(long)bt * 240 + tid] = ex * inv;
}

// ---------- attn_feat -> concat cols [512,1024) f32 (raw feat, dtype-aware) ----------
__global__ __launch_bounds__(256) void attn_k(
    const void* __restrict__ feat, const float* __restrict__ aw,
    float* __restrict__ concat, const int* __restrict__ flag)
{
    const int fl = *flag;
    int b = blockIdx.x >> 3;
    int cc = (blockIdx.x & 7) * 64;
    int tid = threadIdx.x;
    __shared__ float awS[27 * 240];
    __shared__ u16 fS[64 * 240];
    for (int i = tid; i < 27 * 240; i += 256) awS[i] = aw[(long)b * 27 * 240 + i];
    long fbase = ((long)b * 512 + cc) * 240;
    for (int i = tid; i < 64 * 240; i += 256)
        fS[i] = fl ? f2bf(((const float*)feat)[fbase + i]) : ((const u16*)feat)[fbase + i];
    __syncthreads();
    for (int item = tid; item < 64 * 27; item += 256) {
        int c = item / 27, t = item % 27;
        const u16* fp = &fS[c * 240];
        const float* ap = &awS[t * 240];
        float acc = 0.f;
        for (int hw = 0; hw < 240; hw++) acc = fmaf(bf2f(fp[hw]), ap[hw], acc);
        concat[((long)(b * 27 + t)) * 1536 + 512 + cc + c] = acc;
    }
}

// ---------- holistic broadcast -> concat cols [1024,1536) ----------
__global__ __launch_bounds__(256) void holfill_k(const float* __restrict__ holf, float* __restrict__ concat) {
    int idx = blockIdx.x * 256 + threadIdx.x;
    int c = idx & 511;
    int m = idx >> 9;
    int b = m / 27;
    concat[(long)m * 1536 + 1024 + c] = holf[(long)b * 512 + c];
}

// ---------- prediction + slice: out (B,26,97), dtype per flag ----------
__global__ __launch_bounds__(256) void pred_k(
    const float* __restrict__ concat, const u16* __restrict__ pW,
    const u16* __restrict__ pb, void* __restrict__ out, const int* __restrict__ flag)
{
    int m0 = blockIdx.x * 4;
    int tid = threadIdx.x;
    const int fl = *flag;
    __shared__ float aS[4][1536];
    for (int i = tid; i < 4 * 1536; i += 256)
        aS[i / 1536][i % 1536] = concat[(long)(m0 + i / 1536) * 1536 + (i % 1536)];
    __syncthreads();
    int r = tid >> 6;
    int nb = tid & 63;
    int m = m0 + r;
    int b = m / 27, t = m % 27;
    for (int n = nb; n < 97; n += 64) {
        const u16* wp = pW + (long)n * 1536;
        float acc = 0.f;
        for (int k = 0; k < 1536; k++) acc = fmaf(aS[r][k], bf2f(wp[k]), acc);
        acc += bf2f(pb[n]);
        if (t > 0) {
            long o = ((long)(b * 26 + (t - 1))) * 97 + n;
            if (fl) ((float*)out)[o] = acc;
            else    ((u16*)out)[o] = f2bf(acc);
        }
    }
}

// ---------- launch ----------
extern "C" void kernel_launch(void* const* d_in, const int* in_sizes, int n_in,
                              void* d_out, int out_size, void* d_ws, size_t ws_size,
                              hipStream_t stream) {
    (void)in_sizes; (void)n_in; (void)out_size; (void)ws_size;
    const void* feat_r = d_in[0];
    const int*  label  = (const int*)d_in[1];
    const void* vr_r   = d_in[2];

    char* w = (char*)d_ws;
    size_t off = 0;
    auto alloc = [&](size_t bytes) -> void* {
        void* p = w + off;
        off = (off + bytes + 63) & ~(size_t)63;
        return p;
    };
    int*   flag    = (int*)  alloc(4);
    int*   bar     = (int*)  alloc(128 * 4);
    unsigned* hEx  = (unsigned*)alloc(2 * 32 * 256 * 4);
    u16*   canon   = (u16*)  alloc((size_t)CANON_TOTAL * 2);
    float* cvr     = (float*)alloc(32ull * 4);
    u16*   featv   = (u16*)  alloc(655360ull * 2);
    float* xpre    = (float*)alloc(2621440ull * 4);   // kmap aliases after LSTMs
    u16*   seq0    = (u16*)  alloc(655360ull * 2);
    u16*   seq1    = (u16*)  alloc(655360ull * 2);
    u16*   tok     = (u16*)  alloc(442368ull * 2);
    u16*   seqd0   = (u16*)  alloc(442368ull * 2);
    u16*   Hid     = (u16*)  alloc(442368ull * 2);
    float* holf    = (float*)alloc(16384ull * 4);
    float* qf      = (float*)alloc(442368ull * 4);
    u16*   featP   = (u16*)  alloc(5505024ull * 2);
    u16*   W2      = (u16*)  alloc(2359296ull * 2);
    float* aw      = (float*)alloc(207360ull * 4);
    float* concat  = (float*)alloc(1327104ull * 4);
    _Float16* Wq[4];
    for (int i = 0; i < 4; i++) Wq[i] = (_Float16*)alloc(1048576ull * 2);
    u16*   kmap    = (u16*)xpre;

    u16* cW0    = canon + OFF_W0;
    u16* cW1    = canon + OFF_W1;
    u16* cW2    = canon + OFF_W2;
    u16* cW3    = canon + OFF_W3;
    u16* cb0    = canon + OFF_B;
    u16* cencW  = canon + OFF_ENCW;
    u16* cqW    = canon + OFF_QW;
    u16* cpredW = canon + OFF_PREDW;
    u16* cemb   = canon + OFF_EMB;
    u16* cencb  = canon + OFF_ENCB;
    u16* cqb    = canon + OFF_QB;
    u16* ckb    = canon + OFF_KB;
    u16* csW    = canon + OFF_SW;
    u16* csb    = canon + OFF_SB;
    u16* cpredb = canon + OFF_PREDB;

    // ---- sniff + canonicalize ----
    sniff_k<<<dim3(1), 64, 0, stream>>>(feat_r, flag);
    init_bar_k<<<dim3(1), 128, 0, stream>>>(bar);
    SrcPtrs S;
    S.e0Wih = d_in[3];  S.e1Wih = d_in[7];  S.d0Wih = d_in[20]; S.d1Wih = d_in[24];
    S.b0 = d_in[5];  S.b1 = d_in[6];  S.b2 = d_in[9];  S.b3 = d_in[10];
    S.b4 = d_in[22]; S.b5 = d_in[23]; S.b6 = d_in[26]; S.b7 = d_in[27];
    S.encW = d_in[11]; S.qW = d_in[13]; S.predW = d_in[28]; S.emb = d_in[19];
    S.encb = d_in[12]; S.qb = d_in[14]; S.kb = d_in[16]; S.sW = d_in[17];
    S.sb = d_in[18]; S.predb = d_in[29];
    canon_all<<<dim3((CANON_TOTAL + 255) / 256), 256, 0, stream>>>(S, canon, flag);
    canonf_k<<<dim3(1), 64, 0, stream>>>(vr_r, cvr, 32, flag);
    w2_k<<<dim3(9216), 256, 0, stream>>>(d_in[15], W2, flag);
    wq3_all<<<dim3(2048), 256, 0, stream>>>(d_in[4], d_in[8], d_in[21], d_in[25],
                                            Wq[0], Wq[1], Wq[2], Wq[3], flag);

    // ---- prep ----
    featv_k  <<<dim3(2560), 256, 0, stream>>>(feat_r, featv, flag);
    padfeat_k<<<dim3(21504), 256, 0, stream>>>(feat_r, featP, flag);

    // ---- encoder ----
    gemm_nt_f32<<<dim3(32, 20), 256, 0, stream>>>(featv, 512, cW0, cb0 + 0 * 2048, cb0 + 1 * 2048, xpre, 1280, 2048, 512, 2048);
    lstm_sync<<<dim3(256), 512, 0, stream>>>(xpre, Wq[0], seq0, nullptr, hEx, bar + 0, 40, 0);
    gemm_nt_f32<<<dim3(32, 20), 256, 0, stream>>>(seq0, 512, cW1, cb0 + 2 * 2048, cb0 + 3 * 2048, xpre, 1280, 2048, 512, 2048);
    lstm_sync<<<dim3(256), 512, 0, stream>>>(xpre, Wq[1], seq1, nullptr, hEx, bar + 32, 40, 0);
    gemm_nt_f32<<<dim3(8, 1), 256, 0, stream>>>(seq1 + 39 * 512, 40 * 512, cencW, cencb, nullptr, holf, 32, 512, 512, 512);

    // ---- decoder ----
    tok_k<<<dim3(1728), 256, 0, stream>>>(holf, cemb, label, tok);
    gemm_nt_f32<<<dim3(32, 14), 256, 0, stream>>>(tok, 512, cW2, cb0 + 4 * 2048, cb0 + 5 * 2048, xpre, 864, 2048, 512, 2048);
    lstm_sync<<<dim3(256), 512, 0, stream>>>(xpre, Wq[2], seqd0, nullptr, hEx, bar + 64, 27, 0);
    gemm_nt_f32<<<dim3(32, 14), 256, 0, stream>>>(seqd0, 512, cW3, cb0 + 6 * 2048, cb0 + 7 * 2048, xpre, 864, 2048, 512, 2048);
    lstm_sync<<<dim3(256), 512, 0, stream>>>(xpre, Wq[3], Hid, concat, hEx, bar + 96, 27, 1536);

    // ---- attention (xpre dead; kmap aliases it) ----
    gemm_nt_f32<<<dim3(8, 14), 256, 0, stream>>>(Hid, 512, cqW, cqb, nullptr, qf, 864, 512, 512, 512);
    conv_gemm<<<dim3(8, 120), 256, 0, stream>>>(featP, W2, ckb, kmap);
    score_k<<<dim3(864), 256, 0, stream>>>(qf, kmap, csW, csb, cvr, aw);
    attn_k<<<dim3(256), 256, 0, stream>>>(feat_r, aw, concat, flag);
    holfill_k<<<dim3(1728), 256, 0, stream>>>(holf, concat);

    // ---- prediction ----
    pred_k<<<dim3(216), 256, 0, stream>>>(concat, cpredW, cpredb, d_out, flag);
}

// Round 6
// 1387.166 us; speedup vs baseline: 4.2729x; 1.4926x over previous
//
#include <hip/hip_runtime.h>

typedef unsigned short u16;
typedef __attribute__((ext_vector_type(8))) short short8;
typedef __attribute__((ext_vector_type(4))) float floatx4;
typedef _Float16 half8 __attribute__((ext_vector_type(8)));
typedef _Float16 half2v __attribute__((ext_vector_type(2)));

#define AGENT __HIP_MEMORY_SCOPE_AGENT

// ---------- helpers ----------
__device__ __forceinline__ float bf2f(u16 v) { return __uint_as_float(((unsigned)v) << 16); }
__device__ __forceinline__ u16 f2bf(float f) {
    unsigned u = __float_as_uint(f);
    unsigned r = (u + 0x7FFFu + ((u >> 16) & 1u)) >> 16;
    return (u16)r;
}
__device__ __forceinline__ float sigm_(float x) { return 1.f / (1.f + __expf(-x)); }
__device__ __forceinline__ float tanh_(float x) {
    x = fminf(fmaxf(x, -15.f), 15.f);
    float e = __expf(2.f * x);
    return (e - 1.f) / (e + 1.f);
}

// B=32, C=512, H=6, W=40, NC=97, L=26, T=27

// ---------- dtype sniffing: flag=1 if inputs are fp32, 0 if bf16 ----------
__global__ void sniff_k(const void* __restrict__ feat_raw, int* __restrict__ flag) {
    if (threadIdx.x == 0 && blockIdx.x == 0) {
        const u16* p = (const u16*)feat_raw;
        int insane = 0;
        #pragma unroll
        for (int i = 0; i < 32; i += 2) {
            float x = bf2f(p[i]);
            float a = fabsf(x);
            if (!(a <= 1000.f)) insane = 1;
            if (x != 0.f && a < 1e-8f) insane = 1;
        }
        *flag = insane;
    }
}

// zero 2048 ints of per-layer/per-batch/per-slice flags (ws poisoned each launch)
__global__ void init_bar_k(int* __restrict__ flg) {
    flg[blockIdx.x * 256 + threadIdx.x] = 0;
}

// ---------- one-shot canonicalization of all weight tensors into one bf16 region ----------
struct SrcPtrs {
    const void* e0Wih; const void* e1Wih; const void* d0Wih; const void* d1Wih;
    const void* b0; const void* b1; const void* b2; const void* b3;
    const void* b4; const void* b5; const void* b6; const void* b7;
    const void* encW; const void* qW; const void* predW; const void* emb;
    const void* encb; const void* qb; const void* kb; const void* sW;
    const void* sb; const void* predb;
};
// region layout (element offsets)
#define OFF_W0      0
#define OFF_W1      1048576
#define OFF_W2      2097152
#define OFF_W3      3145728
#define OFF_B       4194304     // 8 x 2048
#define OFF_ENCW    4210688
#define OFF_QW      4472832
#define OFF_PREDW   4734976
#define OFF_EMB     4883968
#define OFF_ENCB    4933632
#define OFF_QB      4934144
#define OFF_KB      4934656
#define OFF_SW      4935168
#define OFF_SB      4935680
#define OFF_PREDB   4935681
#define CANON_TOTAL 4935778

__global__ __launch_bounds__(256) void canon_all(SrcPtrs S, u16* __restrict__ dst,
                                                 const int* __restrict__ flag) {
    int idx = blockIdx.x * 256 + threadIdx.x;
    if (idx >= CANON_TOTAL) return;
    const void* s; int loc;
    if (idx < OFF_B) {
        int k = idx >> 20; loc = idx & 1048575;
        s = (k == 0) ? S.e0Wih : (k == 1) ? S.e1Wih : (k == 2) ? S.d0Wih : S.d1Wih;
    } else if (idx < OFF_ENCW) {
        int r = idx - OFF_B; int k = r >> 11; loc = r & 2047;
        s = (k == 0) ? S.b0 : (k == 1) ? S.b1 : (k == 2) ? S.b2 : (k == 3) ? S.b3
          : (k == 4) ? S.b4 : (k == 5) ? S.b5 : (k == 6) ? S.b6 : S.b7;
    } else if (idx < OFF_QW)    { s = S.encW;  loc = idx - OFF_ENCW; }
    else if (idx < OFF_PREDW)   { s = S.qW;    loc = idx - OFF_QW; }
    else if (idx < OFF_EMB)     { s = S.predW; loc = idx - OFF_PREDW; }
    else if (idx < OFF_ENCB)    { s = S.emb;   loc = idx - OFF_EMB; }
    else if (idx < OFF_QB)      { s = S.encb;  loc = idx - OFF_ENCB; }
    else if (idx < OFF_KB)      { s = S.qb;    loc = idx - OFF_QB; }
    else if (idx < OFF_SW)      { s = S.kb;    loc = idx - OFF_KB; }
    else if (idx < OFF_SB)      { s = S.sW;    loc = idx - OFF_SW; }
    else if (idx < OFF_PREDB)   { s = S.sb;    loc = idx - OFF_SB; }
    else                        { s = S.predb; loc = idx - OFF_PREDB; }
    dst[idx] = (*flag) ? f2bf(((const float*)s)[loc]) : ((const u16*)s)[loc];
}

// canonical fp32 copy (for valid_ratios: exact mask arithmetic)
__global__ __launch_bounds__(64) void canonf_k(const void* __restrict__ src, float* __restrict__ dst,
                                               int n, const int* __restrict__ flag) {
    int i = blockIdx.x * 64 + threadIdx.x;
    if (i >= n) return;
    dst[i] = (*flag) ? ((const float*)src)[i] : bf2f(((const u16*)src)[i]);
}

// ---------- prep kernels (read raw feat, dtype-aware) ----------

__device__ __forceinline__ float rdf(const void* p, long i, int fl) {
    return fl ? ((const float*)p)[i] : bf2f(((const u16*)p)[i]);
}

// feat (B,C,6,40) raw -> featv (B,40,C) bf16 (max over H)
__global__ __launch_bounds__(256) void featv_k(const void* __restrict__ feat, u16* __restrict__ featv,
                                               const int* __restrict__ flag) {
    const int fl = *flag;
    int idx = blockIdx.x * 256 + threadIdx.x;
    int c = idx & 511;
    int r = idx >> 9;
    int w = r % 40, b = r / 40;
    float mx = -1e30f;
    long base = ((long)(b * 512 + c) * 6) * 40 + w;
    #pragma unroll
    for (int h = 0; h < 6; h++) mx = fmaxf(mx, rdf(feat, base + h * 40, fl));
    featv[idx] = f2bf(mx);
}

// feat (B,C,6,40) raw -> featP (B,8,42,C) bf16 zero-padded NHWC
__global__ __launch_bounds__(256) void padfeat_k(const void* __restrict__ feat, u16* __restrict__ featP,
                                                 const int* __restrict__ flag) {
    const int fl = *flag;
    int idx = blockIdx.x * 256 + threadIdx.x;
    int c = idx & 511;
    int r = idx >> 9;
    int wp = r % 42; int r2 = r / 42;
    int hp = r2 & 7; int b = r2 >> 3;
    u16 v = 0;
    if (hp >= 1 && hp <= 6 && wp >= 1 && wp <= 40) {
        long si = ((long)(b * 512 + c) * 6 + (hp - 1)) * 40 + (wp - 1);
        v = fl ? f2bf(((const float*)feat)[si]) : ((const u16*)feat)[si];
    }
    featP[idx] = v;
}

// k_W (Co,Ci,3,3) raw -> W2 (Co, (kh*3+kw)*512+ci) bf16
__global__ __launch_bounds__(256) void w2_k(const void* __restrict__ kW, u16* __restrict__ W2,
                                            const int* __restrict__ flag) {
    int idx = blockIdx.x * 256 + threadIdx.x;
    int co = idx / 4608;
    int r = idx % 4608;
    int kh = r / 1536;
    int r2 = r % 1536;
    int kw = r2 / 512;
    int ci = r2 & 511;
    long si = ((long)(co * 512 + ci) * 3 + kh) * 3 + kw;
    W2[idx] = (*flag) ? f2bf(((const float*)kW)[si]) : ((const u16*)kW)[si];
}

// 4x Whh (2048,512) raw -> Wq3 f16 for lstm_sync (all four layers, one launch).
__global__ __launch_bounds__(256) void wq3_all(
    const void* __restrict__ s0, const void* __restrict__ s1,
    const void* __restrict__ s2, const void* __restrict__ s3,
    _Float16* __restrict__ d0, _Float16* __restrict__ d1,
    _Float16* __restrict__ d2, _Float16* __restrict__ d3,
    const int* __restrict__ flag)
{
    int gb = blockIdx.x;
    int id = gb >> 9;
    const void* W = (id == 0) ? s0 : (id == 1) ? s1 : (id == 2) ? s2 : s3;
    _Float16* D = (id == 0) ? d0 : (id == 1) ? d1 : (id == 2) ? d2 : d3;
    int o = (gb & 511) * 256 + threadIdx.x;
    int t = o & 511;
    int c = (o >> 9) & 31;
    int j = o >> 14;
    int rid = t >> 1, hf = t & 1;
    int n = (rid >> 6) * 512 + j * 64 + (rid & 63);
    int k = hf * 256 + c * 8;
    int fl = *flag;
    _Float16* dst = D + (long)o * 8;
    #pragma unroll
    for (int jj = 0; jj < 8; jj++) {
        long si = (long)n * 512 + k + jj;
        float v = fl ? ((const float*)W)[si] : bf2f(((const u16*)W)[si]);
        dst[jj] = (_Float16)v;
    }
}

// ---------- NT GEMM: C(MxN,f32) = A(MxK,bf16,lda) * B(NxK,bf16)^T + bias ----------
__global__ __launch_bounds__(256) void gemm_nt_f32(
    const u16* __restrict__ A, int lda,
    const u16* __restrict__ Bw,
    const u16* __restrict__ bias0, const u16* __restrict__ bias1,
    float* __restrict__ C, int M, int N, int K, int ldc)
{
    __shared__ __align__(16) u16 As[64][40];
    __shared__ __align__(16) u16 Bs[64][40];
    const int tid = threadIdx.x;
    const int bn = blockIdx.x, bm = blockIdx.y;
    const int l = tid & 63, wid = tid >> 6;
    const int wm = wid >> 1, wn = wid & 1;
    const int lr = tid >> 2, lc = (tid & 3) * 8;
    const int l15 = l & 15, lq = l >> 4;

    floatx4 acc00 = (floatx4)(0.f), acc01 = (floatx4)(0.f), acc10 = (floatx4)(0.f), acc11 = (floatx4)(0.f);

    int am = bm * 64 + lr; if (am > M - 1) am = M - 1;
    const u16* Ap = A + (long)am * lda + lc;
    const u16* Bp = Bw + (long)(bn * 64 + lr) * K + lc;

    for (int k0 = 0; k0 < K; k0 += 32) {
        *(short8*)&As[lr][lc] = *(const short8*)(Ap + k0);
        *(short8*)&Bs[lr][lc] = *(const short8*)(Bp + k0);
        __syncthreads();
        short8 af0 = *(const short8*)&As[wm * 32 + l15][lq * 8];
        short8 af1 = *(const short8*)&As[wm * 32 + 16 + l15][lq * 8];
        short8 bf0 = *(const short8*)&Bs[wn * 32 + l15][lq * 8];
        short8 bf1 = *(const short8*)&Bs[wn * 32 + 16 + l15][lq * 8];
        acc00 = __builtin_amdgcn_mfma_f32_16x16x32_bf16(af0, bf0, acc00, 0, 0, 0);
        acc01 = __builtin_amdgcn_mfma_f32_16x16x32_bf16(af0, bf1, acc01, 0, 0, 0);
        acc10 = __builtin_amdgcn_mfma_f32_16x16x32_bf16(af1, bf0, acc10, 0, 0, 0);
        acc11 = __builtin_amdgcn_mfma_f32_16x16x32_bf16(af1, bf1, acc11, 0, 0, 0);
        __syncthreads();
    }
    floatx4 accs[2][2] = {{acc00, acc01}, {acc10, acc11}};
    #pragma unroll
    for (int i = 0; i < 2; i++)
        #pragma unroll
        for (int j = 0; j < 2; j++)
            #pragma unroll
            for (int r = 0; r < 4; r++) {
                int gm = bm * 64 + wm * 32 + i * 16 + lq * 4 + r;
                int gn = bn * 64 + wn * 32 + j * 16 + l15;
                if (gm < M) {
                    float v = accs[i][j][r];
                    if (bias0) v += bf2f(bias0[gn]);
                    if (bias1) v += bf2f(bias1[gn]);
                    C[(long)gm * ldc + gn] = v;
                }
            }
}

// ---------- conv3x3 as implicit-im2col NT GEMM: out kmap (B*240, 512) bf16 ----------
__global__ __launch_bounds__(256) void conv_gemm(
    const u16* __restrict__ featP, const u16* __restrict__ W2,
    const u16* __restrict__ kb, u16* __restrict__ kmap)
{
    __shared__ __align__(16) u16 As[64][40];
    __shared__ __align__(16) u16 Bs[64][40];
    const int tid = threadIdx.x;
    const int bn = blockIdx.x, bm = blockIdx.y;
    const int l = tid & 63, wid = tid >> 6;
    const int wm = wid >> 1, wn = wid & 1;
    const int lr = tid >> 2, lc = (tid & 3) * 8;
    const int l15 = l & 15, lq = l >> 4;

    floatx4 acc00 = (floatx4)(0.f), acc01 = (floatx4)(0.f), acc10 = (floatx4)(0.f), acc11 = (floatx4)(0.f);

    int gm = bm * 64 + lr;
    int b = gm / 240;
    int hw = gm % 240;
    int h = hw / 40, w = hw % 40;
    const u16* fb = featP + (long)(b * 8) * 42 * 512;
    const u16* Bp = W2 + (long)(bn * 64 + lr) * 4608 + lc;

    for (int k0 = 0; k0 < 4608; k0 += 32) {
        int kh = k0 / 1536;
        int kw = (k0 % 1536) / 512;
        int ci0 = k0 & 511;
        const u16* ap = fb + ((long)((h + kh) * 42 + (w + kw))) * 512 + ci0 + lc;
        *(short8*)&As[lr][lc] = *(const short8*)ap;
        *(short8*)&Bs[lr][lc] = *(const short8*)(Bp + k0);
        __syncthreads();
        short8 af0 = *(const short8*)&As[wm * 32 + l15][lq * 8];
        short8 af1 = *(const short8*)&As[wm * 32 + 16 + l15][lq * 8];
        short8 bf0 = *(const short8*)&Bs[wn * 32 + l15][lq * 8];
        short8 bf1 = *(const short8*)&Bs[wn * 32 + 16 + l15][lq * 8];
        acc00 = __builtin_amdgcn_mfma_f32_16x16x32_bf16(af0, bf0, acc00, 0, 0, 0);
        acc01 = __builtin_amdgcn_mfma_f32_16x16x32_bf16(af0, bf1, acc01, 0, 0, 0);
        acc10 = __builtin_amdgcn_mfma_f32_16x16x32_bf16(af1, bf0, acc10, 0, 0, 0);
        acc11 = __builtin_amdgcn_mfma_f32_16x16x32_bf16(af1, bf1, acc11, 0, 0, 0);
        __syncthreads();
    }
    floatx4 accs[2][2] = {{acc00, acc01}, {acc10, acc11}};
    #pragma unroll
    for (int i = 0; i < 2; i++)
        #pragma unroll
        for (int j = 0; j < 2; j++)
            #pragma unroll
            for (int r = 0; r < 4; r++) {
                int om = bm * 64 + wm * 32 + i * 16 + lq * 4 + r;
                int on = bn * 64 + wn * 32 + j * 16 + l15;
                float v = accs[i][j][r] + bf2f(kb[on]);
                kmap[(long)om * 512 + on] = f2bf(v);
            }
}

// ---------- LSTM recurrence, weight-in-register multi-block version ----------
// 256 blocks (b = batch, j = 64-unit slice). Weights pinned as 32 half8 SSA
// values (backend holds them in the unified VGPR/AGPR file — r5 measured: works).
// Rendezvous: per-producer flags flg[b*16+j] (release-stored by producing wave;
// wave's own vmcnt(0) before the release covers its 32 hEx data stores) +
// lane-parallel acquire polls — no central RMW, one visibility hop per step.
#define WL(F) F(0) F(1) F(2) F(3) F(4) F(5) F(6) F(7) F(8) F(9) F(10) F(11) F(12) F(13) F(14) F(15) \
              F(16) F(17) F(18) F(19) F(20) F(21) F(22) F(23) F(24) F(25) F(26) F(27) F(28) F(29) F(30) F(31)
#define WDECL(i) half8 w##i = wp8[(long)(j * 32 + i) * 512 + tid];
#define WPIN(i)  asm volatile("" : "+v"(w##i));
#define DOTC(i) { \
    half8 hv = *(const half8*)&hS2[(hf * 2 + (i / 16)) * 136 + (i % 16) * 8]; \
    a = __builtin_amdgcn_fdot2(__builtin_shufflevector(hv, hv, 0, 1), __builtin_shufflevector(w##i, w##i, 0, 1), a, false); \
    a = __builtin_amdgcn_fdot2(__builtin_shufflevector(hv, hv, 2, 3), __builtin_shufflevector(w##i, w##i, 2, 3), a, false); \
    a = __builtin_amdgcn_fdot2(__builtin_shufflevector(hv, hv, 4, 5), __builtin_shufflevector(w##i, w##i, 4, 5), a, false); \
    a = __builtin_amdgcn_fdot2(__builtin_shufflevector(hv, hv, 6, 7), __builtin_shufflevector(w##i, w##i, 6, 7), a, false); }

__global__ __launch_bounds__(512) __attribute__((amdgpu_waves_per_eu(2, 2))) void lstm_sync(
    const float* __restrict__ xpre, const _Float16* __restrict__ Wq3,
    u16* __restrict__ seq_out, float* __restrict__ f32_out,
    unsigned* __restrict__ hEx, int* __restrict__ flg,
    int T, int f32_ld)
{
    const int i_ = blockIdx.x;
    const int slot = i_ >> 3;
    const int b = (i_ & 7) * 4 + (slot & 3);
    const int j = slot >> 2;
    const int tid = threadIdx.x;
    const int hf = tid & 1;

    __shared__ __align__(16) _Float16 hS2[4 * 136];
    __shared__ float part[512];

    const half8* wp8 = (const half8*)Wq3;
    WL(WDECL)
    WL(WPIN)                         // pin: loads execute once, values opaque
    float cst = 0.f;

    for (int t = 0; t < T; t++) {
        // prefetch this step's x-precomputed gate inputs (independent of h)
        float xi = 0.f, xf = 0.f, xg = 0.f, xo = 0.f;
        if (tid < 64) {
            const float* xp = xpre + ((long)b * T + t) * 2048 + j * 64 + tid;
            xi = xp[0]; xf = xp[512]; xg = xp[1024]; xo = xp[1536];
        }
        float a = 0.f;
        if (t > 0) {
            // lane-parallel poll of the 8 producer flags for h(t-1)
            if (tid < 8) {
                while (__hip_atomic_load(flg + b * 16 + tid, __ATOMIC_ACQUIRE, AGENT) < t) {}
            }
            __syncthreads();
            // stage h(t-1) from the exchange buffer into LDS
            if (tid < 256) {
                unsigned v = __hip_atomic_load(
                    &hEx[(((t - 1) & 1) * 32 + b) * 256 + tid], __ATOMIC_RELAXED, AGENT);
                int k = tid * 2;
                *(unsigned*)&hS2[(k >> 7) * 136 + (k & 127)] = v;
            }
            __syncthreads();
            WL(DOTC)
        }
        part[tid] = a;
        __syncthreads();
        if (tid < 64) {
            float gi = xi + part[(0   + tid) * 2] + part[(0   + tid) * 2 + 1];
            float gf = xf + part[(64  + tid) * 2] + part[(64  + tid) * 2 + 1];
            float gg = xg + part[(128 + tid) * 2] + part[(128 + tid) * 2 + 1];
            float go = xo + part[(192 + tid) * 2] + part[(192 + tid) * 2 + 1];
            cst = sigm_(gf) * cst + sigm_(gi) * tanh_(gg);
            float h = sigm_(go) * tanh_(cst);
            long so = ((long)b * T + t) * 512 + j * 64 + tid;
            seq_out[so] = f2bf(h);
            if (f32_out) f32_out[((long)b * T + t) * f32_ld + j * 64 + tid] = h;
            // in-wave pack (wave0 lanes 0..63): lane w<32 grabs units 2w, 2w+1
            float hlo = __shfl(h, tid * 2);
            float hhi = __shfl(h, tid * 2 + 1);
            if (t + 1 < T) {
                if (tid < 32) {
                    half2v hp; hp[0] = (_Float16)hlo; hp[1] = (_Float16)hhi;
                    __hip_atomic_store(&hEx[((t & 1) * 32 + b) * 256 + j * 32 + tid],
                                       *(unsigned*)&hp, __ATOMIC_RELAXED, AGENT);
                }
                if (tid == 0)
                    __hip_atomic_store(flg + b * 16 + j, t + 1, __ATOMIC_RELEASE, AGENT);
            }
        }
    }
}

// ---------- token build: tok (B,27,512) bf16 ----------
__global__ __launch_bounds__(256) void tok_k(
    const float* __restrict__ holf, const u16* __restrict__ cemb,
    const int* __restrict__ label, u16* __restrict__ tok)
{
    int idx = blockIdx.x * 256 + threadIdx.x;
    int c = idx & 511;
    int m = idx >> 9;
    int b = m / 27, t = m % 27;
    float v;
    if (t == 0) v = holf[(long)b * 512 + c];
    else v = bf2f(cemb[(long)label[b * 26 + (t - 1)] * 512 + c]);
    tok[idx] = f2bf(v);
}

// ---------- fused score: tanh-dot + mask + softmax -> aw (B,27,240) f32 ----------
__global__ __launch_bounds__(256) void score_k(
    const float* __restrict__ q, const u16* __restrict__ kmap,
    const u16* __restrict__ sW, const u16* __restrict__ sb,
    const float* __restrict__ vr, float* __restrict__ aw)
{
    int bt = blockIdx.x;
    int b = bt / 27;
    int tid = threadIdx.x;
    __shared__ float qs[512];
    __shared__ float ss[512];
    __shared__ float red[256];
    qs[tid] = q[(long)bt * 512 + tid];
    qs[tid + 256] = q[(long)bt * 512 + tid + 256];
    ss[tid] = bf2f(sW[tid]);
    ss[tid + 256] = bf2f(sW[tid + 256]);
    __syncthreads();
    float sc = -INFINITY;
    float ex = 0.f;
    if (tid < 240) {
        const u16* kp = kmap + ((long)b * 240 + tid) * 512;
        float acc = 0.f;
        for (int c = 0; c < 512; c++) {
            float x = bf2f(kp[c]) + qs[c];
            acc = fmaf(ss[c], tanh_(x), acc);
        }
        acc += bf2f(sb[0]);
        float r = vr[b];
        int vw = (int)ceilf(40.f * r);
        if (vw > 40) vw = 40;
        int wcol = tid % 40;
        sc = (wcol >= vw) ? -INFINITY : acc;
    }
    red[tid] = sc;
    __syncthreads();
    for (int s = 128; s > 0; s >>= 1) {
        if (tid < s) red[tid] = fmaxf(red[tid], red[tid + s]);
        __syncthreads();
    }
    float mx = red[0];
    __syncthreads();
    if (tid < 240) ex = (sc == -INFINITY) ? 0.f : __expf(sc - mx);
    red[tid] = ex;
    __syncthreads();
    for (int s = 128; s > 0; s >>= 1) {
        if (tid < s) red[tid] += red[tid + s];
        __syncthreads();
    }
    float inv = 1.f / red[0];
    if (tid < 240) aw[(long)bt * 240 + tid] = ex * inv;
}

// ---------- attn_feat -> concat cols [512,1024) f32 (raw feat, dtype-aware) ----------
__global__ __launch_bounds__(256) void attn_k(
    const void* __restrict__ feat, const float* __restrict__ aw,
    float* __restrict__ concat, const int* __restrict__ flag)
{
    const int fl = *flag;
    int b = blockIdx.x >> 3;
    int cc = (blockIdx.x & 7) * 64;
    int tid = threadIdx.x;
    __shared__ float awS[27 * 240];
    __shared__ u16 fS[64 * 240];
    for (int i = tid; i < 27 * 240; i += 256) awS[i] = aw[(long)b * 27 * 240 + i];
    long fbase = ((long)b * 512 + cc) * 240;
    for (int i = tid; i < 64 * 240; i += 256)
        fS[i] = fl ? f2bf(((const float*)feat)[fbase + i]) : ((const u16*)feat)[fbase + i];
    __syncthreads();
    for (int item = tid; item < 64 * 27; item += 256) {
        int c = item / 27, t = item % 27;
        const u16* fp = &fS[c * 240];
        const float* ap = &awS[t * 240];
        float acc = 0.f;
        for (int hw = 0; hw < 240; hw++) acc = fmaf(bf2f(fp[hw]), ap[hw], acc);
        concat[((long)(b * 27 + t)) * 1536 + 512 + cc + c] = acc;
    }
}

// ---------- holistic broadcast -> concat cols [1024,1536) ----------
__global__ __launch_bounds__(256) void holfill_k(const float* __restrict__ holf, float* __restrict__ concat) {
    int idx = blockIdx.x * 256 + threadIdx.x;
    int c = idx & 511;
    int m = idx >> 9;
    int b = m / 27;
    concat[(long)m * 1536 + 1024 + c] = holf[(long)b * 512 + c];
}

// ---------- prediction + slice: out (B,26,97), dtype per flag ----------
__global__ __launch_bounds__(256) void pred_k(
    const float* __restrict__ concat, const u16* __restrict__ pW,
    const u16* __restrict__ pb, void* __restrict__ out, const int* __restrict__ flag)
{
    int m0 = blockIdx.x * 4;
    int tid = threadIdx.x;
    const int fl = *flag;
    __shared__ float aS[4][1536];
    for (int i = tid; i < 4 * 1536; i += 256)
        aS[i / 1536][i % 1536] = concat[(long)(m0 + i / 1536) * 1536 + (i % 1536)];
    __syncthreads();
    int r = tid >> 6;
    int nb = tid & 63;
    int m = m0 + r;
    int b = m / 27, t = m % 27;
    for (int n = nb; n < 97; n += 64) {
        const u16* wp = pW + (long)n * 1536;
        float acc = 0.f;
        for (int k = 0; k < 1536; k++) acc = fmaf(aS[r][k], bf2f(wp[k]), acc);
        acc += bf2f(pb[n]);
        if (t > 0) {
            long o = ((long)(b * 26 + (t - 1))) * 97 + n;
            if (fl) ((float*)out)[o] = acc;
            else    ((u16*)out)[o] = f2bf(acc);
        }
    }
}

// ---------- launch ----------
extern "C" void kernel_launch(void* const* d_in, const int* in_sizes, int n_in,
                              void* d_out, int out_size, void* d_ws, size_t ws_size,
                              hipStream_t stream) {
    (void)in_sizes; (void)n_in; (void)out_size; (void)ws_size;
    const void* feat_r = d_in[0];
    const int*  label  = (const int*)d_in[1];
    const void* vr_r   = d_in[2];

    char* w = (char*)d_ws;
    size_t off = 0;
    auto alloc = [&](size_t bytes) -> void* {
        void* p = w + off;
        off = (off + bytes + 63) & ~(size_t)63;
        return p;
    };
    int*   flag    = (int*)  alloc(4);
    int*   flg     = (int*)  alloc(2048 * 4);         // 4 layers x 32 batch x 16 (8 used)
    unsigned* hEx  = (unsigned*)alloc(2 * 32 * 256 * 4);
    u16*   canon   = (u16*)  alloc((size_t)CANON_TOTAL * 2);
    float* cvr     = (float*)alloc(32ull * 4);
    u16*   featv   = (u16*)  alloc(655360ull * 2);
    float* xpre    = (float*)alloc(2621440ull * 4);   // kmap aliases after LSTMs
    u16*   seq0    = (u16*)  alloc(655360ull * 2);
    u16*   seq1    = (u16*)  alloc(655360ull * 2);
    u16*   tok     = (u16*)  alloc(442368ull * 2);
    u16*   seqd0   = (u16*)  alloc(442368ull * 2);
    u16*   Hid     = (u16*)  alloc(442368ull * 2);
    float* holf    = (float*)alloc(16384ull * 4);
    float* qf      = (float*)alloc(442368ull * 4);
    u16*   featP   = (u16*)  alloc(5505024ull * 2);
    u16*   W2      = (u16*)  alloc(2359296ull * 2);
    float* aw      = (float*)alloc(207360ull * 4);
    float* concat  = (float*)alloc(1327104ull * 4);
    _Float16* Wq[4];
    for (int i = 0; i < 4; i++) Wq[i] = (_Float16*)alloc(1048576ull * 2);
    u16*   kmap    = (u16*)xpre;

    u16* cW0    = canon + OFF_W0;
    u16* cW1    = canon + OFF_W1;
    u16* cW2    = canon + OFF_W2;
    u16* cW3    = canon + OFF_W3;
    u16* cb0    = canon + OFF_B;
    u16* cencW  = canon + OFF_ENCW;
    u16* cqW    = canon + OFF_QW;
    u16* cpredW = canon + OFF_PREDW;
    u16* cemb   = canon + OFF_EMB;
    u16* cencb  = canon + OFF_ENCB;
    u16* cqb    = canon + OFF_QB;
    u16* ckb    = canon + OFF_KB;
    u16* csW    = canon + OFF_SW;
    u16* csb    = canon + OFF_SB;
    u16* cpredb = canon + OFF_PREDB;

    // ---- sniff + canonicalize ----
    sniff_k<<<dim3(1), 64, 0, stream>>>(feat_r, flag);
    init_bar_k<<<dim3(8), 256, 0, stream>>>(flg);
    SrcPtrs S;
    S.e0Wih = d_in[3];  S.e1Wih = d_in[7];  S.d0Wih = d_in[20]; S.d1Wih = d_in[24];
    S.b0 = d_in[5];  S.b1 = d_in[6];  S.b2 = d_in[9];  S.b3 = d_in[10];
    S.b4 = d_in[22]; S.b5 = d_in[23]; S.b6 = d_in[26]; S.b7 = d_in[27];
    S.encW = d_in[11]; S.qW = d_in[13]; S.predW = d_in[28]; S.emb = d_in[19];
    S.encb = d_in[12]; S.qb = d_in[14]; S.kb = d_in[16]; S.sW = d_in[17];
    S.sb = d_in[18]; S.predb = d_in[29];
    canon_all<<<dim3((CANON_TOTAL + 255) / 256), 256, 0, stream>>>(S, canon, flag);
    canonf_k<<<dim3(1), 64, 0, stream>>>(vr_r, cvr, 32, flag);
    w2_k<<<dim3(9216), 256, 0, stream>>>(d_in[15], W2, flag);
    wq3_all<<<dim3(2048), 256, 0, stream>>>(d_in[4], d_in[8], d_in[21], d_in[25],
                                            Wq[0], Wq[1], Wq[2], Wq[3], flag);

    // ---- prep ----
    featv_k  <<<dim3(2560), 256, 0, stream>>>(feat_r, featv, flag);
    padfeat_k<<<dim3(21504), 256, 0, stream>>>(feat_r, featP, flag);

    // ---- encoder ----
    gemm_nt_f32<<<dim3(32, 20), 256, 0, stream>>>(featv, 512, cW0, cb0 + 0 * 2048, cb0 + 1 * 2048, xpre, 1280, 2048, 512, 2048);
    lstm_sync<<<dim3(256), 512, 0, stream>>>(xpre, Wq[0], seq0, nullptr, hEx, flg + 0, 40, 0);
    gemm_nt_f32<<<dim3(32, 20), 256, 0, stream>>>(seq0, 512, cW1, cb0 + 2 * 2048, cb0 + 3 * 2048, xpre, 1280, 2048, 512, 2048);
    lstm_sync<<<dim3(256), 512, 0, stream>>>(xpre, Wq[1], seq1, nullptr, hEx, flg + 512, 40, 0);
    gemm_nt_f32<<<dim3(8, 1), 256, 0, stream>>>(seq1 + 39 * 512, 40 * 512, cencW, cencb, nullptr, holf, 32, 512, 512, 512);

    // ---- decoder ----
    tok_k<<<dim3(1728), 256, 0, stream>>>(holf, cemb, label, tok);
    gemm_nt_f32<<<dim3(32, 14), 256, 0, stream>>>(tok, 512, cW2, cb0 + 4 * 2048, cb0 + 5 * 2048, xpre, 864, 2048, 512, 2048);
    lstm_sync<<<dim3(256), 512, 0, stream>>>(xpre, Wq[2], seqd0, nullptr, hEx, flg + 1024, 27, 0);
    gemm_nt_f32<<<dim3(32, 14), 256, 0, stream>>>(seqd0, 512, cW3, cb0 + 6 * 2048, cb0 + 7 * 2048, xpre, 864, 2048, 512, 2048);
    lstm_sync<<<dim3(256), 512, 0, stream>>>(xpre, Wq[3], Hid, concat, hEx, flg + 1536, 27, 1536);

    // ---- attention (xpre dead; kmap aliases it) ----
    gemm_nt_f32<<<dim3(8, 14), 256, 0, stream>>>(Hid, 512, cqW, cqb, nullptr, qf, 864, 512, 512, 512);
    conv_gemm<<<dim3(8, 120), 256, 0, stream>>>(featP, W2, ckb, kmap);
    score_k<<<dim3(864), 256, 0, stream>>>(qf, kmap, csW, csb, cvr, aw);
    attn_k<<<dim3(256), 256, 0, stream>>>(feat_r, aw, concat, flag);
    holfill_k<<<dim3(1728), 256, 0, stream>>>(holf, concat);

    // ---- prediction ----
    pred_k<<<dim3(216), 256, 0, stream>>>(concat, cpredW, cpredb, d_out, flag);
}

// Round 7
// 1362.549 us; speedup vs baseline: 4.3501x; 1.0181x over previous
//
#include <hip/hip_runtime.h>

typedef unsigned short u16;
typedef __attribute__((ext_vector_type(8))) short short8;
typedef __attribute__((ext_vector_type(4))) float floatx4;
typedef _Float16 half8 __attribute__((ext_vector_type(8)));
typedef _Float16 half2v __attribute__((ext_vector_type(2)));

#define AGENT __HIP_MEMORY_SCOPE_AGENT

// ---------- helpers ----------
__device__ __forceinline__ float bf2f(u16 v) { return __uint_as_float(((unsigned)v) << 16); }
__device__ __forceinline__ u16 f2bf(float f) {
    unsigned u = __float_as_uint(f);
    unsigned r = (u + 0x7FFFu + ((u >> 16) & 1u)) >> 16;
    return (u16)r;
}
__device__ __forceinline__ float sigm_(float x) { return 1.f / (1.f + __expf(-x)); }
__device__ __forceinline__ float tanh_(float x) {
    x = fminf(fmaxf(x, -15.f), 15.f);
    float e = __expf(2.f * x);
    return (e - 1.f) / (e + 1.f);
}

// B=32, C=512, H=6, W=40, NC=97, L=26, T=27

// ---------- init: zero padded lstm flags + dtype sniff (one launch) ----------
__global__ void init_k(const void* __restrict__ feat_raw, int* __restrict__ flag,
                       int* __restrict__ flg) {
    int idx = blockIdx.x * 256 + threadIdx.x;
    flg[idx] = 0;                                 // 64 blocks x 256 = 16384 ints
    if (idx == 0) {
        const u16* p = (const u16*)feat_raw;
        int insane = 0;
        #pragma unroll
        for (int i = 0; i < 32; i += 2) {
            float x = bf2f(p[i]);
            float a = fabsf(x);
            if (!(a <= 1000.f)) insane = 1;
            if (x != 0.f && a < 1e-8f) insane = 1;
        }
        *flag = insane;
    }
}

// ---------- one-shot canonicalization of all weight tensors into one bf16 region ----------
struct SrcPtrs {
    const void* e0Wih; const void* e1Wih; const void* d0Wih; const void* d1Wih;
    const void* b0; const void* b1; const void* b2; const void* b3;
    const void* b4; const void* b5; const void* b6; const void* b7;
    const void* encW; const void* qW; const void* predW; const void* emb;
    const void* encb; const void* qb; const void* kb; const void* sW;
    const void* sb; const void* predb;
};
#define OFF_W0      0
#define OFF_W1      1048576
#define OFF_W2      2097152
#define OFF_W3      3145728
#define OFF_B       4194304
#define OFF_ENCW    4210688
#define OFF_QW      4472832
#define OFF_PREDW   4734976
#define OFF_EMB     4883968
#define OFF_ENCB    4933632
#define OFF_QB      4934144
#define OFF_KB      4934656
#define OFF_SW      4935168
#define OFF_SB      4935680
#define OFF_PREDB   4935681
#define CANON_TOTAL 4935778

__global__ __launch_bounds__(256) void canon_all(SrcPtrs S, u16* __restrict__ dst,
                                                 const int* __restrict__ flag) {
    int idx = blockIdx.x * 256 + threadIdx.x;
    if (idx >= CANON_TOTAL) return;
    const void* s; int loc;
    if (idx < OFF_B) {
        int k = idx >> 20; loc = idx & 1048575;
        s = (k == 0) ? S.e0Wih : (k == 1) ? S.e1Wih : (k == 2) ? S.d0Wih : S.d1Wih;
    } else if (idx < OFF_ENCW) {
        int r = idx - OFF_B; int k = r >> 11; loc = r & 2047;
        s = (k == 0) ? S.b0 : (k == 1) ? S.b1 : (k == 2) ? S.b2 : (k == 3) ? S.b3
          : (k == 4) ? S.b4 : (k == 5) ? S.b5 : (k == 6) ? S.b6 : S.b7;
    } else if (idx < OFF_QW)    { s = S.encW;  loc = idx - OFF_ENCW; }
    else if (idx < OFF_PREDW)   { s = S.qW;    loc = idx - OFF_QW; }
    else if (idx < OFF_EMB)     { s = S.predW; loc = idx - OFF_PREDW; }
    else if (idx < OFF_ENCB)    { s = S.emb;   loc = idx - OFF_EMB; }
    else if (idx < OFF_QB)      { s = S.encb;  loc = idx - OFF_ENCB; }
    else if (idx < OFF_KB)      { s = S.qb;    loc = idx - OFF_QB; }
    else if (idx < OFF_SW)      { s = S.kb;    loc = idx - OFF_KB; }
    else if (idx < OFF_SB)      { s = S.sW;    loc = idx - OFF_SW; }
    else if (idx < OFF_PREDB)   { s = S.sb;    loc = idx - OFF_SB; }
    else                        { s = S.predb; loc = idx - OFF_PREDB; }
    dst[idx] = (*flag) ? f2bf(((const float*)s)[loc]) : ((const u16*)s)[loc];
}

__global__ __launch_bounds__(64) void canonf_k(const void* __restrict__ src, float* __restrict__ dst,
                                               int n, const int* __restrict__ flag) {
    int i = blockIdx.x * 64 + threadIdx.x;
    if (i >= n) return;
    dst[i] = (*flag) ? ((const float*)src)[i] : bf2f(((const u16*)src)[i]);
}

// ---------- prep kernels (read raw feat, dtype-aware) ----------
__device__ __forceinline__ float rdf(const void* p, long i, int fl) {
    return fl ? ((const float*)p)[i] : bf2f(((const u16*)p)[i]);
}

__global__ __launch_bounds__(256) void featv_k(const void* __restrict__ feat, u16* __restrict__ featv,
                                               const int* __restrict__ flag) {
    const int fl = *flag;
    int idx = blockIdx.x * 256 + threadIdx.x;
    int c = idx & 511;
    int r = idx >> 9;
    int w = r % 40, b = r / 40;
    float mx = -1e30f;
    long base = ((long)(b * 512 + c) * 6) * 40 + w;
    #pragma unroll
    for (int h = 0; h < 6; h++) mx = fmaxf(mx, rdf(feat, base + h * 40, fl));
    featv[idx] = f2bf(mx);
}

__global__ __launch_bounds__(256) void padfeat_k(const void* __restrict__ feat, u16* __restrict__ featP,
                                                 const int* __restrict__ flag) {
    const int fl = *flag;
    int idx = blockIdx.x * 256 + threadIdx.x;
    int c = idx & 511;
    int r = idx >> 9;
    int wp = r % 42; int r2 = r / 42;
    int hp = r2 & 7; int b = r2 >> 3;
    u16 v = 0;
    if (hp >= 1 && hp <= 6 && wp >= 1 && wp <= 40) {
        long si = ((long)(b * 512 + c) * 6 + (hp - 1)) * 40 + (wp - 1);
        v = fl ? f2bf(((const float*)feat)[si]) : ((const u16*)feat)[si];
    }
    featP[idx] = v;
}

__global__ __launch_bounds__(256) void w2_k(const void* __restrict__ kW, u16* __restrict__ W2,
                                            const int* __restrict__ flag) {
    int idx = blockIdx.x * 256 + threadIdx.x;
    int co = idx / 4608;
    int r = idx % 4608;
    int kh = r / 1536;
    int r2 = r % 1536;
    int kw = r2 / 512;
    int ci = r2 & 511;
    long si = ((long)(co * 512 + ci) * 3 + kh) * 3 + kw;
    W2[idx] = (*flag) ? f2bf(((const float*)kW)[si]) : ((const u16*)kW)[si];
}

__global__ __launch_bounds__(256) void wq3_all(
    const void* __restrict__ s0, const void* __restrict__ s1,
    const void* __restrict__ s2, const void* __restrict__ s3,
    _Float16* __restrict__ d0, _Float16* __restrict__ d1,
    _Float16* __restrict__ d2, _Float16* __restrict__ d3,
    const int* __restrict__ flag)
{
    int gb = blockIdx.x;
    int id = gb >> 9;
    const void* W = (id == 0) ? s0 : (id == 1) ? s1 : (id == 2) ? s2 : s3;
    _Float16* D = (id == 0) ? d0 : (id == 1) ? d1 : (id == 2) ? d2 : d3;
    int o = (gb & 511) * 256 + threadIdx.x;
    int t = o & 511;
    int c = (o >> 9) & 31;
    int j = o >> 14;
    int rid = t >> 1, hf = t & 1;
    int n = (rid >> 6) * 512 + j * 64 + (rid & 63);
    int k = hf * 256 + c * 8;
    int fl = *flag;
    _Float16* dst = D + (long)o * 8;
    #pragma unroll
    for (int jj = 0; jj < 8; jj++) {
        long si = (long)n * 512 + k + jj;
        float v = fl ? ((const float*)W)[si] : bf2f(((const u16*)W)[si]);
        dst[jj] = (_Float16)v;
    }
}

// ---------- NT GEMM ----------
__global__ __launch_bounds__(256) void gemm_nt_f32(
    const u16* __restrict__ A, int lda,
    const u16* __restrict__ Bw,
    const u16* __restrict__ bias0, const u16* __restrict__ bias1,
    float* __restrict__ C, int M, int N, int K, int ldc)
{
    __shared__ __align__(16) u16 As[64][40];
    __shared__ __align__(16) u16 Bs[64][40];
    const int tid = threadIdx.x;
    const int bn = blockIdx.x, bm = blockIdx.y;
    const int l = tid & 63, wid = tid >> 6;
    const int wm = wid >> 1, wn = wid & 1;
    const int lr = tid >> 2, lc = (tid & 3) * 8;
    const int l15 = l & 15, lq = l >> 4;

    floatx4 acc00 = (floatx4)(0.f), acc01 = (floatx4)(0.f), acc10 = (floatx4)(0.f), acc11 = (floatx4)(0.f);

    int am = bm * 64 + lr; if (am > M - 1) am = M - 1;
    const u16* Ap = A + (long)am * lda + lc;
    const u16* Bp = Bw + (long)(bn * 64 + lr) * K + lc;

    for (int k0 = 0; k0 < K; k0 += 32) {
        *(short8*)&As[lr][lc] = *(const short8*)(Ap + k0);
        *(short8*)&Bs[lr][lc] = *(const short8*)(Bp + k0);
        __syncthreads();
        short8 af0 = *(const short8*)&As[wm * 32 + l15][lq * 8];
        short8 af1 = *(const short8*)&As[wm * 32 + 16 + l15][lq * 8];
        short8 bf0 = *(const short8*)&Bs[wn * 32 + l15][lq * 8];
        short8 bf1 = *(const short8*)&Bs[wn * 32 + 16 + l15][lq * 8];
        acc00 = __builtin_amdgcn_mfma_f32_16x16x32_bf16(af0, bf0, acc00, 0, 0, 0);
        acc01 = __builtin_amdgcn_mfma_f32_16x16x32_bf16(af0, bf1, acc01, 0, 0, 0);
        acc10 = __builtin_amdgcn_mfma_f32_16x16x32_bf16(af1, bf0, acc10, 0, 0, 0);
        acc11 = __builtin_amdgcn_mfma_f32_16x16x32_bf16(af1, bf1, acc11, 0, 0, 0);
        __syncthreads();
    }
    floatx4 accs[2][2] = {{acc00, acc01}, {acc10, acc11}};
    #pragma unroll
    for (int i = 0; i < 2; i++)
        #pragma unroll
        for (int j = 0; j < 2; j++)
            #pragma unroll
            for (int r = 0; r < 4; r++) {
                int gm = bm * 64 + wm * 32 + i * 16 + lq * 4 + r;
                int gn = bn * 64 + wn * 32 + j * 16 + l15;
                if (gm < M) {
                    float v = accs[i][j][r];
                    if (bias0) v += bf2f(bias0[gn]);
                    if (bias1) v += bf2f(bias1[gn]);
                    C[(long)gm * ldc + gn] = v;
                }
            }
}

// ---------- conv3x3 as implicit-im2col NT GEMM ----------
__global__ __launch_bounds__(256) void conv_gemm(
    const u16* __restrict__ featP, const u16* __restrict__ W2,
    const u16* __restrict__ kb, u16* __restrict__ kmap)
{
    __shared__ __align__(16) u16 As[64][40];
    __shared__ __align__(16) u16 Bs[64][40];
    const int tid = threadIdx.x;
    const int bn = blockIdx.x, bm = blockIdx.y;
    const int l = tid & 63, wid = tid >> 6;
    const int wm = wid >> 1, wn = wid & 1;
    const int lr = tid >> 2, lc = (tid & 3) * 8;
    const int l15 = l & 15, lq = l >> 4;

    floatx4 acc00 = (floatx4)(0.f), acc01 = (floatx4)(0.f), acc10 = (floatx4)(0.f), acc11 = (floatx4)(0.f);

    int gm = bm * 64 + lr;
    int b = gm / 240;
    int hw = gm % 240;
    int h = hw / 40, w = hw % 40;
    const u16* fb = featP + (long)(b * 8) * 42 * 512;
    const u16* Bp = W2 + (long)(bn * 64 + lr) * 4608 + lc;

    for (int k0 = 0; k0 < 4608; k0 += 32) {
        int kh = k0 / 1536;
        int kw = (k0 % 1536) / 512;
        int ci0 = k0 & 511;
        const u16* ap = fb + ((long)((h + kh) * 42 + (w + kw))) * 512 + ci0 + lc;
        *(short8*)&As[lr][lc] = *(const short8*)ap;
        *(short8*)&Bs[lr][lc] = *(const short8*)(Bp + k0);
        __syncthreads();
        short8 af0 = *(const short8*)&As[wm * 32 + l15][lq * 8];
        short8 af1 = *(const short8*)&As[wm * 32 + 16 + l15][lq * 8];
        short8 bf0 = *(const short8*)&Bs[wn * 32 + l15][lq * 8];
        short8 bf1 = *(const short8*)&Bs[wn * 32 + 16 + l15][lq * 8];
        acc00 = __builtin_amdgcn_mfma_f32_16x16x32_bf16(af0, bf0, acc00, 0, 0, 0);
        acc01 = __builtin_amdgcn_mfma_f32_16x16x32_bf16(af0, bf1, acc01, 0, 0, 0);
        acc10 = __builtin_amdgcn_mfma_f32_16x16x32_bf16(af1, bf0, acc10, 0, 0, 0);
        acc11 = __builtin_amdgcn_mfma_f32_16x16x32_bf16(af1, bf1, acc11, 0, 0, 0);
        __syncthreads();
    }
    floatx4 accs[2][2] = {{acc00, acc01}, {acc10, acc11}};
    #pragma unroll
    for (int i = 0; i < 2; i++)
        #pragma unroll
        for (int j = 0; j < 2; j++)
            #pragma unroll
            for (int r = 0; r < 4; r++) {
                int om = bm * 64 + wm * 32 + i * 16 + lq * 4 + r;
                int on = bn * 64 + wn * 32 + j * 16 + l15;
                float v = accs[i][j][r] + bf2f(kb[on]);
                kmap[(long)om * 512 + on] = f2bf(v);
            }
}

// ---------- LSTM recurrence v3: weights in unified RF, lean rendezvous ----------
// 256 blocks (b=batch, j=slice of 64 units), XCD-grouped: slice-blocks of batch b
// share blockIdx%8. Flags padded to one 64B line each (kill line ping-pong).
// Wave 0 owns the serial path: poll (lanes<8, s_sleep-paced) -> stage (64xdwordx4,
// same wave, no barrier) -> [sync] -> dot (all waves, 4 acc chains) -> [sync] ->
// elementwise+publish (hEx pack + release flag BEFORE seq stores so the release's
// vmcnt(0) doesn't wait on HBM store acks).
#define WL(F) F(0) F(1) F(2) F(3) F(4) F(5) F(6) F(7) F(8) F(9) F(10) F(11) F(12) F(13) F(14) F(15) \
              F(16) F(17) F(18) F(19) F(20) F(21) F(22) F(23) F(24) F(25) F(26) F(27) F(28) F(29) F(30) F(31)
#define WLA(F) F(0,0) F(1,1) F(2,2) F(3,3) F(4,0) F(5,1) F(6,2) F(7,3) \
               F(8,0) F(9,1) F(10,2) F(11,3) F(12,0) F(13,1) F(14,2) F(15,3) \
               F(16,0) F(17,1) F(18,2) F(19,3) F(20,0) F(21,1) F(22,2) F(23,3) \
               F(24,0) F(25,1) F(26,2) F(27,3) F(28,0) F(29,1) F(30,2) F(31,3)
#define WDECL(i) half8 w##i = wp8[(long)(j * 32 + i) * 512 + tid];
#define WPIN(i)  asm volatile("" : "+v"(w##i));
#define DOTC(i,k) { \
    half8 hv = *(const half8*)&hS2[(hf * 2 + (i / 16)) * 136 + (i % 16) * 8]; \
    a##k = __builtin_amdgcn_fdot2(__builtin_shufflevector(hv, hv, 0, 1), __builtin_shufflevector(w##i, w##i, 0, 1), a##k, false); \
    a##k = __builtin_amdgcn_fdot2(__builtin_shufflevector(hv, hv, 2, 3), __builtin_shufflevector(w##i, w##i, 2, 3), a##k, false); \
    a##k = __builtin_amdgcn_fdot2(__builtin_shufflevector(hv, hv, 4, 5), __builtin_shufflevector(w##i, w##i, 4, 5), a##k, false); \
    a##k = __builtin_amdgcn_fdot2(__builtin_shufflevector(hv, hv, 6, 7), __builtin_shufflevector(w##i, w##i, 6, 7), a##k, false); }

typedef unsigned uint4v __attribute__((ext_vector_type(4)));

__global__ __launch_bounds__(512) __attribute__((amdgpu_waves_per_eu(2, 2))) void lstm_sync(
    const float* __restrict__ xpre, const _Float16* __restrict__ Wq3,
    u16* __restrict__ seq_out, float* __restrict__ f32_out,
    unsigned* __restrict__ hEx, int* __restrict__ flg,
    int T, int f32_ld)
{
    const int i_ = blockIdx.x;
    const int slot = i_ >> 3;
    const int b = (i_ & 7) * 4 + (slot & 3);
    const int j = slot >> 2;
    const int tid = threadIdx.x;
    const int hf = tid & 1;

    __shared__ __align__(16) _Float16 hS2[4 * 136];
    __shared__ float part[512];

    const half8* wp8 = (const half8*)Wq3;
    WL(WDECL)
    WL(WPIN)
    float cst = 0.f;

    for (int t = 0; t < T; t++) {
        // prefetch x-side gate inputs (independent of h)
        float xi = 0.f, xf = 0.f, xg = 0.f, xo = 0.f;
        if (tid < 64) {
            const float* xp = xpre + ((long)b * T + t) * 2048 + j * 64 + tid;
            xi = xp[0]; xf = xp[512]; xg = xp[1024]; xo = xp[1536];
        }
        float a0 = 0.f, a1 = 0.f, a2 = 0.f, a3 = 0.f;
        if (t > 0) {
            if (tid < 64) {
                if (tid < 8) {
                    while (__hip_atomic_load(flg + ((b * 8 + tid) << 4), __ATOMIC_ACQUIRE, AGENT) < t)
                        __builtin_amdgcn_s_sleep(1);
                }
                // stage h(t-1): whole 1KB in one dwordx4 per lane (same wave as poll)
                uint4v v = ((const uint4v*)&hEx[(((t - 1) & 1) * 32 + b) * 256])[tid];
                *(uint4v*)&hS2[(tid >> 4) * 136 + (tid & 15) * 8] = v;
            }
            __syncthreads();
            WLA(DOTC)
        }
        part[tid] = (a0 + a1) + (a2 + a3);
        __syncthreads();
        if (tid < 64) {
            float gi = xi + part[(0   + tid) * 2] + part[(0   + tid) * 2 + 1];
            float gf = xf + part[(64  + tid) * 2] + part[(64  + tid) * 2 + 1];
            float gg = xg + part[(128 + tid) * 2] + part[(128 + tid) * 2 + 1];
            float go = xo + part[(192 + tid) * 2] + part[(192 + tid) * 2 + 1];
            cst = sigm_(gf) * cst + sigm_(gi) * tanh_(gg);
            float h = sigm_(go) * tanh_(cst);
            // publish FIRST (release only waits on the 2 hEx lines)
            float hlo = __shfl(h, tid * 2);
            float hhi = __shfl(h, tid * 2 + 1);
            if (t + 1 < T) {
                if (tid < 32) {
                    half2v hp; hp[0] = (_Float16)hlo; hp[1] = (_Float16)hhi;
                    __hip_atomic_store(&hEx[((t & 1) * 32 + b) * 256 + j * 32 + tid],
                                       *(unsigned*)&hp, __ATOMIC_RELAXED, AGENT);
                }
                if (tid == 0)
                    __hip_atomic_store(flg + ((b * 8 + j) << 4), t + 1, __ATOMIC_RELEASE, AGENT);
            }
            asm volatile("" ::: "memory");   // keep output stores below the release
            long so = ((long)b * T + t) * 512 + j * 64 + tid;
            seq_out[so] = f2bf(h);
            if (f32_out) f32_out[((long)b * T + t) * f32_ld + j * 64 + tid] = h;
        }
    }
}

// ---------- token build ----------
__global__ __launch_bounds__(256) void tok_k(
    const float* __restrict__ holf, const u16* __restrict__ cemb,
    const int* __restrict__ label, u16* __restrict__ tok)
{
    int idx = blockIdx.x * 256 + threadIdx.x;
    int c = idx & 511;
    int m = idx >> 9;
    int b = m / 27, t = m % 27;
    float v;
    if (t == 0) v = holf[(long)b * 512 + c];
    else v = bf2f(cemb[(long)label[b * 26 + (t - 1)] * 512 + c]);
    tok[idx] = f2bf(v);
}

// ---------- fused score ----------
__global__ __launch_bounds__(256) void score_k(
    const float* __restrict__ q, const u16* __restrict__ kmap,
    const u16* __restrict__ sW, const u16* __restrict__ sb,
    const float* __restrict__ vr, float* __restrict__ aw)
{
    int bt = blockIdx.x;
    int b = bt / 27;
    int tid = threadIdx.x;
    __shared__ float qs[512];
    __shared__ float ss[512];
    __shared__ float red[256];
    qs[tid] = q[(long)bt * 512 + tid];
    qs[tid + 256] = q[(long)bt * 512 + tid + 256];
    ss[tid] = bf2f(sW[tid]);
    ss[tid + 256] = bf2f(sW[tid + 256]);
    __syncthreads();
    float sc = -INFINITY;
    float ex = 0.f;
    if (tid < 240) {
        const u16* kp = kmap + ((long)b * 240 + tid) * 512;
        float acc = 0.f;
        for (int c = 0; c < 512; c++) {
            float x = bf2f(kp[c]) + qs[c];
            acc = fmaf(ss[c], tanh_(x), acc);
        }
        acc += bf2f(sb[0]);
        float r = vr[b];
        int vw = (int)ceilf(40.f * r);
        if (vw > 40) vw = 40;
        int wcol = tid % 40;
        sc = (wcol >= vw) ? -INFINITY : acc;
    }
    red[tid] = sc;
    __syncthreads();
    for (int s = 128; s > 0; s >>= 1) {
        if (tid < s) red[tid] = fmaxf(red[tid], red[tid + s]);
        __syncthreads();
    }
    float mx = red[0];
    __syncthreads();
    if (tid < 240) ex = (sc == -INFINITY) ? 0.f : __expf(sc - mx);
    red[tid] = ex;
    __syncthreads();
    for (int s = 128; s > 0; s >>= 1) {
        if (tid < s) red[tid] += red[tid + s];
        __syncthreads();
    }
    float inv = 1.f / red[0];
    if (tid < 240) aw[(long)bt * 240 + tid] = ex * inv;
}

// ---------- attn_feat -> concat cols [512,1024) ----------
__global__ __launch_bounds__(256) void attn_k(
    const void* __restrict__ feat, const float* __restrict__ aw,
    float* __restrict__ concat, const int* __restrict__ flag)
{
    const int fl = *flag;
    int b = blockIdx.x >> 3;
    int cc = (blockIdx.x & 7) * 64;
    int tid = threadIdx.x;
    __shared__ float awS[27 * 240];
    __shared__ u16 fS[64 * 240];
    for (int i = tid; i < 27 * 240; i += 256) awS[i] = aw[(long)b * 27 * 240 + i];
    long fbase = ((long)b * 512 + cc) * 240;
    for (int i = tid; i < 64 * 240; i += 256)
        fS[i] = fl ? f2bf(((const float*)feat)[fbase + i]) : ((const u16*)feat)[fbase + i];
    __syncthreads();
    for (int item = tid; item < 64 * 27; item += 256) {
        int c = item / 27, t = item % 27;
        const u16* fp = &fS[c * 240];
        const float* ap = &awS[t * 240];
        float acc = 0.f;
        for (int hw = 0; hw < 240; hw++) acc = fmaf(bf2f(fp[hw]), ap[hw], acc);
        concat[((long)(b * 27 + t)) * 1536 + 512 + cc + c] = acc;
    }
}

// ---------- prediction + slice (reads holf directly; holfill kernel removed) ----------
__global__ __launch_bounds__(256) void pred_k(
    const float* __restrict__ concat, const float* __restrict__ holf,
    const u16* __restrict__ pW, const u16* __restrict__ pb,
    void* __restrict__ out, const int* __restrict__ flag)
{
    int m0 = blockIdx.x * 4;
    int tid = threadIdx.x;
    const int fl = *flag;
    __shared__ float aS[4][1024];
    __shared__ float hS[4][512];
    for (int i = tid; i < 4 * 1024; i += 256)
        aS[i / 1024][i % 1024] = concat[(long)(m0 + i / 1024) * 1536 + (i % 1024)];
    for (int i = tid; i < 4 * 512; i += 256) {
        int m = m0 + i / 512;
        hS[i / 512][i % 512] = holf[(long)(m / 27) * 512 + (i % 512)];
    }
    __syncthreads();
    int r = tid >> 6;
    int nb = tid & 63;
    int m = m0 + r;
    int b = m / 27, t = m % 27;
    for (int n = nb; n < 97; n += 64) {
        const u16* wp = pW + (long)n * 1536;
        float acc = 0.f;
        for (int k = 0; k < 1024; k++) acc = fmaf(aS[r][k], bf2f(wp[k]), acc);
        for (int k = 0; k < 512; k++) acc = fmaf(hS[r][k], bf2f(wp[1024 + k]), acc);
        acc += bf2f(pb[n]);
        if (t > 0) {
            long o = ((long)(b * 26 + (t - 1))) * 97 + n;
            if (fl) ((float*)out)[o] = acc;
            else    ((u16*)out)[o] = f2bf(acc);
        }
    }
}

// ---------- launch ----------
extern "C" void kernel_launch(void* const* d_in, const int* in_sizes, int n_in,
                              void* d_out, int out_size, void* d_ws, size_t ws_size,
                              hipStream_t stream) {
    (void)in_sizes; (void)n_in; (void)out_size; (void)ws_size;
    const void* feat_r = d_in[0];
    const int*  label  = (const int*)d_in[1];
    const void* vr_r   = d_in[2];

    char* w = (char*)d_ws;
    size_t off = 0;
    auto alloc = [&](size_t bytes) -> void* {
        void* p = w + off;
        off = (off + bytes + 63) & ~(size_t)63;
        return p;
    };
    int*   flag    = (int*)  alloc(4);
    int*   flg     = (int*)  alloc(16384 * 4);        // 4 layers x 32 b x 8 j x 64B-padded
    unsigned* hEx  = (unsigned*)alloc(2 * 32 * 256 * 4);
    u16*   canon   = (u16*)  alloc((size_t)CANON_TOTAL * 2);
    float* cvr     = (float*)alloc(32ull * 4);
    u16*   featv   = (u16*)  alloc(655360ull * 2);
    float* xpre    = (float*)alloc(2621440ull * 4);   // kmap aliases after LSTMs
    u16*   seq0    = (u16*)  alloc(655360ull * 2);
    u16*   seq1    = (u16*)  alloc(655360ull * 2);
    u16*   tok     = (u16*)  alloc(442368ull * 2);
    u16*   seqd0   = (u16*)  alloc(442368ull * 2);
    u16*   Hid     = (u16*)  alloc(442368ull * 2);
    float* holf    = (float*)alloc(16384ull * 4);
    float* qf      = (float*)alloc(442368ull * 4);
    u16*   featP   = (u16*)  alloc(5505024ull * 2);
    u16*   W2      = (u16*)  alloc(2359296ull * 2);
    float* aw      = (float*)alloc(207360ull * 4);
    float* concat  = (float*)alloc(1327104ull * 4);
    _Float16* Wq[4];
    for (int i = 0; i < 4; i++) Wq[i] = (_Float16*)alloc(1048576ull * 2);
    u16*   kmap    = (u16*)xpre;

    u16* cW0    = canon + OFF_W0;
    u16* cW1    = canon + OFF_W1;
    u16* cW2    = canon + OFF_W2;
    u16* cW3    = canon + OFF_W3;
    u16* cb0    = canon + OFF_B;
    u16* cencW  = canon + OFF_ENCW;
    u16* cqW    = canon + OFF_QW;
    u16* cpredW = canon + OFF_PREDW;
    u16* cemb   = canon + OFF_EMB;
    u16* cencb  = canon + OFF_ENCB;
    u16* cqb    = canon + OFF_QB;
    u16* ckb    = canon + OFF_KB;
    u16* csW    = canon + OFF_SW;
    u16* csb    = canon + OFF_SB;
    u16* cpredb = canon + OFF_PREDB;

    // ---- init + canonicalize ----
    init_k<<<dim3(64), 256, 0, stream>>>(feat_r, flag, flg);
    SrcPtrs S;
    S.e0Wih = d_in[3];  S.e1Wih = d_in[7];  S.d0Wih = d_in[20]; S.d1Wih = d_in[24];
    S.b0 = d_in[5];  S.b1 = d_in[6];  S.b2 = d_in[9];  S.b3 = d_in[10];
    S.b4 = d_in[22]; S.b5 = d_in[23]; S.b6 = d_in[26]; S.b7 = d_in[27];
    S.encW = d_in[11]; S.qW = d_in[13]; S.predW = d_in[28]; S.emb = d_in[19];
    S.encb = d_in[12]; S.qb = d_in[14]; S.kb = d_in[16]; S.sW = d_in[17];
    S.sb = d_in[18]; S.predb = d_in[29];
    canon_all<<<dim3((CANON_TOTAL + 255) / 256), 256, 0, stream>>>(S, canon, flag);
    canonf_k<<<dim3(1), 64, 0, stream>>>(vr_r, cvr, 32, flag);
    w2_k<<<dim3(9216), 256, 0, stream>>>(d_in[15], W2, flag);
    wq3_all<<<dim3(2048), 256, 0, stream>>>(d_in[4], d_in[8], d_in[21], d_in[25],
                                            Wq[0], Wq[1], Wq[2], Wq[3], flag);

    // ---- prep ----
    featv_k  <<<dim3(2560), 256, 0, stream>>>(feat_r, featv, flag);
    padfeat_k<<<dim3(21504), 256, 0, stream>>>(feat_r, featP, flag);

    // ---- encoder ----
    gemm_nt_f32<<<dim3(32, 20), 256, 0, stream>>>(featv, 512, cW0, cb0 + 0 * 2048, cb0 + 1 * 2048, xpre, 1280, 2048, 512, 2048);
    lstm_sync<<<dim3(256), 512, 0, stream>>>(xpre, Wq[0], seq0, nullptr, hEx, flg + 0, 40, 0);
    gemm_nt_f32<<<dim3(32, 20), 256, 0, stream>>>(seq0, 512, cW1, cb0 + 2 * 2048, cb0 + 3 * 2048, xpre, 1280, 2048, 512, 2048);
    lstm_sync<<<dim3(256), 512, 0, stream>>>(xpre, Wq[1], seq1, nullptr, hEx, flg + 4096, 40, 0);
    gemm_nt_f32<<<dim3(8, 1), 256, 0, stream>>>(seq1 + 39 * 512, 40 * 512, cencW, cencb, nullptr, holf, 32, 512, 512, 512);

    // ---- decoder ----
    tok_k<<<dim3(1728), 256, 0, stream>>>(holf, cemb, label, tok);
    gemm_nt_f32<<<dim3(32, 14), 256, 0, stream>>>(tok, 512, cW2, cb0 + 4 * 2048, cb0 + 5 * 2048, xpre, 864, 2048, 512, 2048);
    lstm_sync<<<dim3(256), 512, 0, stream>>>(xpre, Wq[2], seqd0, nullptr, hEx, flg + 8192, 27, 0);
    gemm_nt_f32<<<dim3(32, 14), 256, 0, stream>>>(seqd0, 512, cW3, cb0 + 6 * 2048, cb0 + 7 * 2048, xpre, 864, 2048, 512, 2048);
    lstm_sync<<<dim3(256), 512, 0, stream>>>(xpre, Wq[3], Hid, concat, hEx, flg + 12288, 27, 1536);

    // ---- attention (xpre dead; kmap aliases it) ----
    gemm_nt_f32<<<dim3(8, 14), 256, 0, stream>>>(Hid, 512, cqW, cqb, nullptr, qf, 864, 512, 512, 512);
    conv_gemm<<<dim3(8, 120), 256, 0, stream>>>(featP, W2, ckb, kmap);
    score_k<<<dim3(864), 256, 0, stream>>>(qf, kmap, csW, csb, cvr, aw);
    attn_k<<<dim3(256), 256, 0, stream>>>(feat_r, aw, concat, flag);

    // ---- prediction ----
    pred_k<<<dim3(216), 256, 0, stream>>>(concat, holf, cpredW, cpredb, d_out, flag);
}

// Round 8
// 915.195 us; speedup vs baseline: 6.4765x; 1.4888x over previous
//
#include <hip/hip_runtime.h>

typedef unsigned short u16;
typedef __attribute__((ext_vector_type(8))) short short8;
typedef __attribute__((ext_vector_type(4))) float floatx4;
typedef _Float16 half8 __attribute__((ext_vector_type(8)));
typedef _Float16 half2v __attribute__((ext_vector_type(2)));
typedef unsigned uint4v __attribute__((ext_vector_type(4)));

#define AGENT __HIP_MEMORY_SCOPE_AGENT
#define SENT 0x7FFF7FFFu   // f16 NaN pair — unreachable: h = sigm*tanh in (-1,1)

// ---------- helpers ----------
__device__ __forceinline__ float bf2f(u16 v) { return __uint_as_float(((unsigned)v) << 16); }
__device__ __forceinline__ u16 f2bf(float f) {
    unsigned u = __float_as_uint(f);
    unsigned r = (u + 0x7FFFu + ((u >> 16) & 1u)) >> 16;
    return (u16)r;
}
__device__ __forceinline__ float sigm_(float x) { return 1.f / (1.f + __expf(-x)); }
__device__ __forceinline__ float tanh_(float x) {
    x = fminf(fmaxf(x, -15.f), 15.f);
    float e = __expf(2.f * x);
    return (e - 1.f) / (e + 1.f);
}

// B=32, C=512, H=6, W=40, NC=97, L=26, T=27
// hEx: 134 step-slots (40+40+27+27) x 32 batch x 256 words, T-indexed, sentinel-init.
#define HEX_WORDS (134 * 32 * 256)

// ---------- init: sentinel-fill hEx + dtype sniff (one launch) ----------
__global__ void init_k(const void* __restrict__ feat_raw, int* __restrict__ flag,
                       unsigned* __restrict__ hEx) {
    int idx = blockIdx.x * 256 + threadIdx.x;   // 4288 blocks x 256 = HEX_WORDS
    hEx[idx] = SENT;
    if (idx == 0) {
        const u16* p = (const u16*)feat_raw;
        int insane = 0;
        #pragma unroll
        for (int i = 0; i < 32; i += 2) {
            float x = bf2f(p[i]);
            float a = fabsf(x);
            if (!(a <= 1000.f)) insane = 1;
            if (x != 0.f && a < 1e-8f) insane = 1;
        }
        *flag = insane;
    }
}

// ---------- one-shot canonicalization of all weight tensors into one bf16 region ----------
struct SrcPtrs {
    const void* e0Wih; const void* e1Wih; const void* d0Wih; const void* d1Wih;
    const void* b0; const void* b1; const void* b2; const void* b3;
    const void* b4; const void* b5; const void* b6; const void* b7;
    const void* encW; const void* qW; const void* predW; const void* emb;
    const void* encb; const void* qb; const void* kb; const void* sW;
    const void* sb; const void* predb;
};
#define OFF_W0      0
#define OFF_W1      1048576
#define OFF_W2      2097152
#define OFF_W3      3145728
#define OFF_B       4194304
#define OFF_ENCW    4210688
#define OFF_QW      4472832
#define OFF_PREDW   4734976
#define OFF_EMB     4883968
#define OFF_ENCB    4933632
#define OFF_QB      4934144
#define OFF_KB      4934656
#define OFF_SW      4935168
#define OFF_SB      4935680
#define OFF_PREDB   4935681
#define CANON_TOTAL 4935778

__global__ __launch_bounds__(256) void canon_all(SrcPtrs S, u16* __restrict__ dst,
                                                 const int* __restrict__ flag) {
    int idx = blockIdx.x * 256 + threadIdx.x;
    if (idx >= CANON_TOTAL) return;
    const void* s; int loc;
    if (idx < OFF_B) {
        int k = idx >> 20; loc = idx & 1048575;
        s = (k == 0) ? S.e0Wih : (k == 1) ? S.e1Wih : (k == 2) ? S.d0Wih : S.d1Wih;
    } else if (idx < OFF_ENCW) {
        int r = idx - OFF_B; int k = r >> 11; loc = r & 2047;
        s = (k == 0) ? S.b0 : (k == 1) ? S.b1 : (k == 2) ? S.b2 : (k == 3) ? S.b3
          : (k == 4) ? S.b4 : (k == 5) ? S.b5 : (k == 6) ? S.b6 : S.b7;
    } else if (idx < OFF_QW)    { s = S.encW;  loc = idx - OFF_ENCW; }
    else if (idx < OFF_PREDW)   { s = S.qW;    loc = idx - OFF_QW; }
    else if (idx < OFF_EMB)     { s = S.predW; loc = idx - OFF_PREDW; }
    else if (idx < OFF_ENCB)    { s = S.emb;   loc = idx - OFF_EMB; }
    else if (idx < OFF_QB)      { s = S.encb;  loc = idx - OFF_ENCB; }
    else if (idx < OFF_KB)      { s = S.qb;    loc = idx - OFF_QB; }
    else if (idx < OFF_SW)      { s = S.kb;    loc = idx - OFF_KB; }
    else if (idx < OFF_SB)      { s = S.sW;    loc = idx - OFF_SW; }
    else if (idx < OFF_PREDB)   { s = S.sb;    loc = idx - OFF_SB; }
    else                        { s = S.predb; loc = idx - OFF_PREDB; }
    dst[idx] = (*flag) ? f2bf(((const float*)s)[loc]) : ((const u16*)s)[loc];
}

__global__ __launch_bounds__(64) void canonf_k(const void* __restrict__ src, float* __restrict__ dst,
                                               int n, const int* __restrict__ flag) {
    int i = blockIdx.x * 64 + threadIdx.x;
    if (i >= n) return;
    dst[i] = (*flag) ? ((const float*)src)[i] : bf2f(((const u16*)src)[i]);
}

// ---------- prep kernels (read raw feat, dtype-aware) ----------
__device__ __forceinline__ float rdf(const void* p, long i, int fl) {
    return fl ? ((const float*)p)[i] : bf2f(((const u16*)p)[i]);
}

__global__ __launch_bounds__(256) void featv_k(const void* __restrict__ feat, u16* __restrict__ featv,
                                               const int* __restrict__ flag) {
    const int fl = *flag;
    int idx = blockIdx.x * 256 + threadIdx.x;
    int c = idx & 511;
    int r = idx >> 9;
    int w = r % 40, b = r / 40;
    float mx = -1e30f;
    long base = ((long)(b * 512 + c) * 6) * 40 + w;
    #pragma unroll
    for (int h = 0; h < 6; h++) mx = fmaxf(mx, rdf(feat, base + h * 40, fl));
    featv[idx] = f2bf(mx);
}

__global__ __launch_bounds__(256) void padfeat_k(const void* __restrict__ feat, u16* __restrict__ featP,
                                                 const int* __restrict__ flag) {
    const int fl = *flag;
    int idx = blockIdx.x * 256 + threadIdx.x;
    int c = idx & 511;
    int r = idx >> 9;
    int wp = r % 42; int r2 = r / 42;
    int hp = r2 & 7; int b = r2 >> 3;
    u16 v = 0;
    if (hp >= 1 && hp <= 6 && wp >= 1 && wp <= 40) {
        long si = ((long)(b * 512 + c) * 6 + (hp - 1)) * 40 + (wp - 1);
        v = fl ? f2bf(((const float*)feat)[si]) : ((const u16*)feat)[si];
    }
    featP[idx] = v;
}

__global__ __launch_bounds__(256) void w2_k(const void* __restrict__ kW, u16* __restrict__ W2,
                                            const int* __restrict__ flag) {
    int idx = blockIdx.x * 256 + threadIdx.x;
    int co = idx / 4608;
    int r = idx % 4608;
    int kh = r / 1536;
    int r2 = r % 1536;
    int kw = r2 / 512;
    int ci = r2 & 511;
    long si = ((long)(co * 512 + ci) * 3 + kh) * 3 + kw;
    W2[idx] = (*flag) ? f2bf(((const float*)kW)[si]) : ((const u16*)kW)[si];
}

__global__ __launch_bounds__(256) void wq3_all(
    const void* __restrict__ s0, const void* __restrict__ s1,
    const void* __restrict__ s2, const void* __restrict__ s3,
    _Float16* __restrict__ d0, _Float16* __restrict__ d1,
    _Float16* __restrict__ d2, _Float16* __restrict__ d3,
    const int* __restrict__ flag)
{
    int gb = blockIdx.x;
    int id = gb >> 9;
    const void* W = (id == 0) ? s0 : (id == 1) ? s1 : (id == 2) ? s2 : s3;
    _Float16* D = (id == 0) ? d0 : (id == 1) ? d1 : (id == 2) ? d2 : d3;
    int o = (gb & 511) * 256 + threadIdx.x;
    int t = o & 511;
    int c = (o >> 9) & 31;
    int j = o >> 14;
    int rid = t >> 1, hf = t & 1;
    int n = (rid >> 6) * 512 + j * 64 + (rid & 63);
    int k = hf * 256 + c * 8;
    int fl = *flag;
    _Float16* dst = D + (long)o * 8;
    #pragma unroll
    for (int jj = 0; jj < 8; jj++) {
        long si = (long)n * 512 + k + jj;
        float v = fl ? ((const float*)W)[si] : bf2f(((const u16*)W)[si]);
        dst[jj] = (_Float16)v;
    }
}

// ---------- NT GEMM ----------
__global__ __launch_bounds__(256) void gemm_nt_f32(
    const u16* __restrict__ A, int lda,
    const u16* __restrict__ Bw,
    const u16* __restrict__ bias0, const u16* __restrict__ bias1,
    float* __restrict__ C, int M, int N, int K, int ldc)
{
    __shared__ __align__(16) u16 As[64][40];
    __shared__ __align__(16) u16 Bs[64][40];
    const int tid = threadIdx.x;
    const int bn = blockIdx.x, bm = blockIdx.y;
    const int l = tid & 63, wid = tid >> 6;
    const int wm = wid >> 1, wn = wid & 1;
    const int lr = tid >> 2, lc = (tid & 3) * 8;
    const int l15 = l & 15, lq = l >> 4;

    floatx4 acc00 = (floatx4)(0.f), acc01 = (floatx4)(0.f), acc10 = (floatx4)(0.f), acc11 = (floatx4)(0.f);

    int am = bm * 64 + lr; if (am > M - 1) am = M - 1;
    const u16* Ap = A + (long)am * lda + lc;
    const u16* Bp = Bw + (long)(bn * 64 + lr) * K + lc;

    for (int k0 = 0; k0 < K; k0 += 32) {
        *(short8*)&As[lr][lc] = *(const short8*)(Ap + k0);
        *(short8*)&Bs[lr][lc] = *(const short8*)(Bp + k0);
        __syncthreads();
        short8 af0 = *(const short8*)&As[wm * 32 + l15][lq * 8];
        short8 af1 = *(const short8*)&As[wm * 32 + 16 + l15][lq * 8];
        short8 bf0 = *(const short8*)&Bs[wn * 32 + l15][lq * 8];
        short8 bf1 = *(const short8*)&Bs[wn * 32 + 16 + l15][lq * 8];
        acc00 = __builtin_amdgcn_mfma_f32_16x16x32_bf16(af0, bf0, acc00, 0, 0, 0);
        acc01 = __builtin_amdgcn_mfma_f32_16x16x32_bf16(af0, bf1, acc01, 0, 0, 0);
        acc10 = __builtin_amdgcn_mfma_f32_16x16x32_bf16(af1, bf0, acc10, 0, 0, 0);
        acc11 = __builtin_amdgcn_mfma_f32_16x16x32_bf16(af1, bf1, acc11, 0, 0, 0);
        __syncthreads();
    }
    floatx4 accs[2][2] = {{acc00, acc01}, {acc10, acc11}};
    #pragma unroll
    for (int i = 0; i < 2; i++)
        #pragma unroll
        for (int j = 0; j < 2; j++)
            #pragma unroll
            for (int r = 0; r < 4; r++) {
                int gm = bm * 64 + wm * 32 + i * 16 + lq * 4 + r;
                int gn = bn * 64 + wn * 32 + j * 16 + l15;
                if (gm < M) {
                    float v = accs[i][j][r];
                    if (bias0) v += bf2f(bias0[gn]);
                    if (bias1) v += bf2f(bias1[gn]);
                    C[(long)gm * ldc + gn] = v;
                }
            }
}

// ---------- conv3x3 as implicit-im2col NT GEMM ----------
__global__ __launch_bounds__(256) void conv_gemm(
    const u16* __restrict__ featP, const u16* __restrict__ W2,
    const u16* __restrict__ kb, u16* __restrict__ kmap)
{
    __shared__ __align__(16) u16 As[64][40];
    __shared__ __align__(16) u16 Bs[64][40];
    const int tid = threadIdx.x;
    const int bn = blockIdx.x, bm = blockIdx.y;
    const int l = tid & 63, wid = tid >> 6;
    const int wm = wid >> 1, wn = wid & 1;
    const int lr = tid >> 2, lc = (tid & 3) * 8;
    const int l15 = l & 15, lq = l >> 4;

    floatx4 acc00 = (floatx4)(0.f), acc01 = (floatx4)(0.f), acc10 = (floatx4)(0.f), acc11 = (floatx4)(0.f);

    int gm = bm * 64 + lr;
    int b = gm / 240;
    int hw = gm % 240;
    int h = hw / 40, w = hw % 40;
    const u16* fb = featP + (long)(b * 8) * 42 * 512;
    const u16* Bp = W2 + (long)(bn * 64 + lr) * 4608 + lc;

    for (int k0 = 0; k0 < 4608; k0 += 32) {
        int kh = k0 / 1536;
        int kw = (k0 % 1536) / 512;
        int ci0 = k0 & 511;
        const u16* ap = fb + ((long)((h + kh) * 42 + (w + kw))) * 512 + ci0 + lc;
        *(short8*)&As[lr][lc] = *(const short8*)ap;
        *(short8*)&Bs[lr][lc] = *(const short8*)(Bp + k0);
        __syncthreads();
        short8 af0 = *(const short8*)&As[wm * 32 + l15][lq * 8];
        short8 af1 = *(const short8*)&As[wm * 32 + 16 + l15][lq * 8];
        short8 bf0 = *(const short8*)&Bs[wn * 32 + l15][lq * 8];
        short8 bf1 = *(const short8*)&Bs[wn * 32 + 16 + l15][lq * 8];
        acc00 = __builtin_amdgcn_mfma_f32_16x16x32_bf16(af0, bf0, acc00, 0, 0, 0);
        acc01 = __builtin_amdgcn_mfma_f32_16x16x32_bf16(af0, bf1, acc01, 0, 0, 0);
        acc10 = __builtin_amdgcn_mfma_f32_16x16x32_bf16(af1, bf0, acc10, 0, 0, 0);
        acc11 = __builtin_amdgcn_mfma_f32_16x16x32_bf16(af1, bf1, acc11, 0, 0, 0);
        __syncthreads();
    }
    floatx4 accs[2][2] = {{acc00, acc01}, {acc10, acc11}};
    #pragma unroll
    for (int i = 0; i < 2; i++)
        #pragma unroll
        for (int j = 0; j < 2; j++)
            #pragma unroll
            for (int r = 0; r < 4; r++) {
                int om = bm * 64 + wm * 32 + i * 16 + lq * 4 + r;
                int on = bn * 64 + wn * 32 + j * 16 + l15;
                float v = accs[i][j][r] + bf2f(kb[on]);
                kmap[(long)om * 512 + on] = f2bf(v);
            }
}

// ---------- LSTM recurrence v4: sentinel self-announcing exchange ----------
// 256 blocks (b=batch, j=slice of 64 units), XCD-grouped. Weights pinned in
// unified RF (r5-verified mechanism, unchanged). hExT is T-indexed, written
// once per slot, sentinel-initialized. Producer: 32 relaxed agent stores, no
// ack/release/flag. Consumer: wave0's 64 lanes spin on their OWN 4 words of
// h(t-1) until != sentinel — poll result IS the data (1 visibility hop).
#define WL(F) F(0) F(1) F(2) F(3) F(4) F(5) F(6) F(7) F(8) F(9) F(10) F(11) F(12) F(13) F(14) F(15) \
              F(16) F(17) F(18) F(19) F(20) F(21) F(22) F(23) F(24) F(25) F(26) F(27) F(28) F(29) F(30) F(31)
#define WLA(F) F(0,0) F(1,1) F(2,2) F(3,3) F(4,0) F(5,1) F(6,2) F(7,3) \
               F(8,0) F(9,1) F(10,2) F(11,3) F(12,0) F(13,1) F(14,2) F(15,3) \
               F(16,0) F(17,1) F(18,2) F(19,3) F(20,0) F(21,1) F(22,2) F(23,3) \
               F(24,0) F(25,1) F(26,2) F(27,3) F(28,0) F(29,1) F(30,2) F(31,3)
#define WDECL(i) half8 w##i = wp8[(long)(j * 32 + i) * 512 + tid];
#define WPIN(i)  asm volatile("" : "+v"(w##i));
#define DOTC(i,k) { \
    half8 hv = *(const half8*)&hS2[(hf * 2 + (i / 16)) * 136 + (i % 16) * 8]; \
    a##k = __builtin_amdgcn_fdot2(__builtin_shufflevector(hv, hv, 0, 1), __builtin_shufflevector(w##i, w##i, 0, 1), a##k, false); \
    a##k = __builtin_amdgcn_fdot2(__builtin_shufflevector(hv, hv, 2, 3), __builtin_shufflevector(w##i, w##i, 2, 3), a##k, false); \
    a##k = __builtin_amdgcn_fdot2(__builtin_shufflevector(hv, hv, 4, 5), __builtin_shufflevector(w##i, w##i, 4, 5), a##k, false); \
    a##k = __builtin_amdgcn_fdot2(__builtin_shufflevector(hv, hv, 6, 7), __builtin_shufflevector(w##i, w##i, 6, 7), a##k, false); }

__global__ __launch_bounds__(512) __attribute__((amdgpu_waves_per_eu(2, 2))) void lstm_sync(
    const float* __restrict__ xpre, const _Float16* __restrict__ Wq3,
    u16* __restrict__ seq_out, float* __restrict__ f32_out,
    unsigned* __restrict__ hExT, int T, int f32_ld)
{
    const int i_ = blockIdx.x;
    const int slot = i_ >> 3;
    const int b = (i_ & 7) * 4 + (slot & 3);
    const int j = slot >> 2;
    const int tid = threadIdx.x;
    const int hf = tid & 1;

    __shared__ __align__(16) _Float16 hS2[4 * 136];
    __shared__ float part[512];

    const half8* wp8 = (const half8*)Wq3;
    WL(WDECL)
    WL(WPIN)
    float cst = 0.f;

    for (int t = 0; t < T; t++) {
        // prefetch x-side gate inputs (independent of h)
        float xi = 0.f, xf = 0.f, xg = 0.f, xo = 0.f;
        if (tid < 64) {
            const float* xp = xpre + ((long)b * T + t) * 2048 + j * 64 + tid;
            xi = xp[0]; xf = xp[512]; xg = xp[1024]; xo = xp[1536];
        }
        float a0 = 0.f, a1 = 0.f, a2 = 0.f, a3 = 0.f;
        if (t > 0) {
            if (tid < 64) {
                // spin on own 4 words of h(t-1); data doubles as readiness flag
                const unsigned* src = &hExT[((long)(t - 1) * 32 + b) * 256 + tid * 4];
                unsigned v0, v1, v2, v3;
                do {
                    v0 = __hip_atomic_load(src + 0, __ATOMIC_RELAXED, AGENT);
                    v1 = __hip_atomic_load(src + 1, __ATOMIC_RELAXED, AGENT);
                    v2 = __hip_atomic_load(src + 2, __ATOMIC_RELAXED, AGENT);
                    v3 = __hip_atomic_load(src + 3, __ATOMIC_RELAXED, AGENT);
                } while (v0 == SENT || v1 == SENT || v2 == SENT || v3 == SENT);
                uint4v v; v.x = v0; v.y = v1; v.z = v2; v.w = v3;
                *(uint4v*)&hS2[(tid >> 4) * 136 + (tid & 15) * 8] = v;
            }
            __syncthreads();
            WLA(DOTC)
        }
        part[tid] = (a0 + a1) + (a2 + a3);
        __syncthreads();
        if (tid < 64) {
            float gi = xi + part[(0   + tid) * 2] + part[(0   + tid) * 2 + 1];
            float gf = xf + part[(64  + tid) * 2] + part[(64  + tid) * 2 + 1];
            float gg = xg + part[(128 + tid) * 2] + part[(128 + tid) * 2 + 1];
            float go = xo + part[(192 + tid) * 2] + part[(192 + tid) * 2 + 1];
            cst = sigm_(gf) * cst + sigm_(gi) * tanh_(gg);
            float h = sigm_(go) * tanh_(cst);
            // publish immediately: data stores ARE the announcement
            float hlo = __shfl(h, tid * 2);
            float hhi = __shfl(h, tid * 2 + 1);
            if (t + 1 < T && tid < 32) {
                half2v hp; hp[0] = (_Float16)hlo; hp[1] = (_Float16)hhi;
                __hip_atomic_store(&hExT[((long)t * 32 + b) * 256 + j * 32 + tid],
                                   *(unsigned*)&hp, __ATOMIC_RELAXED, AGENT);
            }
            asm volatile("" ::: "memory");   // keep output stores below the publish
            long so = ((long)b * T + t) * 512 + j * 64 + tid;
            seq_out[so] = f2bf(h);
            if (f32_out) f32_out[((long)b * T + t) * f32_ld + j * 64 + tid] = h;
        }
    }
}

// ---------- token build ----------
__global__ __launch_bounds__(256) void tok_k(
    const float* __restrict__ holf, const u16* __restrict__ cemb,
    const int* __restrict__ label, u16* __restrict__ tok)
{
    int idx = blockIdx.x * 256 + threadIdx.x;
    int c = idx & 511;
    int m = idx >> 9;
    int b = m / 27, t = m % 27;
    float v;
    if (t == 0) v = holf[(long)b * 512 + c];
    else v = bf2f(cemb[(long)label[b * 26 + (t - 1)] * 512 + c]);
    tok[idx] = f2bf(v);
}

// ---------- fused score ----------
__global__ __launch_bounds__(256) void score_k(
    const float* __restrict__ q, const u16* __restrict__ kmap,
    const u16* __restrict__ sW, const u16* __restrict__ sb,
    const float* __restrict__ vr, float* __restrict__ aw)
{
    int bt = blockIdx.x;
    int b = bt / 27;
    int tid = threadIdx.x;
    __shared__ float qs[512];
    __shared__ float ss[512];
    __shared__ float red[256];
    qs[tid] = q[(long)bt * 512 + tid];
    qs[tid + 256] = q[(long)bt * 512 + tid + 256];
    ss[tid] = bf2f(sW[tid]);
    ss[tid + 256] = bf2f(sW[tid + 256]);
    __syncthreads();
    float sc = -INFINITY;
    float ex = 0.f;
    if (tid < 240) {
        const u16* kp = kmap + ((long)b * 240 + tid) * 512;
        float acc = 0.f;
        for (int c = 0; c < 512; c++) {
            float x = bf2f(kp[c]) + qs[c];
            acc = fmaf(ss[c], tanh_(x), acc);
        }
        acc += bf2f(sb[0]);
        float r = vr[b];
        int vw = (int)ceilf(40.f * r);
        if (vw > 40) vw = 40;
        int wcol = tid % 40;
        sc = (wcol >= vw) ? -INFINITY : acc;
    }
    red[tid] = sc;
    __syncthreads();
    for (int s = 128; s > 0; s >>= 1) {
        if (tid < s) red[tid] = fmaxf(red[tid], red[tid + s]);
        __syncthreads();
    }
    float mx = red[0];
    __syncthreads();
    if (tid < 240) ex = (sc == -INFINITY) ? 0.f : __expf(sc - mx);
    red[tid] = ex;
    __syncthreads();
    for (int s = 128; s > 0; s >>= 1) {
        if (tid < s) red[tid] += red[tid + s];
        __syncthreads();
    }
    float inv = 1.f / red[0];
    if (tid < 240) aw[(long)bt * 240 + tid] = ex * inv;
}

// ---------- attn_feat -> concat cols [512,1024) ----------
__global__ __launch_bounds__(256) void attn_k(
    const void* __restrict__ feat, const float* __restrict__ aw,
    float* __restrict__ concat, const int* __restrict__ flag)
{
    const int fl = *flag;
    int b = blockIdx.x >> 3;
    int cc = (blockIdx.x & 7) * 64;
    int tid = threadIdx.x;
    __shared__ float awS[27 * 240];
    __shared__ u16 fS[64 * 240];
    for (int i = tid; i < 27 * 240; i += 256) awS[i] = aw[(long)b * 27 * 240 + i];
    long fbase = ((long)b * 512 + cc) * 240;
    for (int i = tid; i < 64 * 240; i += 256)
        fS[i] = fl ? f2bf(((const float*)feat)[fbase + i]) : ((const u16*)feat)[fbase + i];
    __syncthreads();
    for (int item = tid; item < 64 * 27; item += 256) {
        int c = item / 27, t = item % 27;
        const u16* fp = &fS[c * 240];
        const float* ap = &awS[t * 240];
        float acc = 0.f;
        for (int hw = 0; hw < 240; hw++) acc = fmaf(bf2f(fp[hw]), ap[hw], acc);
        concat[((long)(b * 27 + t)) * 1536 + 512 + cc + c] = acc;
    }
}

// ---------- prediction + slice ----------
__global__ __launch_bounds__(256) void pred_k(
    const float* __restrict__ concat, const float* __restrict__ holf,
    const u16* __restrict__ pW, const u16* __restrict__ pb,
    void* __restrict__ out, const int* __restrict__ flag)
{
    int m0 = blockIdx.x * 4;
    int tid = threadIdx.x;
    const int fl = *flag;
    __shared__ float aS[4][1024];
    __shared__ float hS[4][512];
    for (int i = tid; i < 4 * 1024; i += 256)
        aS[i / 1024][i % 1024] = concat[(long)(m0 + i / 1024) * 1536 + (i % 1024)];
    for (int i = tid; i < 4 * 512; i += 256) {
        int m = m0 + i / 512;
        hS[i / 512][i % 512] = holf[(long)(m / 27) * 512 + (i % 512)];
    }
    __syncthreads();
    int r = tid >> 6;
    int nb = tid & 63;
    int m = m0 + r;
    int b = m / 27, t = m % 27;
    for (int n = nb; n < 97; n += 64) {
        const u16* wp = pW + (long)n * 1536;
        float acc = 0.f;
        for (int k = 0; k < 1024; k++) acc = fmaf(aS[r][k], bf2f(wp[k]), acc);
        for (int k = 0; k < 512; k++) acc = fmaf(hS[r][k], bf2f(wp[1024 + k]), acc);
        acc += bf2f(pb[n]);
        if (t > 0) {
            long o = ((long)(b * 26 + (t - 1))) * 97 + n;
            if (fl) ((float*)out)[o] = acc;
            else    ((u16*)out)[o] = f2bf(acc);
        }
    }
}

// ---------- launch ----------
extern "C" void kernel_launch(void* const* d_in, const int* in_sizes, int n_in,
                              void* d_out, int out_size, void* d_ws, size_t ws_size,
                              hipStream_t stream) {
    (void)in_sizes; (void)n_in; (void)out_size; (void)ws_size;
    const void* feat_r = d_in[0];
    const int*  label  = (const int*)d_in[1];
    const void* vr_r   = d_in[2];

    char* w = (char*)d_ws;
    size_t off = 0;
    auto alloc = [&](size_t bytes) -> void* {
        void* p = w + off;
        off = (off + bytes + 63) & ~(size_t)63;
        return p;
    };
    int*   flag    = (int*)  alloc(4);
    unsigned* hEx  = (unsigned*)alloc((size_t)HEX_WORDS * 4);   // 4.39 MB, T-indexed
    u16*   canon   = (u16*)  alloc((size_t)CANON_TOTAL * 2);
    float* cvr     = (float*)alloc(32ull * 4);
    u16*   featv   = (u16*)  alloc(655360ull * 2);
    float* xpre    = (float*)alloc(2621440ull * 4);   // kmap aliases after LSTMs
    u16*   seq0    = (u16*)  alloc(655360ull * 2);
    u16*   seq1    = (u16*)  alloc(655360ull * 2);
    u16*   tok     = (u16*)  alloc(442368ull * 2);
    u16*   seqd0   = (u16*)  alloc(442368ull * 2);
    u16*   Hid     = (u16*)  alloc(442368ull * 2);
    float* holf    = (float*)alloc(16384ull * 4);
    float* qf      = (float*)alloc(442368ull * 4);
    u16*   featP   = (u16*)  alloc(5505024ull * 2);
    u16*   W2      = (u16*)  alloc(2359296ull * 2);
    float* aw      = (float*)alloc(207360ull * 4);
    float* concat  = (float*)alloc(1327104ull * 4);
    _Float16* Wq[4];
    for (int i = 0; i < 4; i++) Wq[i] = (_Float16*)alloc(1048576ull * 2);
    u16*   kmap    = (u16*)xpre;

    // per-layer T-indexed hEx bases: 40+40+27+27 slots of 8192 words
    unsigned* hEx0 = hEx;
    unsigned* hEx1 = hEx + 40ull * 8192;
    unsigned* hEx2 = hEx + 80ull * 8192;
    unsigned* hEx3 = hEx + 107ull * 8192;

    u16* cW0    = canon + OFF_W0;
    u16* cW1    = canon + OFF_W1;
    u16* cW2    = canon + OFF_W2;
    u16* cW3    = canon + OFF_W3;
    u16* cb0    = canon + OFF_B;
    u16* cencW  = canon + OFF_ENCW;
    u16* cqW    = canon + OFF_QW;
    u16* cpredW = canon + OFF_PREDW;
    u16* cemb   = canon + OFF_EMB;
    u16* cencb  = canon + OFF_ENCB;
    u16* cqb    = canon + OFF_QB;
    u16* ckb    = canon + OFF_KB;
    u16* csW    = canon + OFF_SW;
    u16* csb    = canon + OFF_SB;
    u16* cpredb = canon + OFF_PREDB;

    // ---- init (sentinel fill + sniff) + canonicalize ----
    init_k<<<dim3(HEX_WORDS / 256), 256, 0, stream>>>(feat_r, flag, hEx);
    SrcPtrs S;
    S.e0Wih = d_in[3];  S.e1Wih = d_in[7];  S.d0Wih = d_in[20]; S.d1Wih = d_in[24];
    S.b0 = d_in[5];  S.b1 = d_in[6];  S.b2 = d_in[9];  S.b3 = d_in[10];
    S.b4 = d_in[22]; S.b5 = d_in[23]; S.b6 = d_in[26]; S.b7 = d_in[27];
    S.encW = d_in[11]; S.qW = d_in[13]; S.predW = d_in[28]; S.emb = d_in[19];
    S.encb = d_in[12]; S.qb = d_in[14]; S.kb = d_in[16]; S.sW = d_in[17];
    S.sb = d_in[18]; S.predb = d_in[29];
    canon_all<<<dim3((CANON_TOTAL + 255) / 256), 256, 0, stream>>>(S, canon, flag);
    canonf_k<<<dim3(1), 64, 0, stream>>>(vr_r, cvr, 32, flag);
    w2_k<<<dim3(9216), 256, 0, stream>>>(d_in[15], W2, flag);
    wq3_all<<<dim3(2048), 256, 0, stream>>>(d_in[4], d_in[8], d_in[21], d_in[25],
                                            Wq[0], Wq[1], Wq[2], Wq[3], flag);

    // ---- prep ----
    featv_k  <<<dim3(2560), 256, 0, stream>>>(feat_r, featv, flag);
    padfeat_k<<<dim3(21504), 256, 0, stream>>>(feat_r, featP, flag);

    // ---- encoder ----
    gemm_nt_f32<<<dim3(32, 20), 256, 0, stream>>>(featv, 512, cW0, cb0 + 0 * 2048, cb0 + 1 * 2048, xpre, 1280, 2048, 512, 2048);
    lstm_sync<<<dim3(256), 512, 0, stream>>>(xpre, Wq[0], seq0, nullptr, hEx0, 40, 0);
    gemm_nt_f32<<<dim3(32, 20), 256, 0, stream>>>(seq0, 512, cW1, cb0 + 2 * 2048, cb0 + 3 * 2048, xpre, 1280, 2048, 512, 2048);
    lstm_sync<<<dim3(256), 512, 0, stream>>>(xpre, Wq[1], seq1, nullptr, hEx1, 40, 0);
    gemm_nt_f32<<<dim3(8, 1), 256, 0, stream>>>(seq1 + 39 * 512, 40 * 512, cencW, cencb, nullptr, holf, 32, 512, 512, 512);

    // ---- decoder ----
    tok_k<<<dim3(1728), 256, 0, stream>>>(holf, cemb, label, tok);
    gemm_nt_f32<<<dim3(32, 14), 256, 0, stream>>>(tok, 512, cW2, cb0 + 4 * 2048, cb0 + 5 * 2048, xpre, 864, 2048, 512, 2048);
    lstm_sync<<<dim3(256), 512, 0, stream>>>(xpre, Wq[2], seqd0, nullptr, hEx2, 27, 0);
    gemm_nt_f32<<<dim3(32, 14), 256, 0, stream>>>(seqd0, 512, cW3, cb0 + 6 * 2048, cb0 + 7 * 2048, xpre, 864, 2048, 512, 2048);
    lstm_sync<<<dim3(256), 512, 0, stream>>>(xpre, Wq[3], Hid, concat, hEx3, 27, 1536);

    // ---- attention (xpre dead; kmap aliases it) ----
    gemm_nt_f32<<<dim3(8, 14), 256, 0, stream>>>(Hid, 512, cqW, cqb, nullptr, qf, 864, 512, 512, 512);
    conv_gemm<<<dim3(8, 120), 256, 0, stream>>>(featP, W2, ckb, kmap);
    score_k<<<dim3(864), 256, 0, stream>>>(qf, kmap, csW, csb, cvr, aw);
    attn_k<<<dim3(256), 256, 0, stream>>>(feat_r, aw, concat, flag);

    // ---- prediction ----
    pred_k<<<dim3(216), 256, 0, stream>>>(concat, holf, cpredW, cpredb, d_out, flag);
}

// Round 9
// 841.427 us; speedup vs baseline: 7.0443x; 1.0877x over previous
//
#include <hip/hip_runtime.h>

typedef unsigned short u16;
typedef __attribute__((ext_vector_type(8))) short short8;
typedef __attribute__((ext_vector_type(4))) float floatx4;
typedef _Float16 half8 __attribute__((ext_vector_type(8)));
typedef _Float16 half2v __attribute__((ext_vector_type(2)));
typedef unsigned uint4v __attribute__((ext_vector_type(4)));

#define AGENT __HIP_MEMORY_SCOPE_AGENT
#define SENT 0x7FFF7FFFu   // f16 NaN pair — unreachable: h = sigm*tanh in (-1,1)

// ---------- helpers ----------
__device__ __forceinline__ float bf2f(u16 v) { return __uint_as_float(((unsigned)v) << 16); }
__device__ __forceinline__ u16 f2bf(float f) {
    unsigned u = __float_as_uint(f);
    unsigned r = (u + 0x7FFFu + ((u >> 16) & 1u)) >> 16;
    return (u16)r;
}
// fast transcendentals: native v_exp + raw v_rcp (no precise-div sequence)
__device__ __forceinline__ float sigm_(float x) {
    return __builtin_amdgcn_rcpf(1.f + __expf(-x));
}
__device__ __forceinline__ float tanh_(float x) {
    x = fminf(fmaxf(x, -15.f), 15.f);
    float e = __expf(2.f * x);
    return (e - 1.f) * __builtin_amdgcn_rcpf(e + 1.f);
}

// B=32, C=512, H=6, W=40, NC=97, L=26, T=27
#define HEX_WORDS (134 * 32 * 256)

// ---------- init: sentinel-fill hEx + dtype sniff (one launch) ----------
__global__ void init_k(const void* __restrict__ feat_raw, int* __restrict__ flag,
                       unsigned* __restrict__ hEx) {
    int idx = blockIdx.x * 256 + threadIdx.x;
    hEx[idx] = SENT;
    if (idx == 0) {
        const u16* p = (const u16*)feat_raw;
        int insane = 0;
        #pragma unroll
        for (int i = 0; i < 32; i += 2) {
            float x = bf2f(p[i]);
            float a = fabsf(x);
            if (!(a <= 1000.f)) insane = 1;
            if (x != 0.f && a < 1e-8f) insane = 1;
        }
        *flag = insane;
    }
}

// ---------- one-shot canonicalization ----------
struct SrcPtrs {
    const void* e0Wih; const void* e1Wih; const void* d0Wih; const void* d1Wih;
    const void* b0; const void* b1; const void* b2; const void* b3;
    const void* b4; const void* b5; const void* b6; const void* b7;
    const void* encW; const void* qW; const void* predW; const void* emb;
    const void* encb; const void* qb; const void* kb; const void* sW;
    const void* sb; const void* predb;
};
#define OFF_W0      0
#define OFF_W1      1048576
#define OFF_W2      2097152
#define OFF_W3      3145728
#define OFF_B       4194304
#define OFF_ENCW    4210688
#define OFF_QW      4472832
#define OFF_PREDW   4734976
#define OFF_EMB     4883968
#define OFF_ENCB    4933632
#define OFF_QB      4934144
#define OFF_KB      4934656
#define OFF_SW      4935168
#define OFF_SB      4935680
#define OFF_PREDB   4935681
#define CANON_TOTAL 4935778

__global__ __launch_bounds__(256) void canon_all(SrcPtrs S, u16* __restrict__ dst,
                                                 const int* __restrict__ flag) {
    int idx = blockIdx.x * 256 + threadIdx.x;
    if (idx >= CANON_TOTAL) return;
    const void* s; int loc;
    if (idx < OFF_B) {
        int k = idx >> 20; loc = idx & 1048575;
        s = (k == 0) ? S.e0Wih : (k == 1) ? S.e1Wih : (k == 2) ? S.d0Wih : S.d1Wih;
    } else if (idx < OFF_ENCW) {
        int r = idx - OFF_B; int k = r >> 11; loc = r & 2047;
        s = (k == 0) ? S.b0 : (k == 1) ? S.b1 : (k == 2) ? S.b2 : (k == 3) ? S.b3
          : (k == 4) ? S.b4 : (k == 5) ? S.b5 : (k == 6) ? S.b6 : S.b7;
    } else if (idx < OFF_QW)    { s = S.encW;  loc = idx - OFF_ENCW; }
    else if (idx < OFF_PREDW)   { s = S.qW;    loc = idx - OFF_QW; }
    else if (idx < OFF_EMB)     { s = S.predW; loc = idx - OFF_PREDW; }
    else if (idx < OFF_ENCB)    { s = S.emb;   loc = idx - OFF_EMB; }
    else if (idx < OFF_QB)      { s = S.encb;  loc = idx - OFF_ENCB; }
    else if (idx < OFF_KB)      { s = S.qb;    loc = idx - OFF_QB; }
    else if (idx < OFF_SW)      { s = S.kb;    loc = idx - OFF_KB; }
    else if (idx < OFF_SB)      { s = S.sW;    loc = idx - OFF_SW; }
    else if (idx < OFF_PREDB)   { s = S.sb;    loc = idx - OFF_SB; }
    else                        { s = S.predb; loc = idx - OFF_PREDB; }
    dst[idx] = (*flag) ? f2bf(((const float*)s)[loc]) : ((const u16*)s)[loc];
}

__global__ __launch_bounds__(64) void canonf_k(const void* __restrict__ src, float* __restrict__ dst,
                                               int n, const int* __restrict__ flag) {
    int i = blockIdx.x * 64 + threadIdx.x;
    if (i >= n) return;
    dst[i] = (*flag) ? ((const float*)src)[i] : bf2f(((const u16*)src)[i]);
}

// ---------- prep kernels ----------
__device__ __forceinline__ float rdf(const void* p, long i, int fl) {
    return fl ? ((const float*)p)[i] : bf2f(((const u16*)p)[i]);
}

__global__ __launch_bounds__(256) void featv_k(const void* __restrict__ feat, u16* __restrict__ featv,
                                               const int* __restrict__ flag) {
    const int fl = *flag;
    int idx = blockIdx.x * 256 + threadIdx.x;
    int c = idx & 511;
    int r = idx >> 9;
    int w = r % 40, b = r / 40;
    float mx = -1e30f;
    long base = ((long)(b * 512 + c) * 6) * 40 + w;
    #pragma unroll
    for (int h = 0; h < 6; h++) mx = fmaxf(mx, rdf(feat, base + h * 40, fl));
    featv[idx] = f2bf(mx);
}

__global__ __launch_bounds__(256) void padfeat_k(const void* __restrict__ feat, u16* __restrict__ featP,
                                                 const int* __restrict__ flag) {
    const int fl = *flag;
    int idx = blockIdx.x * 256 + threadIdx.x;
    int c = idx & 511;
    int r = idx >> 9;
    int wp = r % 42; int r2 = r / 42;
    int hp = r2 & 7; int b = r2 >> 3;
    u16 v = 0;
    if (hp >= 1 && hp <= 6 && wp >= 1 && wp <= 40) {
        long si = ((long)(b * 512 + c) * 6 + (hp - 1)) * 40 + (wp - 1);
        v = fl ? f2bf(((const float*)feat)[si]) : ((const u16*)feat)[si];
    }
    featP[idx] = v;
}

__global__ __launch_bounds__(256) void w2_k(const void* __restrict__ kW, u16* __restrict__ W2,
                                            const int* __restrict__ flag) {
    int idx = blockIdx.x * 256 + threadIdx.x;
    int co = idx / 4608;
    int r = idx % 4608;
    int kh = r / 1536;
    int r2 = r % 1536;
    int kw = r2 / 512;
    int ci = r2 & 511;
    long si = ((long)(co * 512 + ci) * 3 + kh) * 3 + kw;
    W2[idx] = (*flag) ? f2bf(((const float*)kW)[si]) : ((const u16*)kW)[si];
}

__global__ __launch_bounds__(256) void wq3_all(
    const void* __restrict__ s0, const void* __restrict__ s1,
    const void* __restrict__ s2, const void* __restrict__ s3,
    _Float16* __restrict__ d0, _Float16* __restrict__ d1,
    _Float16* __restrict__ d2, _Float16* __restrict__ d3,
    const int* __restrict__ flag)
{
    int gb = blockIdx.x;
    int id = gb >> 9;
    const void* W = (id == 0) ? s0 : (id == 1) ? s1 : (id == 2) ? s2 : s3;
    _Float16* D = (id == 0) ? d0 : (id == 1) ? d1 : (id == 2) ? d2 : d3;
    int o = (gb & 511) * 256 + threadIdx.x;
    int t = o & 511;
    int c = (o >> 9) & 31;
    int j = o >> 14;
    int rid = t >> 1, hf = t & 1;
    int n = (rid >> 6) * 512 + j * 64 + (rid & 63);
    int k = hf * 256 + c * 8;
    int fl = *flag;
    _Float16* dst = D + (long)o * 8;
    #pragma unroll
    for (int jj = 0; jj < 8; jj++) {
        long si = (long)n * 512 + k + jj;
        float v = fl ? ((const float*)W)[si] : bf2f(((const u16*)W)[si]);
        dst[jj] = (_Float16)v;
    }
}

// ---------- NT GEMM ----------
__global__ __launch_bounds__(256) void gemm_nt_f32(
    const u16* __restrict__ A, int lda,
    const u16* __restrict__ Bw,
    const u16* __restrict__ bias0, const u16* __restrict__ bias1,
    float* __restrict__ C, int M, int N, int K, int ldc)
{
    __shared__ __align__(16) u16 As[64][40];
    __shared__ __align__(16) u16 Bs[64][40];
    const int tid = threadIdx.x;
    const int bn = blockIdx.x, bm = blockIdx.y;
    const int l = tid & 63, wid = tid >> 6;
    const int wm = wid >> 1, wn = wid & 1;
    const int lr = tid >> 2, lc = (tid & 3) * 8;
    const int l15 = l & 15, lq = l >> 4;

    floatx4 acc00 = (floatx4)(0.f), acc01 = (floatx4)(0.f), acc10 = (floatx4)(0.f), acc11 = (floatx4)(0.f);

    int am = bm * 64 + lr; if (am > M - 1) am = M - 1;
    const u16* Ap = A + (long)am * lda + lc;
    const u16* Bp = Bw + (long)(bn * 64 + lr) * K + lc;

    for (int k0 = 0; k0 < K; k0 += 32) {
        *(short8*)&As[lr][lc] = *(const short8*)(Ap + k0);
        *(short8*)&Bs[lr][lc] = *(const short8*)(Bp + k0);
        __syncthreads();
        short8 af0 = *(const short8*)&As[wm * 32 + l15][lq * 8];
        short8 af1 = *(const short8*)&As[wm * 32 + 16 + l15][lq * 8];
        short8 bf0 = *(const short8*)&Bs[wn * 32 + l15][lq * 8];
        short8 bf1 = *(const short8*)&Bs[wn * 32 + 16 + l15][lq * 8];
        acc00 = __builtin_amdgcn_mfma_f32_16x16x32_bf16(af0, bf0, acc00, 0, 0, 0);
        acc01 = __builtin_amdgcn_mfma_f32_16x16x32_bf16(af0, bf1, acc01, 0, 0, 0);
        acc10 = __builtin_amdgcn_mfma_f32_16x16x32_bf16(af1, bf0, acc10, 0, 0, 0);
        acc11 = __builtin_amdgcn_mfma_f32_16x16x32_bf16(af1, bf1, acc11, 0, 0, 0);
        __syncthreads();
    }
    floatx4 accs[2][2] = {{acc00, acc01}, {acc10, acc11}};
    #pragma unroll
    for (int i = 0; i < 2; i++)
        #pragma unroll
        for (int j = 0; j < 2; j++)
            #pragma unroll
            for (int r = 0; r < 4; r++) {
                int gm = bm * 64 + wm * 32 + i * 16 + lq * 4 + r;
                int gn = bn * 64 + wn * 32 + j * 16 + l15;
                if (gm < M) {
                    float v = accs[i][j][r];
                    if (bias0) v += bf2f(bias0[gn]);
                    if (bias1) v += bf2f(bias1[gn]);
                    C[(long)gm * ldc + gn] = v;
                }
            }
}

// ---------- conv3x3 as implicit-im2col NT GEMM ----------
__global__ __launch_bounds__(256) void conv_gemm(
    const u16* __restrict__ featP, const u16* __restrict__ W2,
    const u16* __restrict__ kb, u16* __restrict__ kmap)
{
    __shared__ __align__(16) u16 As[64][40];
    __shared__ __align__(16) u16 Bs[64][40];
    const int tid = threadIdx.x;
    const int bn = blockIdx.x, bm = blockIdx.y;
    const int l = tid & 63, wid = tid >> 6;
    const int wm = wid >> 1, wn = wid & 1;
    const int lr = tid >> 2, lc = (tid & 3) * 8;
    const int l15 = l & 15, lq = l >> 4;

    floatx4 acc00 = (floatx4)(0.f), acc01 = (floatx4)(0.f), acc10 = (floatx4)(0.f), acc11 = (floatx4)(0.f);

    int gm = bm * 64 + lr;
    int b = gm / 240;
    int hw = gm % 240;
    int h = hw / 40, w = hw % 40;
    const u16* fb = featP + (long)(b * 8) * 42 * 512;
    const u16* Bp = W2 + (long)(bn * 64 + lr) * 4608 + lc;

    for (int k0 = 0; k0 < 4608; k0 += 32) {
        int kh = k0 / 1536;
        int kw = (k0 % 1536) / 512;
        int ci0 = k0 & 511;
        const u16* ap = fb + ((long)((h + kh) * 42 + (w + kw))) * 512 + ci0 + lc;
        *(short8*)&As[lr][lc] = *(const short8*)ap;
        *(short8*)&Bs[lr][lc] = *(const short8*)(Bp + k0);
        __syncthreads();
        short8 af0 = *(const short8*)&As[wm * 32 + l15][lq * 8];
        short8 af1 = *(const short8*)&As[wm * 32 + 16 + l15][lq * 8];
        short8 bf0 = *(const short8*)&Bs[wn * 32 + l15][lq * 8];
        short8 bf1 = *(const short8*)&Bs[wn * 32 + 16 + l15][lq * 8];
        acc00 = __builtin_amdgcn_mfma_f32_16x16x32_bf16(af0, bf0, acc00, 0, 0, 0);
        acc01 = __builtin_amdgcn_mfma_f32_16x16x32_bf16(af0, bf1, acc01, 0, 0, 0);
        acc10 = __builtin_amdgcn_mfma_f32_16x16x32_bf16(af1, bf0, acc10, 0, 0, 0);
        acc11 = __builtin_amdgcn_mfma_f32_16x16x32_bf16(af1, bf1, acc11, 0, 0, 0);
        __syncthreads();
    }
    floatx4 accs[2][2] = {{acc00, acc01}, {acc10, acc11}};
    #pragma unroll
    for (int i = 0; i < 2; i++)
        #pragma unroll
        for (int j = 0; j < 2; j++)
            #pragma unroll
            for (int r = 0; r < 4; r++) {
                int om = bm * 64 + wm * 32 + i * 16 + lq * 4 + r;
                int on = bn * 64 + wn * 32 + j * 16 + l15;
                float v = accs[i][j][r] + bf2f(kb[on]);
                kmap[(long)om * 512 + on] = f2bf(v);
            }
}

// ---------- LSTM recurrence v4: sentinel self-announcing exchange (r8-verified) ----------
#define WL(F) F(0) F(1) F(2) F(3) F(4) F(5) F(6) F(7) F(8) F(9) F(10) F(11) F(12) F(13) F(14) F(15) \
              F(16) F(17) F(18) F(19) F(20) F(21) F(22) F(23) F(24) F(25) F(26) F(27) F(28) F(29) F(30) F(31)
#define WLA(F) F(0,0) F(1,1) F(2,2) F(3,3) F(4,0) F(5,1) F(6,2) F(7,3) \
               F(8,0) F(9,1) F(10,2) F(11,3) F(12,0) F(13,1) F(14,2) F(15,3) \
               F(16,0) F(17,1) F(18,2) F(19,3) F(20,0) F(21,1) F(22,2) F(23,3) \
               F(24,0) F(25,1) F(26,2) F(27,3) F(28,0) F(29,1) F(30,2) F(31,3)
#define WDECL(i) half8 w##i = wp8[(long)(j * 32 + i) * 512 + tid];
#define WPIN(i)  asm volatile("" : "+v"(w##i));
#define DOTC(i,k) { \
    half8 hv = *(const half8*)&hS2[(hf * 2 + (i / 16)) * 136 + (i % 16) * 8]; \
    a##k = __builtin_amdgcn_fdot2(__builtin_shufflevector(hv, hv, 0, 1), __builtin_shufflevector(w##i, w##i, 0, 1), a##k, false); \
    a##k = __builtin_amdgcn_fdot2(__builtin_shufflevector(hv, hv, 2, 3), __builtin_shufflevector(w##i, w##i, 2, 3), a##k, false); \
    a##k = __builtin_amdgcn_fdot2(__builtin_shufflevector(hv, hv, 4, 5), __builtin_shufflevector(w##i, w##i, 4, 5), a##k, false); \
    a##k = __builtin_amdgcn_fdot2(__builtin_shufflevector(hv, hv, 6, 7), __builtin_shufflevector(w##i, w##i, 6, 7), a##k, false); }

__global__ __launch_bounds__(512) __attribute__((amdgpu_waves_per_eu(2, 2))) void lstm_sync(
    const float* __restrict__ xpre, const _Float16* __restrict__ Wq3,
    u16* __restrict__ seq_out, float* __restrict__ f32_out,
    unsigned* __restrict__ hExT, int T, int f32_ld)
{
    const int i_ = blockIdx.x;
    const int slot = i_ >> 3;
    const int b = (i_ & 7) * 4 + (slot & 3);
    const int j = slot >> 2;
    const int tid = threadIdx.x;
    const int hf = tid & 1;

    __shared__ __align__(16) _Float16 hS2[4 * 136];
    __shared__ float part[512];

    const half8* wp8 = (const half8*)Wq3;
    WL(WDECL)
    WL(WPIN)
    float cst = 0.f;

    for (int t = 0; t < T; t++) {
        float xi = 0.f, xf = 0.f, xg = 0.f, xo = 0.f;
        if (tid < 64) {
            const float* xp = xpre + ((long)b * T + t) * 2048 + j * 64 + tid;
            xi = xp[0]; xf = xp[512]; xg = xp[1024]; xo = xp[1536];
        }
        float a0 = 0.f, a1 = 0.f, a2 = 0.f, a3 = 0.f;
        if (t > 0) {
            if (tid < 64) {
                const unsigned* src = &hExT[((long)(t - 1) * 32 + b) * 256 + tid * 4];
                unsigned v0, v1, v2, v3;
                do {
                    v0 = __hip_atomic_load(src + 0, __ATOMIC_RELAXED, AGENT);
                    v1 = __hip_atomic_load(src + 1, __ATOMIC_RELAXED, AGENT);
                    v2 = __hip_atomic_load(src + 2, __ATOMIC_RELAXED, AGENT);
                    v3 = __hip_atomic_load(src + 3, __ATOMIC_RELAXED, AGENT);
                } while (v0 == SENT || v1 == SENT || v2 == SENT || v3 == SENT);
                uint4v v; v.x = v0; v.y = v1; v.z = v2; v.w = v3;
                *(uint4v*)&hS2[(tid >> 4) * 136 + (tid & 15) * 8] = v;
            }
            __syncthreads();
            WLA(DOTC)
        }
        part[tid] = (a0 + a1) + (a2 + a3);
        __syncthreads();
        if (tid < 64) {
            float gi = xi + part[(0   + tid) * 2] + part[(0   + tid) * 2 + 1];
            float gf = xf + part[(64  + tid) * 2] + part[(64  + tid) * 2 + 1];
            float gg = xg + part[(128 + tid) * 2] + part[(128 + tid) * 2 + 1];
            float go = xo + part[(192 + tid) * 2] + part[(192 + tid) * 2 + 1];
            cst = sigm_(gf) * cst + sigm_(gi) * tanh_(gg);
            float h = sigm_(go) * tanh_(cst);
            float hlo = __shfl(h, tid * 2);
            float hhi = __shfl(h, tid * 2 + 1);
            if (t + 1 < T && tid < 32) {
                half2v hp; hp[0] = (_Float16)hlo; hp[1] = (_Float16)hhi;
                __hip_atomic_store(&hExT[((long)t * 32 + b) * 256 + j * 32 + tid],
                                   *(unsigned*)&hp, __ATOMIC_RELAXED, AGENT);
            }
            asm volatile("" ::: "memory");
            long so = ((long)b * T + t) * 512 + j * 64 + tid;
            seq_out[so] = f2bf(h);
            if (f32_out) f32_out[((long)b * T + t) * f32_ld + j * 64 + tid] = h;
        }
    }
}

// ---------- token build ----------
__global__ __launch_bounds__(256) void tok_k(
    const float* __restrict__ holf, const u16* __restrict__ cemb,
    const int* __restrict__ label, u16* __restrict__ tok)
{
    int idx = blockIdx.x * 256 + threadIdx.x;
    int c = idx & 511;
    int m = idx >> 9;
    int b = m / 27, t = m % 27;
    float v;
    if (t == 0) v = holf[(long)b * 512 + c];
    else v = bf2f(cemb[(long)label[b * 26 + (t - 1)] * 512 + c]);
    tok[idx] = f2bf(v);
}

// ---------- fused score v2: lanes own channels (regs), coalesced k rows, wave-reduce ----------
// Grid 864 = 8 xcd x 4 bq x 27 t (same-batch blocks share an XCD for kmap L2 reuse).
// Lane ln owns c = ln*8..+8: q,sW in 16 VGPRs, zero LDS in hot loop. Per row:
// one coalesced short8 load (wave covers the whole 1KB row), 8x(tanh+fma), 6-step
// shfl_xor reduce. tanh = (e-1)*v_rcp(e+1) — no precise-div sequence.
__global__ __launch_bounds__(256) void score_k(
    const float* __restrict__ q, const u16* __restrict__ kmap,
    const u16* __restrict__ sW, const u16* __restrict__ sb,
    const float* __restrict__ vr, float* __restrict__ aw)
{
    int blk = blockIdx.x;
    int xcd = blk & 7, rest = blk >> 3;
    int bq = rest & 3, t = rest >> 2;       // t in 0..26
    int b = xcd * 4 + bq;
    int bt = b * 27 + t;
    int tid = threadIdx.x, wv = tid >> 6, ln = tid & 63;

    __shared__ float sc[240];
    __shared__ float red[256];

    float qr[8], sr[8];
    const float* qp = q + (long)bt * 512 + ln * 8;
    #pragma unroll
    for (int i = 0; i < 8; i++) qr[i] = qp[i];
    #pragma unroll
    for (int i = 0; i < 8; i++) sr[i] = bf2f(sW[ln * 8 + i]);

    const u16* kb_ = kmap + (long)b * 240 * 512;
    for (int r = wv * 60; r < wv * 60 + 60; r++) {
        short8 kv = *(const short8*)(kb_ + (long)r * 512 + ln * 8);
        float acc = 0.f;
        #pragma unroll
        for (int i = 0; i < 8; i++) {
            float x = bf2f((u16)kv[i]) + qr[i];
            acc = fmaf(sr[i], tanh_(x), acc);
        }
        #pragma unroll
        for (int m = 32; m > 0; m >>= 1) acc += __shfl_xor(acc, m);
        if (ln == 0) sc[r] = acc;
    }
    __syncthreads();

    float scv = -INFINITY, ex = 0.f;
    if (tid < 240) {
        float rr = vr[b];
        int vw = (int)ceilf(40.f * rr);
        if (vw > 40) vw = 40;
        int wcol = tid % 40;
        scv = (wcol >= vw) ? -INFINITY : (sc[tid] + bf2f(sb[0]));
    }
    red[tid] = scv;
    __syncthreads();
    for (int s = 128; s > 0; s >>= 1) {
        if (tid < s) red[tid] = fmaxf(red[tid], red[tid + s]);
        __syncthreads();
    }
    float mx = red[0];
    __syncthreads();
    if (tid < 240) ex = (scv == -INFINITY) ? 0.f : __expf(scv - mx);
    red[tid] = ex;
    __syncthreads();
    for (int s = 128; s > 0; s >>= 1) {
        if (tid < s) red[tid] += red[tid + s];
        __syncthreads();
    }
    float inv = __builtin_amdgcn_rcpf(red[0]);
    if (tid < 240) aw[(long)bt * 240 + tid] = ex * inv;
}

// ---------- attn_feat -> concat cols [512,1024) ----------
__global__ __launch_bounds__(256) void attn_k(
    const void* __restrict__ feat, const float* __restrict__ aw,
    float* __restrict__ concat, const int* __restrict__ flag)
{
    const int fl = *flag;
    int b = blockIdx.x >> 3;
    int cc = (blockIdx.x & 7) * 64;
    int tid = threadIdx.x;
    __shared__ float awS[27 * 240];
    __shared__ u16 fS[64 * 240];
    for (int i = tid; i < 27 * 240; i += 256) awS[i] = aw[(long)b * 27 * 240 + i];
    long fbase = ((long)b * 512 + cc) * 240;
    for (int i = tid; i < 64 * 240; i += 256)
        fS[i] = fl ? f2bf(((const float*)feat)[fbase + i]) : ((const u16*)feat)[fbase + i];
    __syncthreads();
    for (int item = tid; item < 64 * 27; item += 256) {
        int c = item / 27, t = item % 27;
        const u16* fp = &fS[c * 240];
        const float* ap = &awS[t * 240];
        float acc = 0.f;
        for (int hw = 0; hw < 240; hw++) acc = fmaf(bf2f(fp[hw]), ap[hw], acc);
        concat[((long)(b * 27 + t)) * 1536 + 512 + cc + c] = acc;
    }
}

// ---------- prediction + slice ----------
__global__ __launch_bounds__(256) void pred_k(
    const float* __restrict__ concat, const float* __restrict__ holf,
    const u16* __restrict__ pW, const u16* __restrict__ pb,
    void* __restrict__ out, const int* __restrict__ flag)
{
    int m0 = blockIdx.x * 4;
    int tid = threadIdx.x;
    const int fl = *flag;
    __shared__ float aS[4][1024];
    __shared__ float hS[4][512];
    for (int i = tid; i < 4 * 1024; i += 256)
        aS[i / 1024][i % 1024] = concat[(long)(m0 + i / 1024) * 1536 + (i % 1024)];
    for (int i = tid; i < 4 * 512; i += 256) {
        int m = m0 + i / 512;
        hS[i / 512][i % 512] = holf[(long)(m / 27) * 512 + (i % 512)];
    }
    __syncthreads();
    int r = tid >> 6;
    int nb = tid & 63;
    int m = m0 + r;
    int b = m / 27, t = m % 27;
    for (int n = nb; n < 97; n += 64) {
        const u16* wp = pW + (long)n * 1536;
        float acc = 0.f;
        for (int k = 0; k < 1024; k++) acc = fmaf(aS[r][k], bf2f(wp[k]), acc);
        for (int k = 0; k < 512; k++) acc = fmaf(hS[r][k], bf2f(wp[1024 + k]), acc);
        acc += bf2f(pb[n]);
        if (t > 0) {
            long o = ((long)(b * 26 + (t - 1))) * 97 + n;
            if (fl) ((float*)out)[o] = acc;
            else    ((u16*)out)[o] = f2bf(acc);
        }
    }
}

// ---------- launch ----------
extern "C" void kernel_launch(void* const* d_in, const int* in_sizes, int n_in,
                              void* d_out, int out_size, void* d_ws, size_t ws_size,
                              hipStream_t stream) {
    (void)in_sizes; (void)n_in; (void)out_size; (void)ws_size;
    const void* feat_r = d_in[0];
    const int*  label  = (const int*)d_in[1];
    const void* vr_r   = d_in[2];

    char* w = (char*)d_ws;
    size_t off = 0;
    auto alloc = [&](size_t bytes) -> void* {
        void* p = w + off;
        off = (off + bytes + 63) & ~(size_t)63;
        return p;
    };
    int*   flag    = (int*)  alloc(4);
    unsigned* hEx  = (unsigned*)alloc((size_t)HEX_WORDS * 4);
    u16*   canon   = (u16*)  alloc((size_t)CANON_TOTAL * 2);
    float* cvr     = (float*)alloc(32ull * 4);
    u16*   featv   = (u16*)  alloc(655360ull * 2);
    float* xpre    = (float*)alloc(2621440ull * 4);   // kmap aliases after LSTMs
    u16*   seq0    = (u16*)  alloc(655360ull * 2);
    u16*   seq1    = (u16*)  alloc(655360ull * 2);
    u16*   tok     = (u16*)  alloc(442368ull * 2);
    u16*   seqd0   = (u16*)  alloc(442368ull * 2);
    u16*   Hid     = (u16*)  alloc(442368ull * 2);
    float* holf    = (float*)alloc(16384ull * 4);
    float* qf      = (float*)alloc(442368ull * 4);
    u16*   featP   = (u16*)  alloc(5505024ull * 2);
    u16*   W2      = (u16*)  alloc(2359296ull * 2);
    float* aw      = (float*)alloc(207360ull * 4);
    float* concat  = (float*)alloc(1327104ull * 4);
    _Float16* Wq[4];
    for (int i = 0; i < 4; i++) Wq[i] = (_Float16*)alloc(1048576ull * 2);
    u16*   kmap    = (u16*)xpre;

    unsigned* hEx0 = hEx;
    unsigned* hEx1 = hEx + 40ull * 8192;
    unsigned* hEx2 = hEx + 80ull * 8192;
    unsigned* hEx3 = hEx + 107ull * 8192;

    u16* cW0    = canon + OFF_W0;
    u16* cW1    = canon + OFF_W1;
    u16* cW2    = canon + OFF_W2;
    u16* cW3    = canon + OFF_W3;
    u16* cb0    = canon + OFF_B;
    u16* cencW  = canon + OFF_ENCW;
    u16* cqW    = canon + OFF_QW;
    u16* cpredW = canon + OFF_PREDW;
    u16* cemb   = canon + OFF_EMB;
    u16* cencb  = canon + OFF_ENCB;
    u16* cqb    = canon + OFF_QB;
    u16* ckb    = canon + OFF_KB;
    u16* csW    = canon + OFF_SW;
    u16* csb    = canon + OFF_SB;
    u16* cpredb = canon + OFF_PREDB;

    // ---- init (sentinel fill + sniff) + canonicalize ----
    init_k<<<dim3(HEX_WORDS / 256), 256, 0, stream>>>(feat_r, flag, hEx);
    SrcPtrs S;
    S.e0Wih = d_in[3];  S.e1Wih = d_in[7];  S.d0Wih = d_in[20]; S.d1Wih = d_in[24];
    S.b0 = d_in[5];  S.b1 = d_in[6];  S.b2 = d_in[9];  S.b3 = d_in[10];
    S.b4 = d_in[22]; S.b5 = d_in[23]; S.b6 = d_in[26]; S.b7 = d_in[27];
    S.encW = d_in[11]; S.qW = d_in[13]; S.predW = d_in[28]; S.emb = d_in[19];
    S.encb = d_in[12]; S.qb = d_in[14]; S.kb = d_in[16]; S.sW = d_in[17];
    S.sb = d_in[18]; S.predb = d_in[29];
    canon_all<<<dim3((CANON_TOTAL + 255) / 256), 256, 0, stream>>>(S, canon, flag);
    canonf_k<<<dim3(1), 64, 0, stream>>>(vr_r, cvr, 32, flag);
    w2_k<<<dim3(9216), 256, 0, stream>>>(d_in[15], W2, flag);
    wq3_all<<<dim3(2048), 256, 0, stream>>>(d_in[4], d_in[8], d_in[21], d_in[25],
                                            Wq[0], Wq[1], Wq[2], Wq[3], flag);

    // ---- prep ----
    featv_k  <<<dim3(2560), 256, 0, stream>>>(feat_r, featv, flag);
    padfeat_k<<<dim3(21504), 256, 0, stream>>>(feat_r, featP, flag);

    // ---- encoder ----
    gemm_nt_f32<<<dim3(32, 20), 256, 0, stream>>>(featv, 512, cW0, cb0 + 0 * 2048, cb0 + 1 * 2048, xpre, 1280, 2048, 512, 2048);
    lstm_sync<<<dim3(256), 512, 0, stream>>>(xpre, Wq[0], seq0, nullptr, hEx0, 40, 0);
    gemm_nt_f32<<<dim3(32, 20), 256, 0, stream>>>(seq0, 512, cW1, cb0 + 2 * 2048, cb0 + 3 * 2048, xpre, 1280, 2048, 512, 2048);
    lstm_sync<<<dim3(256), 512, 0, stream>>>(xpre, Wq[1], seq1, nullptr, hEx1, 40, 0);
    gemm_nt_f32<<<dim3(8, 1), 256, 0, stream>>>(seq1 + 39 * 512, 40 * 512, cencW, cencb, nullptr, holf, 32, 512, 512, 512);

    // ---- decoder ----
    tok_k<<<dim3(1728), 256, 0, stream>>>(holf, cemb, label, tok);
    gemm_nt_f32<<<dim3(32, 14), 256, 0, stream>>>(tok, 512, cW2, cb0 + 4 * 2048, cb0 + 5 * 2048, xpre, 864, 2048, 512, 2048);
    lstm_sync<<<dim3(256), 512, 0, stream>>>(xpre, Wq[2], seqd0, nullptr, hEx2, 27, 0);
    gemm_nt_f32<<<dim3(32, 14), 256, 0, stream>>>(seqd0, 512, cW3, cb0 + 6 * 2048, cb0 + 7 * 2048, xpre, 864, 2048, 512, 2048);
    lstm_sync<<<dim3(256), 512, 0, stream>>>(xpre, Wq[3], Hid, concat, hEx3, 27, 1536);

    // ---- attention (xpre dead; kmap aliases it) ----
    gemm_nt_f32<<<dim3(8, 14), 256, 0, stream>>>(Hid, 512, cqW, cqb, nullptr, qf, 864, 512, 512, 512);
    conv_gemm<<<dim3(8, 120), 256, 0, stream>>>(featP, W2, ckb, kmap);
    score_k<<<dim3(864), 256, 0, stream>>>(qf, kmap, csW, csb, cvr, aw);
    attn_k<<<dim3(256), 256, 0, stream>>>(feat_r, aw, concat, flag);

    // ---- prediction ----
    pred_k<<<dim3(216), 256, 0, stream>>>(concat, holf, cpredW, cpredb, d_out, flag);
}

// Round 10
// 840.163 us; speedup vs baseline: 7.0549x; 1.0015x over previous
//
#include <hip/hip_runtime.h>

typedef unsigned short u16;
typedef __attribute__((ext_vector_type(8))) short short8;
typedef __attribute__((ext_vector_type(4))) float floatx4;
typedef _Float16 half8 __attribute__((ext_vector_type(8)));
typedef _Float16 half2v __attribute__((ext_vector_type(2)));
typedef unsigned uint4v __attribute__((ext_vector_type(4)));

#define AGENT __HIP_MEMORY_SCOPE_AGENT
#define SENT 0x7FFF7FFFu   // f16 NaN pair — unreachable: h = sigm*tanh in (-1,1)

// ---------- helpers ----------
__device__ __forceinline__ float bf2f(u16 v) { return __uint_as_float(((unsigned)v) << 16); }
__device__ __forceinline__ u16 f2bf(float f) {
    unsigned u = __float_as_uint(f);
    unsigned r = (u + 0x7FFFu + ((u >> 16) & 1u)) >> 16;
    return (u16)r;
}
// fast transcendentals: native v_exp + raw v_rcp (no precise-div sequence)
__device__ __forceinline__ float sigm_(float x) {
    return __builtin_amdgcn_rcpf(1.f + __expf(-x));
}
__device__ __forceinline__ float tanh_(float x) {
    x = fminf(fmaxf(x, -15.f), 15.f);
    float e = __expf(2.f * x);
    return (e - 1.f) * __builtin_amdgcn_rcpf(e + 1.f);
}

// async global->LDS, 16B per lane; LDS dest is wave-uniform base + lane*16
typedef __attribute__((address_space(1))) void gvoid_t;
typedef __attribute__((address_space(3))) void lvoid_t;
__device__ __forceinline__ void gl_lds16(const void* g, void* l) {
    __builtin_amdgcn_global_load_lds((gvoid_t*)g, (lvoid_t*)l, 16, 0, 0);
}

// B=32, C=512, H=6, W=40, NC=97, L=26, T=27
#define HEX_WORDS (134 * 32 * 256)

// ---------- init: sentinel-fill hEx + dtype sniff (one launch) ----------
__global__ void init_k(const void* __restrict__ feat_raw, int* __restrict__ flag,
                       unsigned* __restrict__ hEx) {
    int idx = blockIdx.x * 256 + threadIdx.x;
    hEx[idx] = SENT;
    if (idx == 0) {
        const u16* p = (const u16*)feat_raw;
        int insane = 0;
        #pragma unroll
        for (int i = 0; i < 32; i += 2) {
            float x = bf2f(p[i]);
            float a = fabsf(x);
            if (!(a <= 1000.f)) insane = 1;
            if (x != 0.f && a < 1e-8f) insane = 1;
        }
        *flag = insane;
    }
}

// ---------- one-shot canonicalization ----------
struct SrcPtrs {
    const void* e0Wih; const void* e1Wih; const void* d0Wih; const void* d1Wih;
    const void* b0; const void* b1; const void* b2; const void* b3;
    const void* b4; const void* b5; const void* b6; const void* b7;
    const void* encW; const void* qW; const void* predW; const void* emb;
    const void* encb; const void* qb; const void* kb; const void* sW;
    const void* sb; const void* predb;
};
#define OFF_W0      0
#define OFF_W1      1048576
#define OFF_W2      2097152
#define OFF_W3      3145728
#define OFF_B       4194304
#define OFF_ENCW    4210688
#define OFF_QW      4472832
#define OFF_PREDW   4734976
#define OFF_EMB     4883968
#define OFF_ENCB    4933632
#define OFF_QB      4934144
#define OFF_KB      4934656
#define OFF_SW      4935168
#define OFF_SB      4935680
#define OFF_PREDB   4935681
#define CANON_TOTAL 4935778

__global__ __launch_bounds__(256) void canon_all(SrcPtrs S, u16* __restrict__ dst,
                                                 const int* __restrict__ flag) {
    int idx = blockIdx.x * 256 + threadIdx.x;
    if (idx >= CANON_TOTAL) return;
    const void* s; int loc;
    if (idx < OFF_B) {
        int k = idx >> 20; loc = idx & 1048575;
        s = (k == 0) ? S.e0Wih : (k == 1) ? S.e1Wih : (k == 2) ? S.d0Wih : S.d1Wih;
    } else if (idx < OFF_ENCW) {
        int r = idx - OFF_B; int k = r >> 11; loc = r & 2047;
        s = (k == 0) ? S.b0 : (k == 1) ? S.b1 : (k == 2) ? S.b2 : (k == 3) ? S.b3
          : (k == 4) ? S.b4 : (k == 5) ? S.b5 : (k == 6) ? S.b6 : S.b7;
    } else if (idx < OFF_QW)    { s = S.encW;  loc = idx - OFF_ENCW; }
    else if (idx < OFF_PREDW)   { s = S.qW;    loc = idx - OFF_QW; }
    else if (idx < OFF_EMB)     { s = S.predW; loc = idx - OFF_PREDW; }
    else if (idx < OFF_ENCB)    { s = S.emb;   loc = idx - OFF_EMB; }
    else if (idx < OFF_QB)      { s = S.encb;  loc = idx - OFF_ENCB; }
    else if (idx < OFF_KB)      { s = S.qb;    loc = idx - OFF_QB; }
    else if (idx < OFF_SW)      { s = S.kb;    loc = idx - OFF_KB; }
    else if (idx < OFF_SB)      { s = S.sW;    loc = idx - OFF_SW; }
    else if (idx < OFF_PREDB)   { s = S.sb;    loc = idx - OFF_SB; }
    else                        { s = S.predb; loc = idx - OFF_PREDB; }
    dst[idx] = (*flag) ? f2bf(((const float*)s)[loc]) : ((const u16*)s)[loc];
}

__global__ __launch_bounds__(64) void canonf_k(const void* __restrict__ src, float* __restrict__ dst,
                                               int n, const int* __restrict__ flag) {
    int i = blockIdx.x * 64 + threadIdx.x;
    if (i >= n) return;
    dst[i] = (*flag) ? ((const float*)src)[i] : bf2f(((const u16*)src)[i]);
}

// ---------- prep kernels ----------
__device__ __forceinline__ float rdf(const void* p, long i, int fl) {
    return fl ? ((const float*)p)[i] : bf2f(((const u16*)p)[i]);
}

__global__ __launch_bounds__(256) void featv_k(const void* __restrict__ feat, u16* __restrict__ featv,
                                               const int* __restrict__ flag) {
    const int fl = *flag;
    int idx = blockIdx.x * 256 + threadIdx.x;
    int c = idx & 511;
    int r = idx >> 9;
    int w = r % 40, b = r / 40;
    float mx = -1e30f;
    long base = ((long)(b * 512 + c) * 6) * 40 + w;
    #pragma unroll
    for (int h = 0; h < 6; h++) mx = fmaxf(mx, rdf(feat, base + h * 40, fl));
    featv[idx] = f2bf(mx);
}

__global__ __launch_bounds__(256) void padfeat_k(const void* __restrict__ feat, u16* __restrict__ featP,
                                                 const int* __restrict__ flag) {
    const int fl = *flag;
    int idx = blockIdx.x * 256 + threadIdx.x;
    int c = idx & 511;
    int r = idx >> 9;
    int wp = r % 42; int r2 = r / 42;
    int hp = r2 & 7; int b = r2 >> 3;
    u16 v = 0;
    if (hp >= 1 && hp <= 6 && wp >= 1 && wp <= 40) {
        long si = ((long)(b * 512 + c) * 6 + (hp - 1)) * 40 + (wp - 1);
        v = fl ? f2bf(((const float*)feat)[si]) : ((const u16*)feat)[si];
    }
    featP[idx] = v;
}

__global__ __launch_bounds__(256) void w2_k(const void* __restrict__ kW, u16* __restrict__ W2,
                                            const int* __restrict__ flag) {
    int idx = blockIdx.x * 256 + threadIdx.x;
    int co = idx / 4608;
    int r = idx % 4608;
    int kh = r / 1536;
    int r2 = r % 1536;
    int kw = r2 / 512;
    int ci = r2 & 511;
    long si = ((long)(co * 512 + ci) * 3 + kh) * 3 + kw;
    W2[idx] = (*flag) ? f2bf(((const float*)kW)[si]) : ((const u16*)kW)[si];
}

__global__ __launch_bounds__(256) void wq3_all(
    const void* __restrict__ s0, const void* __restrict__ s1,
    const void* __restrict__ s2, const void* __restrict__ s3,
    _Float16* __restrict__ d0, _Float16* __restrict__ d1,
    _Float16* __restrict__ d2, _Float16* __restrict__ d3,
    const int* __restrict__ flag)
{
    int gb = blockIdx.x;
    int id = gb >> 9;
    const void* W = (id == 0) ? s0 : (id == 1) ? s1 : (id == 2) ? s2 : s3;
    _Float16* D = (id == 0) ? d0 : (id == 1) ? d1 : (id == 2) ? d2 : d3;
    int o = (gb & 511) * 256 + threadIdx.x;
    int t = o & 511;
    int c = (o >> 9) & 31;
    int j = o >> 14;
    int rid = t >> 1, hf = t & 1;
    int n = (rid >> 6) * 512 + j * 64 + (rid & 63);
    int k = hf * 256 + c * 8;
    int fl = *flag;
    _Float16* dst = D + (long)o * 8;
    #pragma unroll
    for (int jj = 0; jj < 8; jj++) {
        long si = (long)n * 512 + k + jj;
        float v = fl ? ((const float*)W)[si] : bf2f(((const u16*)W)[si]);
        dst[jj] = (_Float16)v;
    }
}

// ---------- NT GEMM ----------
__global__ __launch_bounds__(256) void gemm_nt_f32(
    const u16* __restrict__ A, int lda,
    const u16* __restrict__ Bw,
    const u16* __restrict__ bias0, const u16* __restrict__ bias1,
    float* __restrict__ C, int M, int N, int K, int ldc)
{
    __shared__ __align__(16) u16 As[64][40];
    __shared__ __align__(16) u16 Bs[64][40];
    const int tid = threadIdx.x;
    const int bn = blockIdx.x, bm = blockIdx.y;
    const int l = tid & 63, wid = tid >> 6;
    const int wm = wid >> 1, wn = wid & 1;
    const int lr = tid >> 2, lc = (tid & 3) * 8;
    const int l15 = l & 15, lq = l >> 4;

    floatx4 acc00 = (floatx4)(0.f), acc01 = (floatx4)(0.f), acc10 = (floatx4)(0.f), acc11 = (floatx4)(0.f);

    int am = bm * 64 + lr; if (am > M - 1) am = M - 1;
    const u16* Ap = A + (long)am * lda + lc;
    const u16* Bp = Bw + (long)(bn * 64 + lr) * K + lc;

    for (int k0 = 0; k0 < K; k0 += 32) {
        *(short8*)&As[lr][lc] = *(const short8*)(Ap + k0);
        *(short8*)&Bs[lr][lc] = *(const short8*)(Bp + k0);
        __syncthreads();
        short8 af0 = *(const short8*)&As[wm * 32 + l15][lq * 8];
        short8 af1 = *(const short8*)&As[wm * 32 + 16 + l15][lq * 8];
        short8 bf0 = *(const short8*)&Bs[wn * 32 + l15][lq * 8];
        short8 bf1 = *(const short8*)&Bs[wn * 32 + 16 + l15][lq * 8];
        acc00 = __builtin_amdgcn_mfma_f32_16x16x32_bf16(af0, bf0, acc00, 0, 0, 0);
        acc01 = __builtin_amdgcn_mfma_f32_16x16x32_bf16(af0, bf1, acc01, 0, 0, 0);
        acc10 = __builtin_amdgcn_mfma_f32_16x16x32_bf16(af1, bf0, acc10, 0, 0, 0);
        acc11 = __builtin_amdgcn_mfma_f32_16x16x32_bf16(af1, bf1, acc11, 0, 0, 0);
        __syncthreads();
    }
    floatx4 accs[2][2] = {{acc00, acc01}, {acc10, acc11}};
    #pragma unroll
    for (int i = 0; i < 2; i++)
        #pragma unroll
        for (int j = 0; j < 2; j++)
            #pragma unroll
            for (int r = 0; r < 4; r++) {
                int gm = bm * 64 + wm * 32 + i * 16 + lq * 4 + r;
                int gn = bn * 64 + wn * 32 + j * 16 + l15;
                if (gm < M) {
                    float v = accs[i][j][r];
                    if (bias0) v += bf2f(bias0[gn]);
                    if (bias1) v += bf2f(bias1[gn]);
                    C[(long)gm * ldc + gn] = v;
                }
            }
}

// ---------- conv3x3 v2: 128x128 tile, global_load_lds, LDS dbuf, XCD-local bm slices ----------
// Grid dim3(8,32): bm = bx*8 + (by&7) (0..63, >=60 idle), bn = by>>3 (0..3).
// linear id % 8 == bx -> XCD bx owns bm slice [8bx, 8bx+8): real featP footprint
// ~1.5MB (9x im2col overlap collapses in L2) + B tiles -> A fetched from L3 once.
// Staging: 4 waves x (2 A + 2 B) global_load_lds dwordx4; lane i of segment s
// covers row s*16+i/4, k8=(i%4) — matches LDS auto-scatter base+lane*16 exactly.
__global__ __launch_bounds__(256) void conv_gemm(
    const u16* __restrict__ featP, const u16* __restrict__ W2,
    const u16* __restrict__ kb, u16* __restrict__ kmap)
{
    __shared__ __align__(16) u16 As[2][128][32];
    __shared__ __align__(16) u16 Bs[2][128][32];
    const int tid = threadIdx.x;
    int bm = blockIdx.x * 8 + (blockIdx.y & 7);
    int bn = blockIdx.y >> 3;
    if (bm >= 60) return;
    const int wv = tid >> 6, l = tid & 63;
    const int wm = wv >> 1, wn = wv & 1;
    const int l15 = l & 15, lq = l >> 4;
    const int s0 = wv * 2, s1 = s0 + 1;

    int ar0 = bm * 128 + s0 * 16 + (l >> 2);
    int ar1 = bm * 128 + s1 * 16 + (l >> 2);
    int ab0 = ar0 / 240, ahw0 = ar0 % 240;
    int ab1 = ar1 / 240, ahw1 = ar1 % 240;
    const u16* ga0 = featP + ((long)(ab0 * 8 + ahw0 / 40) * 42 + (ahw0 % 40)) * 512 + (l & 3) * 8;
    const u16* ga1 = featP + ((long)(ab1 * 8 + ahw1 / 40) * 42 + (ahw1 % 40)) * 512 + (l & 3) * 8;
    const u16* gb0 = W2 + (long)(bn * 128 + s0 * 16 + (l >> 2)) * 4608 + (l & 3) * 8;
    const u16* gb1 = W2 + (long)(bn * 128 + s1 * 16 + (l >> 2)) * 4608 + (l & 3) * 8;

    floatx4 acc[4][4];
    #pragma unroll
    for (int i = 0; i < 4; i++)
        #pragma unroll
        for (int j = 0; j < 4; j++) acc[i][j] = (floatx4)(0.f);

    auto stage = [&](int k0, int pb) {
        int kh = k0 / 1536;
        int rem = k0 - kh * 1536;
        int aoff = (kh * 42 + (rem >> 9)) * 512 + (rem & 511);
        gl_lds16(ga0 + aoff, &As[pb][s0 * 16][0]);
        gl_lds16(ga1 + aoff, &As[pb][s1 * 16][0]);
        gl_lds16(gb0 + k0, &Bs[pb][s0 * 16][0]);
        gl_lds16(gb1 + k0, &Bs[pb][s1 * 16][0]);
    };

    stage(0, 0);
    __syncthreads();
    for (int k = 0; k < 144; k++) {
        int cur = k & 1;
        if (k + 1 < 144) stage((k + 1) * 32, cur ^ 1);
        short8 af[4], bf[4];
        #pragma unroll
        for (int i = 0; i < 4; i++) af[i] = *(const short8*)&As[cur][wm * 64 + i * 16 + l15][lq * 8];
        #pragma unroll
        for (int j = 0; j < 4; j++) bf[j] = *(const short8*)&Bs[cur][wn * 64 + j * 16 + l15][lq * 8];
        #pragma unroll
        for (int i = 0; i < 4; i++)
            #pragma unroll
            for (int j = 0; j < 4; j++)
                acc[i][j] = __builtin_amdgcn_mfma_f32_16x16x32_bf16(af[i], bf[j], acc[i][j], 0, 0, 0);
        __syncthreads();
    }

    #pragma unroll
    for (int i = 0; i < 4; i++)
        #pragma unroll
        for (int j = 0; j < 4; j++)
            #pragma unroll
            for (int r = 0; r < 4; r++) {
                int row = bm * 128 + wm * 64 + i * 16 + lq * 4 + r;
                int col = bn * 128 + wn * 64 + j * 16 + l15;
                kmap[(long)row * 512 + col] = f2bf(acc[i][j][r] + bf2f(kb[col]));
            }
}

// ---------- LSTM recurrence v4: sentinel self-announcing exchange (r8-verified) ----------
#define WL(F) F(0) F(1) F(2) F(3) F(4) F(5) F(6) F(7) F(8) F(9) F(10) F(11) F(12) F(13) F(14) F(15) \
              F(16) F(17) F(18) F(19) F(20) F(21) F(22) F(23) F(24) F(25) F(26) F(27) F(28) F(29) F(30) F(31)
#define WLA(F) F(0,0) F(1,1) F(2,2) F(3,3) F(4,0) F(5,1) F(6,2) F(7,3) \
               F(8,0) F(9,1) F(10,2) F(11,3) F(12,0) F(13,1) F(14,2) F(15,3) \
               F(16,0) F(17,1) F(18,2) F(19,3) F(20,0) F(21,1) F(22,2) F(23,3) \
               F(24,0) F(25,1) F(26,2) F(27,3) F(28,0) F(29,1) F(30,2) F(31,3)
#define WDECL(i) half8 w##i = wp8[(long)(j * 32 + i) * 512 + tid];
#define WPIN(i)  asm volatile("" : "+v"(w##i));
#define DOTC(i,k) { \
    half8 hv = *(const half8*)&hS2[(hf * 2 + (i / 16)) * 136 + (i % 16) * 8]; \
    a##k = __builtin_amdgcn_fdot2(__builtin_shufflevector(hv, hv, 0, 1), __builtin_shufflevector(w##i, w##i, 0, 1), a##k, false); \
    a##k = __builtin_amdgcn_fdot2(__builtin_shufflevector(hv, hv, 2, 3), __builtin_shufflevector(w##i, w##i, 2, 3), a##k, false); \
    a##k = __builtin_amdgcn_fdot2(__builtin_shufflevector(hv, hv, 4, 5), __builtin_shufflevector(w##i, w##i, 4, 5), a##k, false); \
    a##k = __builtin_amdgcn_fdot2(__builtin_shufflevector(hv, hv, 6, 7), __builtin_shufflevector(w##i, w##i, 6, 7), a##k, false); }

__global__ __launch_bounds__(512) __attribute__((amdgpu_waves_per_eu(2, 2))) void lstm_sync(
    const float* __restrict__ xpre, const _Float16* __restrict__ Wq3,
    u16* __restrict__ seq_out, float* __restrict__ f32_out,
    unsigned* __restrict__ hExT, int T, int f32_ld)
{
    const int i_ = blockIdx.x;
    const int slot = i_ >> 3;
    const int b = (i_ & 7) * 4 + (slot & 3);
    const int j = slot >> 2;
    const int tid = threadIdx.x;
    const int hf = tid & 1;

    __shared__ __align__(16) _Float16 hS2[4 * 136];
    __shared__ float part[512];

    const half8* wp8 = (const half8*)Wq3;
    WL(WDECL)
    WL(WPIN)
    float cst = 0.f;

    for (int t = 0; t < T; t++) {
        float xi = 0.f, xf = 0.f, xg = 0.f, xo = 0.f;
        if (tid < 64) {
            const float* xp = xpre + ((long)b * T + t) * 2048 + j * 64 + tid;
            xi = xp[0]; xf = xp[512]; xg = xp[1024]; xo = xp[1536];
        }
        float a0 = 0.f, a1 = 0.f, a2 = 0.f, a3 = 0.f;
        if (t > 0) {
            if (tid < 64) {
                const unsigned* src = &hExT[((long)(t - 1) * 32 + b) * 256 + tid * 4];
                unsigned v0, v1, v2, v3;
                do {
                    v0 = __hip_atomic_load(src + 0, __ATOMIC_RELAXED, AGENT);
                    v1 = __hip_atomic_load(src + 1, __ATOMIC_RELAXED, AGENT);
                    v2 = __hip_atomic_load(src + 2, __ATOMIC_RELAXED, AGENT);
                    v3 = __hip_atomic_load(src + 3, __ATOMIC_RELAXED, AGENT);
                } while (v0 == SENT || v1 == SENT || v2 == SENT || v3 == SENT);
                uint4v v; v.x = v0; v.y = v1; v.z = v2; v.w = v3;
                *(uint4v*)&hS2[(tid >> 4) * 136 + (tid & 15) * 8] = v;
            }
            __syncthreads();
            WLA(DOTC)
        }
        part[tid] = (a0 + a1) + (a2 + a3);
        __syncthreads();
        if (tid < 64) {
            float gi = xi + part[(0   + tid) * 2] + part[(0   + tid) * 2 + 1];
            float gf = xf + part[(64  + tid) * 2] + part[(64  + tid) * 2 + 1];
            float gg = xg + part[(128 + tid) * 2] + part[(128 + tid) * 2 + 1];
            float go = xo + part[(192 + tid) * 2] + part[(192 + tid) * 2 + 1];
            cst = sigm_(gf) * cst + sigm_(gi) * tanh_(gg);
            float h = sigm_(go) * tanh_(cst);
            float hlo = __shfl(h, tid * 2);
            float hhi = __shfl(h, tid * 2 + 1);
            if (t + 1 < T && tid < 32) {
                half2v hp; hp[0] = (_Float16)hlo; hp[1] = (_Float16)hhi;
                __hip_atomic_store(&hExT[((long)t * 32 + b) * 256 + j * 32 + tid],
                                   *(unsigned*)&hp, __ATOMIC_RELAXED, AGENT);
            }
            asm volatile("" ::: "memory");
            long so = ((long)b * T + t) * 512 + j * 64 + tid;
            seq_out[so] = f2bf(h);
            if (f32_out) f32_out[((long)b * T + t) * f32_ld + j * 64 + tid] = h;
        }
    }
}

// ---------- token build ----------
__global__ __launch_bounds__(256) void tok_k(
    const float* __restrict__ holf, const u16* __restrict__ cemb,
    const int* __restrict__ label, u16* __restrict__ tok)
{
    int idx = blockIdx.x * 256 + threadIdx.x;
    int c = idx & 511;
    int m = idx >> 9;
    int b = m / 27, t = m % 27;
    float v;
    if (t == 0) v = holf[(long)b * 512 + c];
    else v = bf2f(cemb[(long)label[b * 26 + (t - 1)] * 512 + c]);
    tok[idx] = f2bf(v);
}

// ---------- fused score v2 (r9-verified) ----------
__global__ __launch_bounds__(256) void score_k(
    const float* __restrict__ q, const u16* __restrict__ kmap,
    const u16* __restrict__ sW, const u16* __restrict__ sb,
    const float* __restrict__ vr, float* __restrict__ aw)
{
    int blk = blockIdx.x;
    int xcd = blk & 7, rest = blk >> 3;
    int bq = rest & 3, t = rest >> 2;
    int b = xcd * 4 + bq;
    int bt = b * 27 + t;
    int tid = threadIdx.x, wv = tid >> 6, ln = tid & 63;

    __shared__ float sc[240];
    __shared__ float red[256];

    float qr[8], sr[8];
    const float* qp = q + (long)bt * 512 + ln * 8;
    #pragma unroll
    for (int i = 0; i < 8; i++) qr[i] = qp[i];
    #pragma unroll
    for (int i = 0; i < 8; i++) sr[i] = bf2f(sW[ln * 8 + i]);

    const u16* kb_ = kmap + (long)b * 240 * 512;
    for (int r = wv * 60; r < wv * 60 + 60; r++) {
        short8 kv = *(const short8*)(kb_ + (long)r * 512 + ln * 8);
        float acc = 0.f;
        #pragma unroll
        for (int i = 0; i < 8; i++) {
            float x = bf2f((u16)kv[i]) + qr[i];
            acc = fmaf(sr[i], tanh_(x), acc);
        }
        #pragma unroll
        for (int m = 32; m > 0; m >>= 1) acc += __shfl_xor(acc, m);
        if (ln == 0) sc[r] = acc;
    }
    __syncthreads();

    float scv = -INFINITY, ex = 0.f;
    if (tid < 240) {
        float rr = vr[b];
        int vw = (int)ceilf(40.f * rr);
        if (vw > 40) vw = 40;
        int wcol = tid % 40;
        scv = (wcol >= vw) ? -INFINITY : (sc[tid] + bf2f(sb[0]));
    }
    red[tid] = scv;
    __syncthreads();
    for (int s = 128; s > 0; s >>= 1) {
        if (tid < s) red[tid] = fmaxf(red[tid], red[tid + s]);
        __syncthreads();
    }
    float mx = red[0];
    __syncthreads();
    if (tid < 240) ex = (scv == -INFINITY) ? 0.f : __expf(scv - mx);
    red[tid] = ex;
    __syncthreads();
    for (int s = 128; s > 0; s >>= 1) {
        if (tid < s) red[tid] += red[tid + s];
        __syncthreads();
    }
    float inv = __builtin_amdgcn_rcpf(red[0]);
    if (tid < 240) aw[(long)bt * 240 + tid] = ex * inv;
}

// ---------- attn_feat -> concat cols [512,1024) ----------
__global__ __launch_bounds__(256) void attn_k(
    const void* __restrict__ feat, const float* __restrict__ aw,
    float* __restrict__ concat, const int* __restrict__ flag)
{
    const int fl = *flag;
    int b = blockIdx.x >> 3;
    int cc = (blockIdx.x & 7) * 64;
    int tid = threadIdx.x;
    __shared__ float awS[27 * 240];
    __shared__ u16 fS[64 * 240];
    for (int i = tid; i < 27 * 240; i += 256) awS[i] = aw[(long)b * 27 * 240 + i];
    long fbase = ((long)b * 512 + cc) * 240;
    for (int i = tid; i < 64 * 240; i += 256)
        fS[i] = fl ? f2bf(((const float*)feat)[fbase + i]) : ((const u16*)feat)[fbase + i];
    __syncthreads();
    for (int item = tid; item < 64 * 27; item += 256) {
        int c = item / 27, t = item % 27;
        const u16* fp = &fS[c * 240];
        const float* ap = &awS[t * 240];
        float acc = 0.f;
        for (int hw = 0; hw < 240; hw++) acc = fmaf(bf2f(fp[hw]), ap[hw], acc);
        concat[((long)(b * 27 + t)) * 1536 + 512 + cc + c] = acc;
    }
}

// ---------- prediction + slice ----------
__global__ __launch_bounds__(256) void pred_k(
    const float* __restrict__ concat, const float* __restrict__ holf,
    const u16* __restrict__ pW, const u16* __restrict__ pb,
    void* __restrict__ out, const int* __restrict__ flag)
{
    int m0 = blockIdx.x * 4;
    int tid = threadIdx.x;
    const int fl = *flag;
    __shared__ float aS[4][1024];
    __shared__ float hS[4][512];
    for (int i = tid; i < 4 * 1024; i += 256)
        aS[i / 1024][i % 1024] = concat[(long)(m0 + i / 1024) * 1536 + (i % 1024)];
    for (int i = tid; i < 4 * 512; i += 256) {
        int m = m0 + i / 512;
        hS[i / 512][i % 512] = holf[(long)(m / 27) * 512 + (i % 512)];
    }
    __syncthreads();
    int r = tid >> 6;
    int nb = tid & 63;
    int m = m0 + r;
    int b = m / 27, t = m % 27;
    for (int n = nb; n < 97; n += 64) {
        const u16* wp = pW + (long)n * 1536;
        float acc = 0.f;
        for (int k = 0; k < 1024; k++) acc = fmaf(aS[r][k], bf2f(wp[k]), acc);
        for (int k = 0; k < 512; k++) acc = fmaf(hS[r][k], bf2f(wp[1024 + k]), acc);
        acc += bf2f(pb[n]);
        if (t > 0) {
            long o = ((long)(b * 26 + (t - 1))) * 97 + n;
            if (fl) ((float*)out)[o] = acc;
            else    ((u16*)out)[o] = f2bf(acc);
        }
    }
}

// ---------- launch ----------
extern "C" void kernel_launch(void* const* d_in, const int* in_sizes, int n_in,
                              void* d_out, int out_size, void* d_ws, size_t ws_size,
                              hipStream_t stream) {
    (void)in_sizes; (void)n_in; (void)out_size; (void)ws_size;
    const void* feat_r = d_in[0];
    const int*  label  = (const int*)d_in[1];
    const void* vr_r   = d_in[2];

    char* w = (char*)d_ws;
    size_t off = 0;
    auto alloc = [&](size_t bytes) -> void* {
        void* p = w + off;
        off = (off + bytes + 63) & ~(size_t)63;
        return p;
    };
    int*   flag    = (int*)  alloc(4);
    unsigned* hEx  = (unsigned*)alloc((size_t)HEX_WORDS * 4);
    u16*   canon   = (u16*)  alloc((size_t)CANON_TOTAL * 2);
    float* cvr     = (float*)alloc(32ull * 4);
    u16*   featv   = (u16*)  alloc(655360ull * 2);
    float* xpre    = (float*)alloc(2621440ull * 4);   // kmap aliases after LSTMs
    u16*   seq0    = (u16*)  alloc(655360ull * 2);
    u16*   seq1    = (u16*)  alloc(655360ull * 2);
    u16*   tok     = (u16*)  alloc(442368ull * 2);
    u16*   seqd0   = (u16*)  alloc(442368ull * 2);
    u16*   Hid     = (u16*)  alloc(442368ull * 2);
    float* holf    = (float*)alloc(16384ull * 4);
    float* qf      = (float*)alloc(442368ull * 4);
    u16*   featP   = (u16*)  alloc(5505024ull * 2);
    u16*   W2      = (u16*)  alloc(2359296ull * 2);
    float* aw      = (float*)alloc(207360ull * 4);
    float* concat  = (float*)alloc(1327104ull * 4);
    _Float16* Wq[4];
    for (int i = 0; i < 4; i++) Wq[i] = (_Float16*)alloc(1048576ull * 2);
    u16*   kmap    = (u16*)xpre;

    unsigned* hEx0 = hEx;
    unsigned* hEx1 = hEx + 40ull * 8192;
    unsigned* hEx2 = hEx + 80ull * 8192;
    unsigned* hEx3 = hEx + 107ull * 8192;

    u16* cW0    = canon + OFF_W0;
    u16* cW1    = canon + OFF_W1;
    u16* cW2    = canon + OFF_W2;
    u16* cW3    = canon + OFF_W3;
    u16* cb0    = canon + OFF_B;
    u16* cencW  = canon + OFF_ENCW;
    u16* cqW    = canon + OFF_QW;
    u16* cpredW = canon + OFF_PREDW;
    u16* cemb   = canon + OFF_EMB;
    u16* cencb  = canon + OFF_ENCB;
    u16* cqb    = canon + OFF_QB;
    u16* ckb    = canon + OFF_KB;
    u16* csW    = canon + OFF_SW;
    u16* csb    = canon + OFF_SB;
    u16* cpredb = canon + OFF_PREDB;

    // ---- init (sentinel fill + sniff) + canonicalize ----
    init_k<<<dim3(HEX_WORDS / 256), 256, 0, stream>>>(feat_r, flag, hEx);
    SrcPtrs S;
    S.e0Wih = d_in[3];  S.e1Wih = d_in[7];  S.d0Wih = d_in[20]; S.d1Wih = d_in[24];
    S.b0 = d_in[5];  S.b1 = d_in[6];  S.b2 = d_in[9];  S.b3 = d_in[10];
    S.b4 = d_in[22]; S.b5 = d_in[23]; S.b6 = d_in[26]; S.b7 = d_in[27];
    S.encW = d_in[11]; S.qW = d_in[13]; S.predW = d_in[28]; S.emb = d_in[19];
    S.encb = d_in[12]; S.qb = d_in[14]; S.kb = d_in[16]; S.sW = d_in[17];
    S.sb = d_in[18]; S.predb = d_in[29];
    canon_all<<<dim3((CANON_TOTAL + 255) / 256), 256, 0, stream>>>(S, canon, flag);
    canonf_k<<<dim3(1), 64, 0, stream>>>(vr_r, cvr, 32, flag);
    w2_k<<<dim3(9216), 256, 0, stream>>>(d_in[15], W2, flag);
    wq3_all<<<dim3(2048), 256, 0, stream>>>(d_in[4], d_in[8], d_in[21], d_in[25],
                                            Wq[0], Wq[1], Wq[2], Wq[3], flag);

    // ---- prep ----
    featv_k  <<<dim3(2560), 256, 0, stream>>>(feat_r, featv, flag);
    padfeat_k<<<dim3(21504), 256, 0, stream>>>(feat_r, featP, flag);

    // ---- encoder ----
    gemm_nt_f32<<<dim3(32, 20), 256, 0, stream>>>(featv, 512, cW0, cb0 + 0 * 2048, cb0 + 1 * 2048, xpre, 1280, 2048, 512, 2048);
    lstm_sync<<<dim3(256), 512, 0, stream>>>(xpre, Wq[0], seq0, nullptr, hEx0, 40, 0);
    gemm_nt_f32<<<dim3(32, 20), 256, 0, stream>>>(seq0, 512, cW1, cb0 + 2 * 2048, cb0 + 3 * 2048, xpre, 1280, 2048, 512, 2048);
    lstm_sync<<<dim3(256), 512, 0, stream>>>(xpre, Wq[1], seq1, nullptr, hEx1, 40, 0);
    gemm_nt_f32<<<dim3(8, 1), 256, 0, stream>>>(seq1 + 39 * 512, 40 * 512, cencW, cencb, nullptr, holf, 32, 512, 512, 512);

    // ---- decoder ----
    tok_k<<<dim3(1728), 256, 0, stream>>>(holf, cemb, label, tok);
    gemm_nt_f32<<<dim3(32, 14), 256, 0, stream>>>(tok, 512, cW2, cb0 + 4 * 2048, cb0 + 5 * 2048, xpre, 864, 2048, 512, 2048);
    lstm_sync<<<dim3(256), 512, 0, stream>>>(xpre, Wq[2], seqd0, nullptr, hEx2, 27, 0);
    gemm_nt_f32<<<dim3(32, 14), 256, 0, stream>>>(seqd0, 512, cW3, cb0 + 6 * 2048, cb0 + 7 * 2048, xpre, 864, 2048, 512, 2048);
    lstm_sync<<<dim3(256), 512, 0, stream>>>(xpre, Wq[3], Hid, concat, hEx3, 27, 1536);

    // ---- attention (xpre dead; kmap aliases it) ----
    gemm_nt_f32<<<dim3(8, 14), 256, 0, stream>>>(Hid, 512, cqW, cqb, nullptr, qf, 864, 512, 512, 512);
    conv_gemm<<<dim3(8, 32), 256, 0, stream>>>(featP, W2, ckb, kmap);
    score_k<<<dim3(864), 256, 0, stream>>>(qf, kmap, csW, csb, cvr, aw);
    attn_k<<<dim3(256), 256, 0, stream>>>(feat_r, aw, concat, flag);

    // ---- prediction ----
    pred_k<<<dim3(216), 256, 0, stream>>>(concat, holf, cpredW, cpredb, d_out, flag);
}